// Round 1
// baseline (7680.405 us; speedup 1.0000x reference)
//
#include <hip/hip_runtime.h>
#include <math.h>

constexpr float SCALE_QK = 0.125f;  // 64^-0.5

// ============ axis means of img_feats (2,32,112,112,80) ============
__global__ void mean_d_k(const float* __restrict__ in, float* __restrict__ out) {
    int idx = blockIdx.x * 256 + threadIdx.x;
    constexpr int TOT = 2*32*112*80;
    if (idx >= TOT) return;
    int w = idx % 80, rest = idx / 80;
    int h = rest % 112, bc = rest / 112;
    const float* p = in + (size_t)bc*(112*112*80) + h*80 + w;
    float s = 0.f;
    #pragma unroll 4
    for (int d = 0; d < 112; ++d) s += p[(size_t)d*(112*80)];
    out[idx] = s * (1.f/112.f);
}

__global__ void mean_h_k(const float* __restrict__ in, float* __restrict__ out) {
    int idx = blockIdx.x * 256 + threadIdx.x;
    constexpr int TOT = 2*32*112*80;
    if (idx >= TOT) return;
    int w = idx % 80, rest = idx / 80;
    int d = rest % 112, bc = rest / 112;
    const float* p = in + (size_t)bc*(112*112*80) + (size_t)d*(112*80) + w;
    float s = 0.f;
    #pragma unroll 4
    for (int h = 0; h < 112; ++h) s += p[h*80];
    out[idx] = s * (1.f/112.f);
}

__global__ void mean_w_k(const float* __restrict__ in, float* __restrict__ out) {
    int idx = blockIdx.x * 256 + threadIdx.x;
    constexpr int TOT = 2*32*112*112;
    if (idx >= TOT) return;
    int h = idx % 112, rest = idx / 112;
    int d = rest % 112, bc = rest / 112;
    const float4* p = reinterpret_cast<const float4*>(
        in + (size_t)bc*(112*112*80) + (size_t)d*(112*80) + (size_t)h*80);
    float s = 0.f;
    #pragma unroll
    for (int i = 0; i < 20; ++i) { float4 v = p[i]; s += v.x+v.y+v.z+v.w; }
    out[idx] = s * (1.f/80.f);
}

// ============ patchify: v2d (2,32,16*p1,16*p2) -> P (2*256, p1*p2*32) ============
__global__ void patchify_k(const float* __restrict__ v2d, float* __restrict__ P,
                           int p1, int p2, int PD) {
    int idx = blockIdx.x * 256 + threadIdx.x;
    int total = 2*256*PD;
    if (idx >= total) return;
    int f = idx % PD, bn = idx / PD;
    int n = bn & 255, b = bn >> 8;
    int c = f & 31, pp = f >> 5;              // f = (pp1*p2+pp2)*32 + c
    int pp2 = pp % p2, pp1 = pp / p2;
    int ww = n & 15, hh = n >> 4;             // 16x16 patch grid for all branches
    int Ht = 16*p1, Wt = 16*p2;
    P[idx] = v2d[(((size_t)b*32 + c)*Ht + hh*p1 + pp1)*Wt + ww*p2 + pp2];
}

// ============ generic fp32 GEMM: C = A(MxK) @ B(KxN) + epilogue ============
// bias: [N] or null; pos: [(row%256)*N + col] or null; resid: [M*N] or null;
// act: 0 none, 1 exact gelu
__global__ __launch_bounds__(256) void gemm_f32(
    const float* __restrict__ A, const float* __restrict__ B, float* __restrict__ C,
    int M, int N, int K,
    const float* __restrict__ bias, const float* __restrict__ pos,
    const float* __restrict__ resid, int act)
{
    constexpr int BM = 64, BN = 64, BK = 16;
    __shared__ float As[BK][BM];
    __shared__ float Bs[BK][BN];
    int t = threadIdx.x;
    int m0 = blockIdx.y * BM, n0 = blockIdx.x * BN;
    int tx = t & 15, ty = t >> 4;
    float acc[4][4] = {};
    for (int k0 = 0; k0 < K; k0 += BK) {
        #pragma unroll
        for (int i = 0; i < 4; ++i) {
            int idx = t + i*256;
            int r = idx >> 4, kk = idx & 15;
            int gr = m0 + r;
            As[kk][r] = (gr < M) ? A[(size_t)gr*K + k0 + kk] : 0.f;
        }
        #pragma unroll
        for (int i = 0; i < 4; ++i) {
            int idx = t + i*256;
            int kk = idx >> 6, c = idx & 63;
            int gc = n0 + c;
            Bs[kk][c] = (gc < N) ? B[(size_t)(k0+kk)*N + gc] : 0.f;
        }
        __syncthreads();
        #pragma unroll
        for (int kk = 0; kk < BK; ++kk) {
            float a[4], b[4];
            #pragma unroll
            for (int i = 0; i < 4; ++i) a[i] = As[kk][ty*4+i];
            #pragma unroll
            for (int j = 0; j < 4; ++j) b[j] = Bs[kk][tx*4+j];
            #pragma unroll
            for (int i = 0; i < 4; ++i)
                #pragma unroll
                for (int j = 0; j < 4; ++j)
                    acc[i][j] += a[i]*b[j];
        }
        __syncthreads();
    }
    #pragma unroll
    for (int i = 0; i < 4; ++i) {
        int gr = m0 + ty*4 + i;
        if (gr >= M) continue;
        #pragma unroll
        for (int j = 0; j < 4; ++j) {
            int gc = n0 + tx*4 + j;
            if (gc >= N) continue;
            float v = acc[i][j];
            if (bias)  v += bias[gc];
            if (pos)   v += pos[(size_t)(gr & 255)*N + gc];
            if (resid) v += resid[(size_t)gr*N + gc];
            if (act == 1) v = 0.5f*v*(1.0f + erff(v*0.70710678118654752f));
            C[(size_t)gr*N + gc] = v;
        }
    }
}

// ============ LayerNorm, rows of 768 ============
__global__ __launch_bounds__(256) void ln_k(const float* __restrict__ in, float* __restrict__ out,
                                            const float* __restrict__ g, const float* __restrict__ bta) {
    constexpr int N = 768;
    int row = blockIdx.x;
    const float* x = in + (size_t)row * N;
    float* y = out + (size_t)row * N;
    int t = threadIdx.x;
    float v0 = x[t], v1 = x[t+256], v2 = x[t+512];
    float s = v0+v1+v2, s2 = v0*v0+v1*v1+v2*v2;
    #pragma unroll
    for (int off = 32; off > 0; off >>= 1) { s += __shfl_down(s, off); s2 += __shfl_down(s2, off); }
    __shared__ float red[8];
    int wid = t >> 6, lane = t & 63;
    if (lane == 0) { red[wid] = s; red[wid+4] = s2; }
    __syncthreads();
    if (t == 0) {
        float S = red[0]+red[1]+red[2]+red[3];
        float S2 = red[4]+red[5]+red[6]+red[7];
        float mean = S * (1.f/N);
        float var = S2 * (1.f/N) - mean*mean;
        red[0] = mean; red[1] = rsqrtf(var + 1e-5f);
    }
    __syncthreads();
    float mean = red[0], rstd = red[1];
    y[t]     = (v0-mean)*rstd*g[t]     + bta[t];
    y[t+256] = (v1-mean)*rstd*g[t+256] + bta[t+256];
    y[t+512] = (v2-mean)*rstd*g[t+512] + bta[t+512];
}

// ============ fused self-attention: one block per (b,head), 256 q-rows ============
__global__ __launch_bounds__(256) void attn_k(
    const float* __restrict__ Q, const float* __restrict__ K, const float* __restrict__ V,
    float* __restrict__ O)
{
    int bh = blockIdx.x; int b = bh / 12, h = bh % 12;
    __shared__ float ks[256][64];
    __shared__ float vs[256][64];
    int t = threadIdx.x;
    for (int idx = t; idx < 256*64; idx += 256) {
        int m = idx >> 6, c = idx & 63;
        size_t goff = ((size_t)(b*256 + m))*768 + h*64 + c;
        ks[m][c] = K[goff];
        vs[m][c] = V[goff];
    }
    __syncthreads();
    float q[64];
    size_t qoff = ((size_t)(b*256 + t))*768 + h*64;
    #pragma unroll
    for (int c = 0; c < 64; ++c) q[c] = Q[qoff + c] * SCALE_QK;
    float mmax = -1e30f;
    for (int j = 0; j < 256; ++j) {
        float s = 0.f;
        #pragma unroll
        for (int c = 0; c < 64; ++c) s += q[c]*ks[j][c];
        mmax = fmaxf(mmax, s);
    }
    float o[64];
    #pragma unroll
    for (int c = 0; c < 64; ++c) o[c] = 0.f;
    float l = 0.f;
    for (int j = 0; j < 256; ++j) {
        float s = 0.f;
        #pragma unroll
        for (int c = 0; c < 64; ++c) s += q[c]*ks[j][c];
        float p = __expf(s - mmax);
        l += p;
        #pragma unroll
        for (int c = 0; c < 64; ++c) o[c] += p*vs[j][c];
    }
    float inv = 1.f / l;
    #pragma unroll
    for (int c = 0; c < 64; ++c) O[qoff + c] = o[c]*inv;
}

// ============ cross-attn colsum weights: W[b,h,j] = sum_i softmax_j(QH_i . KH_j * SC) ============
__global__ __launch_bounds__(128) void ca_w_k(
    const float* __restrict__ QH,   // (2*77, 768)
    const float* __restrict__ KH,   // (2*256, 768)
    float* __restrict__ Wout)       // (2,12,256)
{
    int bh = blockIdx.x; int b = bh / 12, h = bh % 12;
    __shared__ float ks[256][64];
    __shared__ float wsum[256];
    int t = threadIdx.x;
    for (int idx = t; idx < 256*64; idx += 128) {
        int m = idx >> 6, c = idx & 63;
        ks[m][c] = KH[((size_t)(b*256 + m))*768 + h*64 + c];
    }
    for (int j = t; j < 256; j += 128) wsum[j] = 0.f;
    __syncthreads();
    if (t < 77) {
        float q[64];
        size_t qoff = ((size_t)(b*77 + t))*768 + h*64;
        #pragma unroll
        for (int c = 0; c < 64; ++c) q[c] = QH[qoff + c] * SCALE_QK;
        float mmax = -1e30f;
        for (int j = 0; j < 256; ++j) {
            float s = 0.f;
            #pragma unroll
            for (int c = 0; c < 64; ++c) s += q[c]*ks[j][c];
            mmax = fmaxf(mmax, s);
        }
        float l = 0.f;
        for (int j = 0; j < 256; ++j) {
            float s = 0.f;
            #pragma unroll
            for (int c = 0; c < 64; ++c) s += q[c]*ks[j][c];
            l += __expf(s - mmax);
        }
        float inv = 1.f / l;
        for (int j = 0; j < 256; ++j) {
            float s = 0.f;
            #pragma unroll
            for (int c = 0; c < 64; ++c) s += q[c]*ks[j][c];
            atomicAdd(&wsum[j], __expf(s - mmax)*inv);
        }
    }
    __syncthreads();
    for (int j = t; j < 256; j += 128)
        Wout[((size_t)b*12 + h)*256 + j] = wsum[j];
}

// ============ O2[b,j,h*64+c] = W[b,h,j] * VH[b,j,h*64+c] ============
__global__ void ca_apply_k(const float* __restrict__ W, const float* __restrict__ VH,
                           float* __restrict__ O2) {
    int idx = blockIdx.x*256 + threadIdx.x;
    if (idx >= 512*768) return;
    int row = idx / 768, col = idx - row*768;
    int b = row >> 8, j = row & 255, h = col >> 6;
    O2[idx] = W[(b*12 + h)*256 + j] * VH[idx];
}

// ============ final: out = img + vw0*oax + vw1*osag + vw2*ocor (unpatchify fused) ============
__global__ void final_k(const float* __restrict__ img, const float* __restrict__ yax,
                        const float* __restrict__ ysag, const float* __restrict__ ycor,
                        const float* __restrict__ vw, float* __restrict__ out) {
    size_t idx = (size_t)blockIdx.x*256 + threadIdx.x;
    constexpr size_t TOT = (size_t)2*32*112*112*80;
    if (idx >= TOT) return;
    int w = (int)(idx % 80); size_t r = idx / 80;
    int h = (int)(r % 112); r /= 112;
    int d = (int)(r % 112); r /= 112;
    int c = (int)(r % 32);  int b = (int)(r / 32);
    float a  = yax [((size_t)(b*256 + (h/7)*16 + w/5))*1120 + (size_t)((h%7)*5 + (w%5))*32 + c];
    float sg = ysag[((size_t)(b*256 + (d/7)*16 + w/5))*1120 + (size_t)((d%7)*5 + (w%5))*32 + c];
    float co = ycor[((size_t)(b*256 + (d/7)*16 + h/7))*1568 + (size_t)((d%7)*7 + (h%7))*32 + c];
    out[idx] = img[idx] + vw[0]*a + vw[1]*sg + vw[2]*co;
}

static inline void gemm(hipStream_t s, const float* A, const float* B, float* C,
                        int M, int N, int K, const float* bias, const float* pos,
                        const float* resid, int act) {
    dim3 g((N+63)/64, (M+63)/64);
    gemm_f32<<<g, 256, 0, s>>>(A, B, C, M, N, K, bias, pos, resid, act);
}

extern "C" void kernel_launch(void* const* d_in, const int* in_sizes, int n_in,
                              void* d_out, int out_size, void* d_ws, size_t ws_size,
                              hipStream_t stream) {
    (void)in_sizes; (void)n_in; (void)out_size; (void)ws_size;
    const float* img    = (const float*)d_in[0];
    const float* txt    = (const float*)d_in[1];
    const float* pe_w[3] = {(const float*)d_in[2], (const float*)d_in[4], (const float*)d_in[6]};
    const float* pe_b[3] = {(const float*)d_in[3], (const float*)d_in[5], (const float*)d_in[7]};
    const float* pos[3]  = {(const float*)d_in[8], (const float*)d_in[9], (const float*)d_in[10]};
    const float* qw = (const float*)d_in[11];
    const float* kw = (const float*)d_in[12];
    const float* vw_attn = (const float*)d_in[13];
    const float* pw = (const float*)d_in[14];
    const float* pb = (const float*)d_in[15];
    const float* caq_w = (const float*)d_in[16];
    const float* caq_b = (const float*)d_in[17];
    const float* cak_w = (const float*)d_in[18];
    const float* cak_b = (const float*)d_in[19];
    const float* cav_w = (const float*)d_in[20];
    const float* cav_b = (const float*)d_in[21];
    const float* cao_w = (const float*)d_in[22];
    const float* cao_b = (const float*)d_in[23];
    const float* mlp_w1 = (const float*)d_in[24];
    const float* mlp_b1 = (const float*)d_in[25];
    const float* mlp_w2 = (const float*)d_in[26];
    const float* mlp_b2 = (const float*)d_in[27];
    const float* ow[3] = {(const float*)d_in[28], (const float*)d_in[30], (const float*)d_in[32]};
    const float* ob[3] = {(const float*)d_in[29], (const float*)d_in[31], (const float*)d_in[33]};
    const float* view_w = (const float*)d_in[34];
    const float* n_g[3] = {(const float*)d_in[35], (const float*)d_in[36], (const float*)d_in[37]};
    const float* n_b[3] = {(const float*)d_in[38], (const float*)d_in[39], (const float*)d_in[40]};

    float* ws = (float*)d_ws;
    size_t off = 0;
    auto alloc = [&](size_t n) { float* p = ws + off; off += n; return p; };
    float* m_ax  = alloc(573440);
    float* m_sag = alloc(573440);
    float* m_cor = alloc(802816);
    float* P   = alloc(802816);     // up to 512x1568
    float* X0  = alloc(393216);
    float* X1  = alloc(393216);
    float* Qb  = alloc(393216);
    float* Kb  = alloc(393216);
    float* Vb  = alloc(393216);
    float* Ob  = alloc(393216);
    float* X2  = alloc(393216);
    float* X3  = alloc(393216);
    float* X4  = alloc(393216);
    float* X5  = alloc(393216);
    float* Hb  = alloc(1572864);    // 512x3072
    float* X6  = alloc(393216);
    float* QH  = alloc(118272);     // 154x768
    float* Wb  = alloc(6144);       // 2x12x256
    float* Y[3];
    Y[0] = alloc(573440);           // 512x1120
    Y[1] = alloc(573440);
    Y[2] = alloc(802816);           // 512x1568

    mean_d_k<<<(573440+255)/256, 256, 0, stream>>>(img, m_ax);
    mean_h_k<<<(573440+255)/256, 256, 0, stream>>>(img, m_sag);
    mean_w_k<<<(802816+255)/256, 256, 0, stream>>>(img, m_cor);

    // txt queries for cross-attn (branch-independent): QH = txt @ caq_w + caq_b
    gemm(stream, txt, caq_w, QH, 154, 768, 768, caq_b, nullptr, nullptr, 0);

    const float* v2d[3] = {m_ax, m_sag, m_cor};
    const int p1a[3] = {7,7,7}, p2a[3] = {5,5,7};
    const int PDa[3] = {1120,1120,1568};

    for (int br = 0; br < 3; ++br) {
        int PD = PDa[br];
        patchify_k<<<(2*256*PD+255)/256, 256, 0, stream>>>(v2d[br], P, p1a[br], p2a[br], PD);
        // embed + pos
        gemm(stream, P, pe_w[br], X0, 512, 768, PD, pe_b[br], pos[br], nullptr, 0);
        ln_k<<<512, 256, 0, stream>>>(X0, X1, n_g[0], n_b[0]);
        // self-attention
        gemm(stream, X1, qw, Qb, 512, 768, 768, nullptr, nullptr, nullptr, 0);
        gemm(stream, X1, kw, Kb, 512, 768, 768, nullptr, nullptr, nullptr, 0);
        gemm(stream, X1, vw_attn, Vb, 512, 768, 768, nullptr, nullptr, nullptr, 0);
        attn_k<<<24, 256, 0, stream>>>(Qb, Kb, Vb, Ob);
        gemm(stream, Ob, pw, X2, 512, 768, 768, pb, nullptr, X1, 0);
        ln_k<<<512, 256, 0, stream>>>(X2, X3, n_g[1], n_b[1]);
        // cross-attention (note faithful colsum semantics)
        gemm(stream, X3, cak_w, Kb, 512, 768, 768, cak_b, nullptr, nullptr, 0);
        gemm(stream, X3, cav_w, Vb, 512, 768, 768, cav_b, nullptr, nullptr, 0);
        ca_w_k<<<24, 128, 0, stream>>>(QH, Kb, Wb);
        ca_apply_k<<<1536, 256, 0, stream>>>(Wb, Vb, Ob);
        gemm(stream, Ob, cao_w, X4, 512, 768, 768, cao_b, nullptr, X3, 0);
        ln_k<<<512, 256, 0, stream>>>(X4, X5, n_g[2], n_b[2]);
        // MLP
        gemm(stream, X5, mlp_w1, Hb, 512, 3072, 768, mlp_b1, nullptr, nullptr, 1);
        gemm(stream, Hb, mlp_w2, X6, 512, 768, 3072, mlp_b2, nullptr, X4, 0);
        // output projection
        gemm(stream, X6, ow[br], Y[br], 512, PD, 768, ob[br], nullptr, nullptr, 0);
    }

    final_k<<<(int)((64225280ULL + 255)/256), 256, 0, stream>>>(
        img, Y[0], Y[1], Y[2], view_w, (float*)d_out);
}

// Round 2
// 1235.867 us; speedup vs baseline: 6.2146x; 6.2146x over previous
//
#include <hip/hip_runtime.h>
#include <math.h>

typedef __attribute__((ext_vector_type(8))) short s8;
typedef __attribute__((ext_vector_type(4))) float f4;

__device__ inline unsigned short f2bf(float f) {
    unsigned u = __float_as_uint(f);
    u += 0x7fffu + ((u >> 16) & 1u);
    return (unsigned short)(u >> 16);
}

// ============ axis means of img_feats (2,32,112,112,80) ============
__global__ void mean_d_k(const float* __restrict__ in, float* __restrict__ out) {
    int idx = blockIdx.x * 256 + threadIdx.x;
    constexpr int TOT = 2*32*112*80;
    if (idx >= TOT) return;
    int w = idx % 80, rest = idx / 80;
    int h = rest % 112, bc = rest / 112;
    const float* p = in + (size_t)bc*(112*112*80) + h*80 + w;
    float s = 0.f;
    #pragma unroll 4
    for (int d = 0; d < 112; ++d) s += p[(size_t)d*(112*80)];
    out[idx] = s * (1.f/112.f);
}

__global__ void mean_h_k(const float* __restrict__ in, float* __restrict__ out) {
    int idx = blockIdx.x * 256 + threadIdx.x;
    constexpr int TOT = 2*32*112*80;
    if (idx >= TOT) return;
    int w = idx % 80, rest = idx / 80;
    int d = rest % 112, bc = rest / 112;
    const float* p = in + (size_t)bc*(112*112*80) + (size_t)d*(112*80) + w;
    float s = 0.f;
    #pragma unroll 4
    for (int h = 0; h < 112; ++h) s += p[h*80];
    out[idx] = s * (1.f/112.f);
}

__global__ void mean_w_k(const float* __restrict__ in, float* __restrict__ out) {
    int idx = blockIdx.x * 256 + threadIdx.x;
    constexpr int TOT = 2*32*112*112;
    if (idx >= TOT) return;
    int h = idx % 112, rest = idx / 112;
    int d = rest % 112, bc = rest / 112;
    const float4* p = reinterpret_cast<const float4*>(
        in + (size_t)bc*(112*112*80) + (size_t)d*(112*80) + (size_t)h*80);
    float s = 0.f;
    #pragma unroll
    for (int i = 0; i < 20; ++i) { float4 v = p[i]; s += v.x+v.y+v.z+v.w; }
    out[idx] = s * (1.f/80.f);
}

// ============ patchify -> bf16 ============
__global__ void patchify_k(const float* __restrict__ v2d, unsigned short* __restrict__ P,
                           int p1, int p2, int PD) {
    int idx = blockIdx.x * 256 + threadIdx.x;
    int total = 2*256*PD;
    if (idx >= total) return;
    int f = idx % PD, bn = idx / PD;
    int n = bn & 255, b = bn >> 8;
    int c = f & 31, pp = f >> 5;
    int pp2 = pp % p2, pp1 = pp / p2;
    int ww = n & 15, hh = n >> 4;
    int Ht = 16*p1, Wt = 16*p2;
    P[idx] = f2bf(v2d[(((size_t)b*32 + c)*Ht + hh*p1 + pp1)*Wt + ww*p2 + pp2]);
}

// ============ f32 [K][N] -> bf16 [N][K] transpose-convert ============
__global__ __launch_bounds__(256) void transp_cvt(const float* __restrict__ in,
                                                  unsigned short* __restrict__ out,
                                                  int K, int N) {
    __shared__ float tl[32][33];
    int k0 = blockIdx.y*32, n0 = blockIdx.x*32;
    int t = threadIdx.x;
    int r = t >> 5, c = t & 31;
    #pragma unroll
    for (int i = 0; i < 4; ++i) tl[r + i*8][c] = in[(long)(k0 + r + i*8)*N + n0 + c];
    __syncthreads();
    #pragma unroll
    for (int i = 0; i < 4; ++i) out[(long)(n0 + r + i*8)*K + k0 + c] = f2bf(tl[c][r + i*8]);
}

__global__ void cvt_k(const float* __restrict__ in, unsigned short* __restrict__ out, int n) {
    int i = blockIdx.x*256 + threadIdx.x;
    if (i < n) out[i] = f2bf(in[i]);
}

// ============ bf16 MFMA GEMM: C = A(MxK) @ Bt(NxK)^T + epilogue ============
// mode 0: plain (blockIdx.z==0). mode 1: attn QK^T batched over 72 heads.
// mode 2: attn PV batched over 72 heads.
__global__ __launch_bounds__(256) void gemm_bf(
    const unsigned short* __restrict__ A, const unsigned short* __restrict__ Bt,
    float* __restrict__ Cf, unsigned short* __restrict__ Cb,
    int M, int N, int K, int lda, int ldb, int ldc,
    const float* __restrict__ bias, const float* __restrict__ pos,
    const float* __restrict__ resid, int act, float cscale, int mode)
{
    __shared__ unsigned short As[64][40];
    __shared__ unsigned short Bs[64][40];
    const unsigned short* Ab = A;
    const unsigned short* Bb = Bt;
    long coff = 0;
    int z = blockIdx.z;
    if (mode == 1) {           // A=Q rows, B=K rows (as Bt), C=S[z]
        long o = (long)(z / 12) * 196608 + (long)(z % 12) * 64;
        Ab += o; Bb += o; coff = (long)z * 65536;
    } else if (mode == 2) {    // A=P[z], B=Vt[z], C=O rows
        Ab += (long)z * 65536; Bb += (long)z * 16384;
        coff = (long)(z / 12) * 196608 + (long)(z % 12) * 64;
    }
    int t = threadIdx.x;
    int m0 = blockIdx.y * 64, n0 = blockIdx.x * 64;
    int wave = t >> 6, lane = t & 63;
    int wr = wave >> 1, wc = wave & 1;
    int lrow = lane & 15, lk = (lane >> 4) * 8;
    f4 acc[2][2];
    #pragma unroll
    for (int m = 0; m < 2; ++m)
        #pragma unroll
        for (int n = 0; n < 2; ++n)
            #pragma unroll
            for (int r = 0; r < 4; ++r) acc[m][n][r] = 0.f;
    int srow = t >> 2, sc = (t & 3) * 8;
    for (int k0 = 0; k0 < K; k0 += 32) {
        s8 av, bv;
        #pragma unroll
        for (int i = 0; i < 8; ++i) { av[i] = 0; bv[i] = 0; }
        if (m0 + srow < M) av = *reinterpret_cast<const s8*>(Ab + (long)(m0 + srow)*lda + k0 + sc);
        if (n0 + srow < N) bv = *reinterpret_cast<const s8*>(Bb + (long)(n0 + srow)*ldb + k0 + sc);
        *reinterpret_cast<s8*>(&As[srow][sc]) = av;
        *reinterpret_cast<s8*>(&Bs[srow][sc]) = bv;
        __syncthreads();
        s8 af0 = *reinterpret_cast<const s8*>(&As[wr*32 + lrow][lk]);
        s8 af1 = *reinterpret_cast<const s8*>(&As[wr*32 + 16 + lrow][lk]);
        s8 bg0 = *reinterpret_cast<const s8*>(&Bs[wc*32 + lrow][lk]);
        s8 bg1 = *reinterpret_cast<const s8*>(&Bs[wc*32 + 16 + lrow][lk]);
        acc[0][0] = __builtin_amdgcn_mfma_f32_16x16x32_bf16(af0, bg0, acc[0][0], 0, 0, 0);
        acc[0][1] = __builtin_amdgcn_mfma_f32_16x16x32_bf16(af0, bg1, acc[0][1], 0, 0, 0);
        acc[1][0] = __builtin_amdgcn_mfma_f32_16x16x32_bf16(af1, bg0, acc[1][0], 0, 0, 0);
        acc[1][1] = __builtin_amdgcn_mfma_f32_16x16x32_bf16(af1, bg1, acc[1][1], 0, 0, 0);
        __syncthreads();
    }
    #pragma unroll
    for (int m = 0; m < 2; ++m) {
        int rbase = m0 + wr*32 + m*16 + (lane >> 4) * 4;
        #pragma unroll
        for (int n = 0; n < 2; ++n) {
            int col = n0 + wc*32 + n*16 + (lane & 15);
            if (col >= N) continue;
            #pragma unroll
            for (int r = 0; r < 4; ++r) {
                int row = rbase + r;
                if (row >= M) continue;
                float v = acc[m][n][r];
                if (bias)  v += bias[col];
                if (pos)   v += pos[(long)(row & 255) * N + col];
                if (resid) v += resid[(long)row * ldc + col];
                if (act == 1) v = 0.5f * v * (1.0f + erff(v * 0.70710678118654752f));
                v *= cscale;
                long ci = coff + (long)row * ldc + col;
                if (Cf) Cf[ci] = v;
                if (Cb) Cb[ci] = f2bf(v);
            }
        }
    }
}

// ============ LayerNorm rows of 768, fp32 in, fp32 + optional bf16 out ============
__global__ __launch_bounds__(256) void ln_k(const float* __restrict__ in,
                                            float* __restrict__ outf,
                                            unsigned short* __restrict__ outb,
                                            const float* __restrict__ g,
                                            const float* __restrict__ bta) {
    constexpr int N = 768;
    int row = blockIdx.x;
    const float* x = in + (size_t)row * N;
    int t = threadIdx.x;
    float v0 = x[t], v1 = x[t+256], v2 = x[t+512];
    float s = v0+v1+v2, s2 = v0*v0+v1*v1+v2*v2;
    #pragma unroll
    for (int off = 32; off > 0; off >>= 1) { s += __shfl_down(s, off); s2 += __shfl_down(s2, off); }
    __shared__ float red[8];
    int wid = t >> 6, lane = t & 63;
    if (lane == 0) { red[wid] = s; red[wid+4] = s2; }
    __syncthreads();
    if (t == 0) {
        float S = red[0]+red[1]+red[2]+red[3];
        float S2 = red[4]+red[5]+red[6]+red[7];
        float mean = S * (1.f/N);
        float var = S2 * (1.f/N) - mean*mean;
        red[0] = mean; red[1] = rsqrtf(var + 1e-5f);
    }
    __syncthreads();
    float mean = red[0], rstd = red[1];
    float y0 = (v0-mean)*rstd*g[t]     + bta[t];
    float y1 = (v1-mean)*rstd*g[t+256] + bta[t+256];
    float y2 = (v2-mean)*rstd*g[t+512] + bta[t+512];
    if (outf) {
        float* y = outf + (size_t)row * N;
        y[t] = y0; y[t+256] = y1; y[t+512] = y2;
    }
    if (outb) {
        unsigned short* y = outb + (size_t)row * N;
        y[t] = f2bf(y0); y[t+256] = f2bf(y1); y[t+512] = f2bf(y2);
    }
}

// ============ V transpose per head: Vt[z][d][j] = Vb[(z/12*256+j)*768 + (z%12)*64 + d] ============
__global__ void vt_k(const unsigned short* __restrict__ V, unsigned short* __restrict__ Vt) {
    int idx = blockIdx.x*256 + threadIdx.x;      // over 72*64*256
    if (idx >= 72*64*256) return;
    int j = idx & 255, rest = idx >> 8;
    int d = rest & 63, z = rest >> 6;
    Vt[idx] = V[((long)(z/12)*256 + j)*768 + (long)(z%12)*64 + d];
}

// ============ row softmax on S[72*256][256] -> bf16 P ============
__global__ __launch_bounds__(256) void softmax_k(const float* __restrict__ S,
                                                 unsigned short* __restrict__ P) {
    int row = blockIdx.x*4 + (threadIdx.x >> 6);
    int lane = threadIdx.x & 63;
    const float4 v = *reinterpret_cast<const float4*>(S + (long)row*256 + lane*4);
    float m = fmaxf(fmaxf(v.x, v.y), fmaxf(v.z, v.w));
    #pragma unroll
    for (int o = 32; o; o >>= 1) m = fmaxf(m, __shfl_xor(m, o));
    float p0 = __expf(v.x - m), p1 = __expf(v.y - m), p2 = __expf(v.z - m), p3 = __expf(v.w - m);
    float l = p0 + p1 + p2 + p3;
    #pragma unroll
    for (int o = 32; o; o >>= 1) l += __shfl_xor(l, o);
    float inv = 1.f / l;
    unsigned b0 = f2bf(p0*inv), b1 = f2bf(p1*inv), b2 = f2bf(p2*inv), b3 = f2bf(p3*inv);
    uint2 pk; pk.x = b0 | (b1 << 16); pk.y = b2 | (b3 << 16);
    *reinterpret_cast<uint2*>(P + (long)row*256 + lane*4) = pk;
}

// ============ cross-attn colsum weights, batched over 72 (rowblk,h) ============
__global__ __launch_bounds__(256) void ca_w_k(const float* __restrict__ QH,
                                              const float* __restrict__ KH,
                                              float* __restrict__ Wout) {
    int bh = blockIdx.x;
    int rowblk = bh / 12, h = bh % 12, b = rowblk & 1;
    __shared__ float qs[77*64];
    __shared__ float red[8];
    int t = threadIdx.x;
    for (int idx = t; idx < 77*64; idx += 256) {
        int i = idx >> 6, c = idx & 63;
        qs[idx] = QH[((long)(b*77 + i))*768 + h*64 + c];
    }
    __syncthreads();
    float kx[64];
    {
        const float4* kp = reinterpret_cast<const float4*>(KH + ((long)(rowblk*256 + t))*768 + h*64);
        #pragma unroll
        for (int i = 0; i < 16; ++i) {
            float4 v = kp[i];
            kx[4*i] = v.x; kx[4*i+1] = v.y; kx[4*i+2] = v.z; kx[4*i+3] = v.w;
        }
    }
    int wid = t >> 6, lane = t & 63;
    float w = 0.f;
    for (int i = 0; i < 77; ++i) {
        float s = 0.f;
        #pragma unroll
        for (int c = 0; c < 64; ++c) s += qs[i*64 + c] * kx[c];
        s *= 0.125f;
        float m = s;
        #pragma unroll
        for (int o = 32; o; o >>= 1) m = fmaxf(m, __shfl_xor(m, o));
        if (lane == 0) red[wid] = m;
        __syncthreads();
        m = fmaxf(fmaxf(red[0], red[1]), fmaxf(red[2], red[3]));
        float p = __expf(s - m);
        float l = p;
        #pragma unroll
        for (int o = 32; o; o >>= 1) l += __shfl_xor(l, o);
        if (lane == 0) red[4 + wid] = l;
        __syncthreads();
        l = red[4] + red[5] + red[6] + red[7];
        w += p / l;
        __syncthreads();
    }
    Wout[(long)bh*256 + t] = w;
}

// ============ O[row,col] = W[rowblk,h,j] * VH[row,col]  (bf16 out) ============
__global__ void ca_apply_k(const float* __restrict__ W, const float* __restrict__ VH,
                           unsigned short* __restrict__ O) {
    int idx = blockIdx.x*256 + threadIdx.x;
    if (idx >= 1536*768) return;
    int row = idx / 768, col = idx - row*768;
    int rowblk = row >> 8, j = row & 255, h = col >> 6;
    O[idx] = f2bf(W[((long)rowblk*12 + h)*256 + j] * VH[idx]);
}

// ============ final combine ============
__global__ void final_k(const float* __restrict__ img, const float* __restrict__ yax,
                        const float* __restrict__ ysag, const float* __restrict__ ycor,
                        const float* __restrict__ vw, float* __restrict__ out) {
    size_t idx = (size_t)blockIdx.x*256 + threadIdx.x;
    constexpr size_t TOT = (size_t)2*32*112*112*80;
    if (idx >= TOT) return;
    int w = (int)(idx % 80); size_t r = idx / 80;
    int h = (int)(r % 112); r /= 112;
    int d = (int)(r % 112); r /= 112;
    int c = (int)(r % 32);  int b = (int)(r / 32);
    float a  = yax [((size_t)(b*256 + (h/7)*16 + w/5))*1120 + (size_t)((h%7)*5 + (w%5))*32 + c];
    float sg = ysag[((size_t)(b*256 + (d/7)*16 + w/5))*1120 + (size_t)((d%7)*5 + (w%5))*32 + c];
    float co = ycor[((size_t)(b*256 + (d/7)*16 + h/7))*1568 + (size_t)((d%7)*7 + (h%7))*32 + c];
    out[idx] = img[idx] + vw[0]*a + vw[1]*sg + vw[2]*co;
}

extern "C" void kernel_launch(void* const* d_in, const int* in_sizes, int n_in,
                              void* d_out, int out_size, void* d_ws, size_t ws_size,
                              hipStream_t stream) {
    (void)in_sizes; (void)n_in; (void)out_size; (void)ws_size;
    const float* img    = (const float*)d_in[0];
    const float* txt    = (const float*)d_in[1];
    const float* pe_w[3] = {(const float*)d_in[2], (const float*)d_in[4], (const float*)d_in[6]};
    const float* pe_b[3] = {(const float*)d_in[3], (const float*)d_in[5], (const float*)d_in[7]};
    const float* pos[3]  = {(const float*)d_in[8], (const float*)d_in[9], (const float*)d_in[10]};
    const float* qw = (const float*)d_in[11];
    const float* kw = (const float*)d_in[12];
    const float* vw_attn = (const float*)d_in[13];
    const float* pw = (const float*)d_in[14];
    const float* pb = (const float*)d_in[15];
    const float* caq_w = (const float*)d_in[16];
    const float* caq_b = (const float*)d_in[17];
    const float* cak_w = (const float*)d_in[18];
    const float* cak_b = (const float*)d_in[19];
    const float* cav_w = (const float*)d_in[20];
    const float* cav_b = (const float*)d_in[21];
    const float* cao_w = (const float*)d_in[22];
    const float* cao_b = (const float*)d_in[23];
    const float* mlp_w1 = (const float*)d_in[24];
    const float* mlp_b1 = (const float*)d_in[25];
    const float* mlp_w2 = (const float*)d_in[26];
    const float* mlp_b2 = (const float*)d_in[27];
    const float* ow[3] = {(const float*)d_in[28], (const float*)d_in[30], (const float*)d_in[32]};
    const float* ob[3] = {(const float*)d_in[29], (const float*)d_in[31], (const float*)d_in[33]};
    const float* view_w = (const float*)d_in[34];
    const float* n_g[3] = {(const float*)d_in[35], (const float*)d_in[36], (const float*)d_in[37]};
    const float* n_b[3] = {(const float*)d_in[38], (const float*)d_in[39], (const float*)d_in[40]};

    typedef unsigned short u16;
    // ---- big scratch lives in d_out (fully rewritten by final_k) ----
    unsigned char* sb = (unsigned char*)d_out;
    size_t off = 0;
    auto B = [&](size_t bytes) -> void* {
        void* p = sb + off; off += (bytes + 511) & ~(size_t)511; return p;
    };
    u16* qwT  = (u16*)B(768*768*2);
    u16* kwT  = (u16*)B(768*768*2);
    u16* vwT  = (u16*)B(768*768*2);
    u16* pwT  = (u16*)B(768*768*2);
    u16* caqT = (u16*)B(768*768*2);
    u16* cakT = (u16*)B(768*768*2);
    u16* cavT = (u16*)B(768*768*2);
    u16* caoT = (u16*)B(768*768*2);
    u16* mlp1T = (u16*)B((size_t)3072*768*2);
    u16* mlp2T = (u16*)B((size_t)768*3072*2);
    u16* peT[3]; peT[0] = (u16*)B((size_t)768*1120*2); peT[1] = (u16*)B((size_t)768*1120*2); peT[2] = (u16*)B((size_t)768*1568*2);
    u16* owT[3]; owT[0] = (u16*)B((size_t)1120*768*2); owT[1] = (u16*)B((size_t)1120*768*2); owT[2] = (u16*)B((size_t)1568*768*2);
    u16* txtb = (u16*)B(154*768*2);
    float* m_ax  = (float*)B(573440*4);
    float* m_sag = (float*)B(573440*4);
    float* m_cor = (float*)B(802816*4);
    u16* Pb = (u16*)B((size_t)512*1568*2);
    float* X0  = (float*)B((size_t)1536*768*4);
    float* X1f = (float*)B((size_t)1536*768*4);
    float* X2  = (float*)B((size_t)1536*768*4);
    float* X3f = (float*)B((size_t)1536*768*4);
    float* X4  = (float*)B((size_t)1536*768*4);
    u16* X1b = (u16*)B((size_t)1536*768*2);
    u16* X3b = (u16*)B((size_t)1536*768*2);
    u16* X5b = (u16*)B((size_t)1536*768*2);
    u16* X6b = (u16*)B((size_t)1536*768*2);
    u16* Qbf = (u16*)B((size_t)1536*768*2);
    u16* Kbf = (u16*)B((size_t)1536*768*2);
    u16* Vbf = (u16*)B((size_t)1536*768*2);
    u16* Obf = (u16*)B((size_t)1536*768*2);
    u16* Vt  = (u16*)B((size_t)72*64*256*2);
    u16* Hb  = (u16*)B((size_t)1536*3072*2);
    float* S  = (float*)B((size_t)72*256*256*4);
    u16* Pat = (u16*)B((size_t)72*256*256*2);
    float* KHf = (float*)B((size_t)1536*768*4);
    float* VHf = (float*)B((size_t)1536*768*4);
    float* QHf = (float*)B((size_t)154*768*4);
    float* Wb  = (float*)B((size_t)72*256*4);

    // ---- Y lives in d_ws (read by final_k while it writes d_out) ----
    float* ws = (float*)d_ws;
    float* Y[3]; Y[0] = ws; Y[1] = ws + 573440; Y[2] = ws + 1146880;

    auto tc = [&](const float* in, u16* out, int K, int N) {
        dim3 g(N/32, K/32);
        transp_cvt<<<g, 256, 0, stream>>>(in, out, K, N);
    };
    // weights: in [K][N] -> out [N][K]
    tc(qw, qwT, 768, 768); tc(kw, kwT, 768, 768); tc(vw_attn, vwT, 768, 768); tc(pw, pwT, 768, 768);
    tc(caq_w, caqT, 768, 768); tc(cak_w, cakT, 768, 768); tc(cav_w, cavT, 768, 768); tc(cao_w, caoT, 768, 768);
    tc(mlp_w1, mlp1T, 768, 3072); tc(mlp_w2, mlp2T, 3072, 768);
    tc(pe_w[0], peT[0], 1120, 768); tc(pe_w[1], peT[1], 1120, 768); tc(pe_w[2], peT[2], 1568, 768);
    tc(ow[0], owT[0], 768, 1120); tc(ow[1], owT[1], 768, 1120); tc(ow[2], owT[2], 768, 1568);
    cvt_k<<<(154*768 + 255)/256, 256, 0, stream>>>(txt, txtb, 154*768);

    mean_d_k<<<(573440+255)/256, 256, 0, stream>>>(img, m_ax);
    mean_h_k<<<(573440+255)/256, 256, 0, stream>>>(img, m_sag);
    mean_w_k<<<(802816+255)/256, 256, 0, stream>>>(img, m_cor);

    auto gemm = [&](const u16* A, const u16* Bt, float* Cf, u16* Cb,
                    int M, int N, int K, int lda, int ldb, int ldc,
                    const float* bias, const float* posp, const float* resid,
                    int act, float cscale, int mode, int batch) {
        dim3 g((N+63)/64, (M+63)/64, batch);
        gemm_bf<<<g, 256, 0, stream>>>(A, Bt, Cf, Cb, M, N, K, lda, ldb, ldc,
                                       bias, posp, resid, act, cscale, mode);
    };

    // QH = txt @ caq_w + caq_b  (154x768)
    gemm(txtb, caqT, QHf, nullptr, 154, 768, 768, 768, 768, 768,
         caq_b, nullptr, nullptr, 0, 1.f, 0, 1);

    // per-branch patchify + embed into batched X0 (1536x768)
    const float* v2d[3] = {m_ax, m_sag, m_cor};
    const int p1a[3] = {7,7,7}, p2a[3] = {5,5,7};
    const int PDa[3] = {1120,1120,1568};
    for (int br = 0; br < 3; ++br) {
        int PD = PDa[br];
        patchify_k<<<(2*256*PD+255)/256, 256, 0, stream>>>(v2d[br], Pb, p1a[br], p2a[br], PD);
        gemm(Pb, peT[br], X0 + (size_t)br*512*768, nullptr, 512, 768, PD, PD, PD, 768,
             pe_b[br], pos[br], nullptr, 0, 1.f, 0, 1);
    }

    // batched trunk (M = 1536)
    ln_k<<<1536, 256, 0, stream>>>(X0, X1f, X1b, n_g[0], n_b[0]);
    gemm(X1b, qwT, nullptr, Qbf, 1536, 768, 768, 768, 768, 768, nullptr, nullptr, nullptr, 0, 0.125f, 0, 1);
    gemm(X1b, kwT, nullptr, Kbf, 1536, 768, 768, 768, 768, 768, nullptr, nullptr, nullptr, 0, 1.f, 0, 1);
    gemm(X1b, vwT, nullptr, Vbf, 1536, 768, 768, 768, 768, 768, nullptr, nullptr, nullptr, 0, 1.f, 0, 1);
    vt_k<<<(72*64*256 + 255)/256, 256, 0, stream>>>(Vbf, Vt);
    // S = Q K^T (per head), softmax, O = P V
    gemm(Qbf, Kbf, S, nullptr, 256, 256, 64, 768, 768, 256, nullptr, nullptr, nullptr, 0, 1.f, 1, 72);
    softmax_k<<<72*256/4, 256, 0, stream>>>(S, Pat);
    gemm(Pat, Vt, nullptr, Obf, 256, 64, 256, 256, 256, 768, nullptr, nullptr, nullptr, 0, 1.f, 2, 72);
    gemm(Obf, pwT, X2, nullptr, 1536, 768, 768, 768, 768, 768, pb, nullptr, X1f, 0, 1.f, 0, 1);
    ln_k<<<1536, 256, 0, stream>>>(X2, X3f, X3b, n_g[1], n_b[1]);
    // cross-attention
    gemm(X3b, cakT, KHf, nullptr, 1536, 768, 768, 768, 768, 768, cak_b, nullptr, nullptr, 0, 1.f, 0, 1);
    gemm(X3b, cavT, VHf, nullptr, 1536, 768, 768, 768, 768, 768, cav_b, nullptr, nullptr, 0, 1.f, 0, 1);
    ca_w_k<<<72, 256, 0, stream>>>(QHf, KHf, Wb);
    ca_apply_k<<<(1536*768 + 255)/256, 256, 0, stream>>>(Wb, VHf, Obf);
    gemm(Obf, caoT, X4, nullptr, 1536, 768, 768, 768, 768, 768, cao_b, nullptr, X3f, 0, 1.f, 0, 1);
    ln_k<<<1536, 256, 0, stream>>>(X4, nullptr, X5b, n_g[2], n_b[2]);
    // MLP
    gemm(X5b, mlp1T, nullptr, Hb, 1536, 3072, 768, 768, 768, 3072, mlp_b1, nullptr, nullptr, 1, 1.f, 0, 1);
    gemm(Hb, mlp2T, nullptr, X6b, 1536, 768, 3072, 3072, 3072, 768, mlp_b2, nullptr, X4, 0, 1.f, 0, 1);
    // output projections
    for (int br = 0; br < 3; ++br) {
        int PD = PDa[br];
        gemm(X6b + (size_t)br*512*768, owT[br], Y[br], nullptr, 512, PD, 768, 768, 768, PD,
             ob[br], nullptr, nullptr, 0, 1.f, 0, 1);
    }

    final_k<<<(int)((64225280ULL + 255)/256), 256, 0, stream>>>(
        img, Y[0], Y[1], Y[2], view_w, (float*)d_out);
}

// Round 3
// 1138.463 us; speedup vs baseline: 6.7463x; 1.0856x over previous
//
#include <hip/hip_runtime.h>
#include <math.h>

typedef __attribute__((ext_vector_type(8))) short s8;
typedef __attribute__((ext_vector_type(4))) float f4;

__device__ inline unsigned short f2bf(float f) {
    unsigned u = __float_as_uint(f);
    u += 0x7fffu + ((u >> 16) & 1u);
    return (unsigned short)(u >> 16);
}

// ============ fused axis means: one pass over img (2,32,112,112,80) ============
// grid 256: blk = bc*4 + dc (bc in [0,64), dc in [0,4) -> d-range 28)
// ax (b,c,h,w): global atomicAdd partial sums over d (pre-zeroed; scaled later in patchify)
// sag (b,c,d,w): complete within block (sum over h), scaled here
// cor (b,c,d,h): complete within block (sum over w), scaled here
__global__ __launch_bounds__(256) void mean3_k(const float* __restrict__ img,
                                               float* __restrict__ ax,
                                               float* __restrict__ sag,
                                               float* __restrict__ cor) {
    __shared__ float sag_l[2240];
    __shared__ float cor_l[3136];
    int blk = blockIdx.x;
    int dc = blk & 3, bc = blk >> 2;
    int d0 = dc * 28;
    int t = threadIdx.x;
    for (int i = t; i < 2240; i += 256) sag_l[i] = 0.f;
    for (int i = t; i < 3136; i += 256) cor_l[i] = 0.f;
    __syncthreads();
    const float* base = img + (size_t)bc * (112*112*80);
    float* axg = ax + (size_t)bc * 8960;
    for (int p = t; p < 2240; p += 256) {
        int h = p / 20, w4 = p % 20;
        float ax0 = 0.f, ax1 = 0.f, ax2 = 0.f, ax3 = 0.f;
        #pragma unroll 4
        for (int d = 0; d < 28; ++d) {
            const float4 v = *reinterpret_cast<const float4*>(
                base + ((size_t)(d0 + d)*112 + h)*80 + w4*4);
            ax0 += v.x; ax1 += v.y; ax2 += v.z; ax3 += v.w;
            atomicAdd(&sag_l[d*80 + w4*4 + 0], v.x);
            atomicAdd(&sag_l[d*80 + w4*4 + 1], v.y);
            atomicAdd(&sag_l[d*80 + w4*4 + 2], v.z);
            atomicAdd(&sag_l[d*80 + w4*4 + 3], v.w);
            atomicAdd(&cor_l[d*112 + h], v.x + v.y + v.z + v.w);
        }
        int o = h*80 + w4*4;
        atomicAdd(&axg[o+0], ax0);
        atomicAdd(&axg[o+1], ax1);
        atomicAdd(&axg[o+2], ax2);
        atomicAdd(&axg[o+3], ax3);
    }
    __syncthreads();
    float* sagg = sag + ((size_t)bc*112 + d0)*80;
    for (int i = t; i < 2240; i += 256) sagg[i] = sag_l[i] * (1.f/112.f);
    float* corg = cor + ((size_t)bc*112 + d0)*112;
    for (int i = t; i < 3136; i += 256) corg[i] = cor_l[i] * (1.f/80.f);
}

// ============ patchify -> bf16 (with scale; ax needs 1/112 post-atomic scale) ============
__global__ void patchify_k(const float* __restrict__ v2d, unsigned short* __restrict__ P,
                           int p1, int p2, int PD, float scale) {
    int idx = blockIdx.x * 256 + threadIdx.x;
    int total = 2*256*PD;
    if (idx >= total) return;
    int f = idx % PD, bn = idx / PD;
    int n = bn & 255, b = bn >> 8;
    int c = f & 31, pp = f >> 5;
    int pp2 = pp % p2, pp1 = pp / p2;
    int ww = n & 15, hh = n >> 4;
    int Ht = 16*p1, Wt = 16*p2;
    P[idx] = f2bf(scale * v2d[(((size_t)b*32 + c)*Ht + hh*p1 + pp1)*Wt + ww*p2 + pp2]);
}

// ============ f32 [K][N] -> bf16 [N][K] transpose-convert ============
__global__ __launch_bounds__(256) void transp_cvt(const float* __restrict__ in,
                                                  unsigned short* __restrict__ out,
                                                  int K, int N) {
    __shared__ float tl[32][33];
    int k0 = blockIdx.y*32, n0 = blockIdx.x*32;
    int t = threadIdx.x;
    int r = t >> 5, c = t & 31;
    #pragma unroll
    for (int i = 0; i < 4; ++i) tl[r + i*8][c] = in[(long)(k0 + r + i*8)*N + n0 + c];
    __syncthreads();
    #pragma unroll
    for (int i = 0; i < 4; ++i) out[(long)(n0 + r + i*8)*K + k0 + c] = f2bf(tl[c][r + i*8]);
}

__global__ void cvt_k(const float* __restrict__ in, unsigned short* __restrict__ out, int n) {
    int i = blockIdx.x*256 + threadIdx.x;
    if (i < n) out[i] = f2bf(in[i]);
}

// ============ bf16 MFMA GEMM: C = A(MxK) @ Bt(NxK)^T + epilogue ============
__global__ __launch_bounds__(256) void gemm_bf(
    const unsigned short* __restrict__ A, const unsigned short* __restrict__ Bt,
    float* __restrict__ Cf, unsigned short* __restrict__ Cb,
    int M, int N, int K, int lda, int ldb, int ldc,
    const float* __restrict__ bias, const float* __restrict__ pos,
    const float* __restrict__ resid, int act, float cscale, int mode)
{
    __shared__ unsigned short As[64][40];
    __shared__ unsigned short Bs[64][40];
    const unsigned short* Ab = A;
    const unsigned short* Bb = Bt;
    long coff = 0;
    int z = blockIdx.z;
    if (mode == 1) {
        long o = (long)(z / 12) * 196608 + (long)(z % 12) * 64;
        Ab += o; Bb += o; coff = (long)z * 65536;
    } else if (mode == 2) {
        Ab += (long)z * 65536; Bb += (long)z * 16384;
        coff = (long)(z / 12) * 196608 + (long)(z % 12) * 64;
    }
    int t = threadIdx.x;
    int m0 = blockIdx.y * 64, n0 = blockIdx.x * 64;
    int wave = t >> 6, lane = t & 63;
    int wr = wave >> 1, wc = wave & 1;
    int lrow = lane & 15, lk = (lane >> 4) * 8;
    f4 acc[2][2];
    #pragma unroll
    for (int m = 0; m < 2; ++m)
        #pragma unroll
        for (int n = 0; n < 2; ++n)
            #pragma unroll
            for (int r = 0; r < 4; ++r) acc[m][n][r] = 0.f;
    int srow = t >> 2, sc = (t & 3) * 8;
    for (int k0 = 0; k0 < K; k0 += 32) {
        s8 av, bv;
        #pragma unroll
        for (int i = 0; i < 8; ++i) { av[i] = 0; bv[i] = 0; }
        if (m0 + srow < M) av = *reinterpret_cast<const s8*>(Ab + (long)(m0 + srow)*lda + k0 + sc);
        if (n0 + srow < N) bv = *reinterpret_cast<const s8*>(Bb + (long)(n0 + srow)*ldb + k0 + sc);
        *reinterpret_cast<s8*>(&As[srow][sc]) = av;
        *reinterpret_cast<s8*>(&Bs[srow][sc]) = bv;
        __syncthreads();
        s8 af0 = *reinterpret_cast<const s8*>(&As[wr*32 + lrow][lk]);
        s8 af1 = *reinterpret_cast<const s8*>(&As[wr*32 + 16 + lrow][lk]);
        s8 bg0 = *reinterpret_cast<const s8*>(&Bs[wc*32 + lrow][lk]);
        s8 bg1 = *reinterpret_cast<const s8*>(&Bs[wc*32 + 16 + lrow][lk]);
        acc[0][0] = __builtin_amdgcn_mfma_f32_16x16x32_bf16(af0, bg0, acc[0][0], 0, 0, 0);
        acc[0][1] = __builtin_amdgcn_mfma_f32_16x16x32_bf16(af0, bg1, acc[0][1], 0, 0, 0);
        acc[1][0] = __builtin_amdgcn_mfma_f32_16x16x32_bf16(af1, bg0, acc[1][0], 0, 0, 0);
        acc[1][1] = __builtin_amdgcn_mfma_f32_16x16x32_bf16(af1, bg1, acc[1][1], 0, 0, 0);
        __syncthreads();
    }
    #pragma unroll
    for (int m = 0; m < 2; ++m) {
        int rbase = m0 + wr*32 + m*16 + (lane >> 4) * 4;
        #pragma unroll
        for (int n = 0; n < 2; ++n) {
            int col = n0 + wc*32 + n*16 + (lane & 15);
            if (col >= N) continue;
            #pragma unroll
            for (int r = 0; r < 4; ++r) {
                int row = rbase + r;
                if (row >= M) continue;
                float v = acc[m][n][r];
                if (bias)  v += bias[col];
                if (pos)   v += pos[(long)(row & 255) * N + col];
                if (resid) v += resid[(long)row * ldc + col];
                if (act == 1) v = 0.5f * v * (1.0f + erff(v * 0.70710678118654752f));
                v *= cscale;
                long ci = coff + (long)row * ldc + col;
                if (Cf) Cf[ci] = v;
                if (Cb) Cb[ci] = f2bf(v);
            }
        }
    }
}

// ============ LayerNorm rows of 768 ============
__global__ __launch_bounds__(256) void ln_k(const float* __restrict__ in,
                                            float* __restrict__ outf,
                                            unsigned short* __restrict__ outb,
                                            const float* __restrict__ g,
                                            const float* __restrict__ bta) {
    constexpr int N = 768;
    int row = blockIdx.x;
    const float* x = in + (size_t)row * N;
    int t = threadIdx.x;
    float v0 = x[t], v1 = x[t+256], v2 = x[t+512];
    float s = v0+v1+v2, s2 = v0*v0+v1*v1+v2*v2;
    #pragma unroll
    for (int off = 32; off > 0; off >>= 1) { s += __shfl_down(s, off); s2 += __shfl_down(s2, off); }
    __shared__ float red[8];
    int wid = t >> 6, lane = t & 63;
    if (lane == 0) { red[wid] = s; red[wid+4] = s2; }
    __syncthreads();
    if (t == 0) {
        float S = red[0]+red[1]+red[2]+red[3];
        float S2 = red[4]+red[5]+red[6]+red[7];
        float mean = S * (1.f/N);
        float var = S2 * (1.f/N) - mean*mean;
        red[0] = mean; red[1] = rsqrtf(var + 1e-5f);
    }
    __syncthreads();
    float mean = red[0], rstd = red[1];
    float y0 = (v0-mean)*rstd*g[t]     + bta[t];
    float y1 = (v1-mean)*rstd*g[t+256] + bta[t+256];
    float y2 = (v2-mean)*rstd*g[t+512] + bta[t+512];
    if (outf) {
        float* y = outf + (size_t)row * N;
        y[t] = y0; y[t+256] = y1; y[t+512] = y2;
    }
    if (outb) {
        unsigned short* y = outb + (size_t)row * N;
        y[t] = f2bf(y0); y[t+256] = f2bf(y1); y[t+512] = f2bf(y2);
    }
}

// ============ V transpose per head ============
__global__ void vt_k(const unsigned short* __restrict__ V, unsigned short* __restrict__ Vt) {
    int idx = blockIdx.x*256 + threadIdx.x;
    if (idx >= 72*64*256) return;
    int j = idx & 255, rest = idx >> 8;
    int d = rest & 63, z = rest >> 6;
    Vt[idx] = V[((long)(z/12)*256 + j)*768 + (long)(z%12)*64 + d];
}

// ============ row softmax on S[72*256][256] -> bf16 P ============
__global__ __launch_bounds__(256) void softmax_k(const float* __restrict__ S,
                                                 unsigned short* __restrict__ P) {
    int row = blockIdx.x*4 + (threadIdx.x >> 6);
    int lane = threadIdx.x & 63;
    const float4 v = *reinterpret_cast<const float4*>(S + (long)row*256 + lane*4);
    float m = fmaxf(fmaxf(v.x, v.y), fmaxf(v.z, v.w));
    #pragma unroll
    for (int o = 32; o; o >>= 1) m = fmaxf(m, __shfl_xor(m, o));
    float p0 = __expf(v.x - m), p1 = __expf(v.y - m), p2 = __expf(v.z - m), p3 = __expf(v.w - m);
    float l = p0 + p1 + p2 + p3;
    #pragma unroll
    for (int o = 32; o; o >>= 1) l += __shfl_xor(l, o);
    float inv = 1.f / l;
    unsigned b0 = f2bf(p0*inv), b1 = f2bf(p1*inv), b2 = f2bf(p2*inv), b3 = f2bf(p3*inv);
    uint2 pk; pk.x = b0 | (b1 << 16); pk.y = b2 | (b3 << 16);
    *reinterpret_cast<uint2*>(P + (long)row*256 + lane*4) = pk;
}

// ============ cross-attn colsum weights ============
__global__ __launch_bounds__(256) void ca_w_k(const float* __restrict__ QH,
                                              const float* __restrict__ KH,
                                              float* __restrict__ Wout) {
    int bh = blockIdx.x;
    int rowblk = bh / 12, h = bh % 12, b = rowblk & 1;
    __shared__ float qs[77*64];
    __shared__ float red[8];
    int t = threadIdx.x;
    for (int idx = t; idx < 77*64; idx += 256) {
        int i = idx >> 6, c = idx & 63;
        qs[idx] = QH[((long)(b*77 + i))*768 + h*64 + c];
    }
    __syncthreads();
    float kx[64];
    {
        const float4* kp = reinterpret_cast<const float4*>(KH + ((long)(rowblk*256 + t))*768 + h*64);
        #pragma unroll
        for (int i = 0; i < 16; ++i) {
            float4 v = kp[i];
            kx[4*i] = v.x; kx[4*i+1] = v.y; kx[4*i+2] = v.z; kx[4*i+3] = v.w;
        }
    }
    int wid = t >> 6, lane = t & 63;
    float w = 0.f;
    for (int i = 0; i < 77; ++i) {
        float s = 0.f;
        #pragma unroll
        for (int c = 0; c < 64; ++c) s += qs[i*64 + c] * kx[c];
        s *= 0.125f;
        float m = s;
        #pragma unroll
        for (int o = 32; o; o >>= 1) m = fmaxf(m, __shfl_xor(m, o));
        if (lane == 0) red[wid] = m;
        __syncthreads();
        m = fmaxf(fmaxf(red[0], red[1]), fmaxf(red[2], red[3]));
        float p = __expf(s - m);
        float l = p;
        #pragma unroll
        for (int o = 32; o; o >>= 1) l += __shfl_xor(l, o);
        if (lane == 0) red[4 + wid] = l;
        __syncthreads();
        l = red[4] + red[5] + red[6] + red[7];
        w += p / l;
        __syncthreads();
    }
    Wout[(long)bh*256 + t] = w;
}

// ============ O = W * VH (bf16 out) ============
__global__ void ca_apply_k(const float* __restrict__ W, const float* __restrict__ VH,
                           unsigned short* __restrict__ O) {
    int idx = blockIdx.x*256 + threadIdx.x;
    if (idx >= 1536*768) return;
    int row = idx / 768, col = idx - row*768;
    int rowblk = row >> 8, j = row & 255, h = col >> 6;
    O[idx] = f2bf(W[((long)rowblk*12 + h)*256 + j] * VH[idx]);
}

// ============ unpatchify Y (512 x PD) -> dense plane, pre-weighted by view_w ============
__global__ void unpatch_k(const float* __restrict__ y, float* __restrict__ A,
                          const float* __restrict__ vw, int vwi,
                          int Wd, int p2, int PD, int total) {
    int idx = blockIdx.x*256 + threadIdx.x;
    if (idx >= total) return;
    int w = idx % Wd; int r = idx / Wd;
    int h = r % 112; r /= 112;
    int c = r % 32; int b = r / 32;
    int src = (b*256 + (h/7)*16 + (w/p2))*PD + ((h%7)*p2 + (w%p2))*32 + c;
    A[idx] = vw[vwi] * y[src];
}

// ============ streaming final combine: per (b,c,d) slice, all coalesced float4 ============
__global__ __launch_bounds__(256) void final_k(const float* __restrict__ img,
                                               const float* __restrict__ Aax,
                                               const float* __restrict__ Asag,
                                               const float* __restrict__ Acor,
                                               float* __restrict__ out) {
    int blk = blockIdx.x;                 // bc*112 + d
    int bc = blk / 112;
    const float4* ip = reinterpret_cast<const float4*>(img + (size_t)blk * 8960);
    const float4* ap = reinterpret_cast<const float4*>(Aax + (size_t)bc * 8960);
    const float4* sp = reinterpret_cast<const float4*>(Asag + (size_t)blk * 80);
    const float*  cp = Acor + (size_t)blk * 112;
    float4* op = reinterpret_cast<float4*>(out + (size_t)blk * 8960);
    int t = threadIdx.x;
    for (int q = t; q < 2240; q += 256) {
        int h = q / 20, w4 = q % 20;
        float4 iv = ip[q], av = ap[q], sv = sp[w4];
        float cv = cp[h];
        float4 o;
        o.x = iv.x + av.x + sv.x + cv;
        o.y = iv.y + av.y + sv.y + cv;
        o.z = iv.z + av.z + sv.z + cv;
        o.w = iv.w + av.w + sv.w + cv;
        op[q] = o;
    }
}

extern "C" void kernel_launch(void* const* d_in, const int* in_sizes, int n_in,
                              void* d_out, int out_size, void* d_ws, size_t ws_size,
                              hipStream_t stream) {
    (void)in_sizes; (void)n_in; (void)out_size; (void)ws_size;
    const float* img    = (const float*)d_in[0];
    const float* txt    = (const float*)d_in[1];
    const float* pe_w[3] = {(const float*)d_in[2], (const float*)d_in[4], (const float*)d_in[6]};
    const float* pe_b[3] = {(const float*)d_in[3], (const float*)d_in[5], (const float*)d_in[7]};
    const float* pos[3]  = {(const float*)d_in[8], (const float*)d_in[9], (const float*)d_in[10]};
    const float* qw = (const float*)d_in[11];
    const float* kw = (const float*)d_in[12];
    const float* vw_attn = (const float*)d_in[13];
    const float* pw = (const float*)d_in[14];
    const float* pb = (const float*)d_in[15];
    const float* caq_w = (const float*)d_in[16];
    const float* caq_b = (const float*)d_in[17];
    const float* cak_w = (const float*)d_in[18];
    const float* cak_b = (const float*)d_in[19];
    const float* cav_w = (const float*)d_in[20];
    const float* cav_b = (const float*)d_in[21];
    const float* cao_w = (const float*)d_in[22];
    const float* cao_b = (const float*)d_in[23];
    const float* mlp_w1 = (const float*)d_in[24];
    const float* mlp_b1 = (const float*)d_in[25];
    const float* mlp_w2 = (const float*)d_in[26];
    const float* mlp_b2 = (const float*)d_in[27];
    const float* ow[3] = {(const float*)d_in[28], (const float*)d_in[30], (const float*)d_in[32]};
    const float* ob[3] = {(const float*)d_in[29], (const float*)d_in[31], (const float*)d_in[33]};
    const float* view_w = (const float*)d_in[34];
    const float* n_g[3] = {(const float*)d_in[35], (const float*)d_in[36], (const float*)d_in[37]};
    const float* n_b[3] = {(const float*)d_in[38], (const float*)d_in[39], (const float*)d_in[40]};

    typedef unsigned short u16;
    // ---- big scratch lives in d_out (fully rewritten by final_k) ----
    unsigned char* sb = (unsigned char*)d_out;
    size_t off = 0;
    auto B = [&](size_t bytes) -> void* {
        void* p = sb + off; off += (bytes + 511) & ~(size_t)511; return p;
    };
    u16* qwT  = (u16*)B(768*768*2);
    u16* kwT  = (u16*)B(768*768*2);
    u16* vwT  = (u16*)B(768*768*2);
    u16* pwT  = (u16*)B(768*768*2);
    u16* caqT = (u16*)B(768*768*2);
    u16* cakT = (u16*)B(768*768*2);
    u16* cavT = (u16*)B(768*768*2);
    u16* caoT = (u16*)B(768*768*2);
    u16* mlp1T = (u16*)B((size_t)3072*768*2);
    u16* mlp2T = (u16*)B((size_t)768*3072*2);
    u16* peT[3]; peT[0] = (u16*)B((size_t)768*1120*2); peT[1] = (u16*)B((size_t)768*1120*2); peT[2] = (u16*)B((size_t)768*1568*2);
    u16* owT[3]; owT[0] = (u16*)B((size_t)1120*768*2); owT[1] = (u16*)B((size_t)1120*768*2); owT[2] = (u16*)B((size_t)1568*768*2);
    u16* txtb = (u16*)B(154*768*2);
    float* m_ax  = (float*)B(573440*4);
    float* m_sag = (float*)B(573440*4);
    float* m_cor = (float*)B(802816*4);
    u16* Pb = (u16*)B((size_t)512*1568*2);
    float* X0  = (float*)B((size_t)1536*768*4);
    float* X1f = (float*)B((size_t)1536*768*4);
    float* X2  = (float*)B((size_t)1536*768*4);
    float* X3f = (float*)B((size_t)1536*768*4);
    float* X4  = (float*)B((size_t)1536*768*4);
    u16* X1b = (u16*)B((size_t)1536*768*2);
    u16* X3b = (u16*)B((size_t)1536*768*2);
    u16* X5b = (u16*)B((size_t)1536*768*2);
    u16* X6b = (u16*)B((size_t)1536*768*2);
    u16* Qbf = (u16*)B((size_t)1536*768*2);
    u16* Kbf = (u16*)B((size_t)1536*768*2);
    u16* Vbf = (u16*)B((size_t)1536*768*2);
    u16* Obf = (u16*)B((size_t)1536*768*2);
    u16* Vt  = (u16*)B((size_t)72*64*256*2);
    u16* Hb  = (u16*)B((size_t)1536*3072*2);
    float* S  = (float*)B((size_t)72*256*256*4);
    u16* Pat = (u16*)B((size_t)72*256*256*2);
    float* KHf = (float*)B((size_t)1536*768*4);
    float* VHf = (float*)B((size_t)1536*768*4);
    float* QHf = (float*)B((size_t)154*768*4);
    float* Wb  = (float*)B((size_t)72*256*4);
    float* Y[3];
    Y[0] = (float*)B(573440*4);
    Y[1] = (float*)B(573440*4);
    Y[2] = (float*)B(802816*4);

    // ---- dense view planes live in d_ws (read by final_k while it writes d_out) ----
    float* ws = (float*)d_ws;
    float* Aax  = ws;
    float* Asag = ws + 573440;
    float* Acor = ws + 1146880;

    auto tc = [&](const float* in, u16* out, int K, int N) {
        dim3 g(N/32, K/32);
        transp_cvt<<<g, 256, 0, stream>>>(in, out, K, N);
    };
    tc(qw, qwT, 768, 768); tc(kw, kwT, 768, 768); tc(vw_attn, vwT, 768, 768); tc(pw, pwT, 768, 768);
    tc(caq_w, caqT, 768, 768); tc(cak_w, cakT, 768, 768); tc(cav_w, cavT, 768, 768); tc(cao_w, caoT, 768, 768);
    tc(mlp_w1, mlp1T, 768, 3072); tc(mlp_w2, mlp2T, 3072, 768);
    tc(pe_w[0], peT[0], 1120, 768); tc(pe_w[1], peT[1], 1120, 768); tc(pe_w[2], peT[2], 1568, 768);
    tc(ow[0], owT[0], 768, 1120); tc(ow[1], owT[1], 768, 1120); tc(ow[2], owT[2], 768, 1568);
    cvt_k<<<(154*768 + 255)/256, 256, 0, stream>>>(txt, txtb, 154*768);

    hipMemsetAsync(m_ax, 0, 573440*4, stream);
    mean3_k<<<256, 256, 0, stream>>>(img, m_ax, m_sag, m_cor);

    auto gemm = [&](const u16* A, const u16* Bt, float* Cf, u16* Cb,
                    int M, int N, int K, int lda, int ldb, int ldc,
                    const float* bias, const float* posp, const float* resid,
                    int act, float cscale, int mode, int batch) {
        dim3 g((N+63)/64, (M+63)/64, batch);
        gemm_bf<<<g, 256, 0, stream>>>(A, Bt, Cf, Cb, M, N, K, lda, ldb, ldc,
                                       bias, posp, resid, act, cscale, mode);
    };

    gemm(txtb, caqT, QHf, nullptr, 154, 768, 768, 768, 768, 768,
         caq_b, nullptr, nullptr, 0, 1.f, 0, 1);

    const float* v2d[3] = {m_ax, m_sag, m_cor};
    const int p1a[3] = {7,7,7}, p2a[3] = {5,5,7};
    const int PDa[3] = {1120,1120,1568};
    const float scl[3] = {1.f/112.f, 1.f, 1.f};
    for (int br = 0; br < 3; ++br) {
        int PD = PDa[br];
        patchify_k<<<(2*256*PD+255)/256, 256, 0, stream>>>(v2d[br], Pb, p1a[br], p2a[br], PD, scl[br]);
        gemm(Pb, peT[br], X0 + (size_t)br*512*768, nullptr, 512, 768, PD, PD, PD, 768,
             pe_b[br], pos[br], nullptr, 0, 1.f, 0, 1);
    }

    ln_k<<<1536, 256, 0, stream>>>(X0, X1f, X1b, n_g[0], n_b[0]);
    gemm(X1b, qwT, nullptr, Qbf, 1536, 768, 768, 768, 768, 768, nullptr, nullptr, nullptr, 0, 0.125f, 0, 1);
    gemm(X1b, kwT, nullptr, Kbf, 1536, 768, 768, 768, 768, 768, nullptr, nullptr, nullptr, 0, 1.f, 0, 1);
    gemm(X1b, vwT, nullptr, Vbf, 1536, 768, 768, 768, 768, 768, nullptr, nullptr, nullptr, 0, 1.f, 0, 1);
    vt_k<<<(72*64*256 + 255)/256, 256, 0, stream>>>(Vbf, Vt);
    gemm(Qbf, Kbf, S, nullptr, 256, 256, 64, 768, 768, 256, nullptr, nullptr, nullptr, 0, 1.f, 1, 72);
    softmax_k<<<72*256/4, 256, 0, stream>>>(S, Pat);
    gemm(Pat, Vt, nullptr, Obf, 256, 64, 256, 256, 256, 768, nullptr, nullptr, nullptr, 0, 1.f, 2, 72);
    gemm(Obf, pwT, X2, nullptr, 1536, 768, 768, 768, 768, 768, pb, nullptr, X1f, 0, 1.f, 0, 1);
    ln_k<<<1536, 256, 0, stream>>>(X2, X3f, X3b, n_g[1], n_b[1]);
    gemm(X3b, cakT, KHf, nullptr, 1536, 768, 768, 768, 768, 768, cak_b, nullptr, nullptr, 0, 1.f, 0, 1);
    gemm(X3b, cavT, VHf, nullptr, 1536, 768, 768, 768, 768, 768, cav_b, nullptr, nullptr, 0, 1.f, 0, 1);
    ca_w_k<<<72, 256, 0, stream>>>(QHf, KHf, Wb);
    ca_apply_k<<<(1536*768 + 255)/256, 256, 0, stream>>>(Wb, VHf, Obf);
    gemm(Obf, caoT, X4, nullptr, 1536, 768, 768, 768, 768, 768, cao_b, nullptr, X3f, 0, 1.f, 0, 1);
    ln_k<<<1536, 256, 0, stream>>>(X4, nullptr, X5b, n_g[2], n_b[2]);
    gemm(X5b, mlp1T, nullptr, Hb, 1536, 3072, 768, 768, 768, 3072, mlp_b1, nullptr, nullptr, 1, 1.f, 0, 1);
    gemm(Hb, mlp2T, nullptr, X6b, 1536, 768, 3072, 3072, 3072, 768, mlp_b2, nullptr, X4, 0, 1.f, 0, 1);
    for (int br = 0; br < 3; ++br) {
        int PD = PDa[br];
        gemm(X6b + (size_t)br*512*768, owT[br], Y[br], nullptr, 512, PD, 768, 768, 768, PD,
             ob[br], nullptr, nullptr, 0, 1.f, 0, 1);
    }

    unpatch_k<<<(573440+255)/256, 256, 0, stream>>>(Y[0], Aax,  view_w, 0,  80, 5, 1120, 573440);
    unpatch_k<<<(573440+255)/256, 256, 0, stream>>>(Y[1], Asag, view_w, 1,  80, 5, 1120, 573440);
    unpatch_k<<<(802816+255)/256, 256, 0, stream>>>(Y[2], Acor, view_w, 2, 112, 7, 1568, 802816);

    final_k<<<7168, 256, 0, stream>>>(img, Aax, Asag, Acor, (float*)d_out);
}

// Round 4
// 763.155 us; speedup vs baseline: 10.0640x; 1.4918x over previous
//
#include <hip/hip_runtime.h>
#include <math.h>

typedef __attribute__((ext_vector_type(8))) short s8;
typedef __attribute__((ext_vector_type(4))) float f4;

__device__ inline unsigned short f2bf(float f) {
    unsigned u = __float_as_uint(f);
    u += 0x7fffu + ((u >> 16) & 1u);
    return (unsigned short)(u >> 16);
}

// ============ fused axis means, no atomics ============
// grid 1024: blk = bc*16 + dc; each block handles 7 d-slices of (b,c)=bc.
// ax: thread-private f4 accumulation over d -> partial plane axp[dc][bc][8960]
// sag[bc][d][w] (sum over h) and cor[bc][d][h] (sum over w): complete per slice via LDS.
__global__ __launch_bounds__(256) void mean3_k(const float* __restrict__ img,
                                               float* __restrict__ axp,
                                               float* __restrict__ sag,
                                               float* __restrict__ cor) {
    __shared__ float sl[112*81];
    int blk = blockIdx.x;
    int dc = blk & 15, bc = blk >> 4;
    int d0 = dc * 7;
    int t = threadIdx.x;
    f4 axr[9];
    #pragma unroll
    for (int k = 0; k < 9; ++k) axr[k] = (f4){0.f,0.f,0.f,0.f};
    const float* base = img + (size_t)bc * 1003520 + (size_t)d0 * 8960;
    for (int sidx = 0; sidx < 7; ++sidx) {
        const f4* sp = reinterpret_cast<const f4*>(base + (size_t)sidx * 8960);
        #pragma unroll
        for (int k = 0; k < 9; ++k) {
            int q = t + k * 256;
            if (q < 2240) {
                f4 v = sp[q];
                axr[k] += v;
                int h = q / 20, w4 = q % 20;
                float* row = &sl[h * 81 + w4 * 4];
                row[0] = v[0]; row[1] = v[1]; row[2] = v[2]; row[3] = v[3];
            }
        }
        __syncthreads();
        if (t < 112) {
            float acc = 0.f;
            #pragma unroll 8
            for (int w = 0; w < 80; ++w) acc += sl[t * 81 + w];
            cor[((size_t)bc * 112 + d0 + sidx) * 112 + t] = acc * (1.f / 80.f);
        } else if (t < 192) {
            int w = t - 112;
            float acc = 0.f;
            #pragma unroll 8
            for (int h = 0; h < 112; ++h) acc += sl[h * 81 + w];
            sag[((size_t)bc * 112 + d0 + sidx) * 80 + w] = acc * (1.f / 112.f);
        }
        __syncthreads();
    }
    float* axo = axp + ((size_t)dc * 64 + bc) * 8960;
    #pragma unroll
    for (int k = 0; k < 9; ++k) {
        int q = t + k * 256;
        if (q < 2240) *reinterpret_cast<f4*>(axo + q * 4) = axr[k];
    }
}

// reduce 16 partial ax planes -> ax (with 1/112 scale)
__global__ void axred_k(const float* __restrict__ axp, float* __restrict__ ax) {
    int idx = blockIdx.x * 256 + threadIdx.x;   // over 143360 float4
    if (idx >= 143360) return;
    f4 s = (f4){0.f,0.f,0.f,0.f};
    #pragma unroll
    for (int i = 0; i < 16; ++i)
        s += *reinterpret_cast<const f4*>(axp + (size_t)i * 573440 + (size_t)idx * 4);
    s *= (1.f / 112.f);
    *reinterpret_cast<f4*>(ax + (size_t)idx * 4) = s;
}

// ============ patchify -> bf16 ============
__global__ void patchify_k(const float* __restrict__ v2d, unsigned short* __restrict__ P,
                           int p1, int p2, int PD) {
    int idx = blockIdx.x * 256 + threadIdx.x;
    int total = 2*256*PD;
    if (idx >= total) return;
    int f = idx % PD, bn = idx / PD;
    int n = bn & 255, b = bn >> 8;
    int c = f & 31, pp = f >> 5;
    int pp2 = pp % p2, pp1 = pp / p2;
    int ww = n & 15, hh = n >> 4;
    int Ht = 16*p1, Wt = 16*p2;
    P[idx] = f2bf(v2d[(((size_t)b*32 + c)*Ht + hh*p1 + pp1)*Wt + ww*p2 + pp2]);
}

// ============ f32 [K][N] -> bf16 [N][K] transpose-convert ============
__global__ __launch_bounds__(256) void transp_cvt(const float* __restrict__ in,
                                                  unsigned short* __restrict__ out,
                                                  int K, int N) {
    __shared__ float tl[32][33];
    int k0 = blockIdx.y*32, n0 = blockIdx.x*32;
    int t = threadIdx.x;
    int r = t >> 5, c = t & 31;
    #pragma unroll
    for (int i = 0; i < 4; ++i) tl[r + i*8][c] = in[(long)(k0 + r + i*8)*N + n0 + c];
    __syncthreads();
    #pragma unroll
    for (int i = 0; i < 4; ++i) out[(long)(n0 + r + i*8)*K + k0 + c] = f2bf(tl[c][r + i*8]);
}

__global__ void cvt_k(const float* __restrict__ in, unsigned short* __restrict__ out, int n) {
    int i = blockIdx.x*256 + threadIdx.x;
    if (i < n) out[i] = f2bf(in[i]);
}

// ============ bf16 MFMA GEMM: C = A(MxK) @ Bt(NxK)^T + epilogue ============
__global__ __launch_bounds__(256) void gemm_bf(
    const unsigned short* __restrict__ A, const unsigned short* __restrict__ Bt,
    float* __restrict__ Cf, unsigned short* __restrict__ Cb,
    int M, int N, int K, int lda, int ldb, int ldc,
    const float* __restrict__ bias, const float* __restrict__ pos,
    const float* __restrict__ resid, int act, float cscale, int mode)
{
    __shared__ unsigned short As[64][40];
    __shared__ unsigned short Bs[64][40];
    const unsigned short* Ab = A;
    const unsigned short* Bb = Bt;
    long coff = 0;
    int z = blockIdx.z;
    if (mode == 1) {           // A,B rows inside fused QKV buffer; C = S[z]
        long o = (long)(z / 12) * 256 * lda + (long)(z % 12) * 64;
        Ab += o; Bb += o; coff = (long)z * 256 * ldc;
    } else if (mode == 2) {    // A=P[z], B=Vt[z], C=O rows
        Ab += (long)z * 65536; Bb += (long)z * 16384;
        coff = (long)(z / 12) * 256 * ldc + (long)(z % 12) * 64;
    }
    int t = threadIdx.x;
    int m0 = blockIdx.y * 64, n0 = blockIdx.x * 64;
    int wave = t >> 6, lane = t & 63;
    int wr = wave >> 1, wc = wave & 1;
    int lrow = lane & 15, lk = (lane >> 4) * 8;
    f4 acc[2][2];
    #pragma unroll
    for (int m = 0; m < 2; ++m)
        #pragma unroll
        for (int n = 0; n < 2; ++n)
            #pragma unroll
            for (int r = 0; r < 4; ++r) acc[m][n][r] = 0.f;
    int srow = t >> 2, sc = (t & 3) * 8;
    for (int k0 = 0; k0 < K; k0 += 32) {
        s8 av, bv;
        #pragma unroll
        for (int i = 0; i < 8; ++i) { av[i] = 0; bv[i] = 0; }
        if (m0 + srow < M) av = *reinterpret_cast<const s8*>(Ab + (long)(m0 + srow)*lda + k0 + sc);
        if (n0 + srow < N) bv = *reinterpret_cast<const s8*>(Bb + (long)(n0 + srow)*ldb + k0 + sc);
        *reinterpret_cast<s8*>(&As[srow][sc]) = av;
        *reinterpret_cast<s8*>(&Bs[srow][sc]) = bv;
        __syncthreads();
        s8 af0 = *reinterpret_cast<const s8*>(&As[wr*32 + lrow][lk]);
        s8 af1 = *reinterpret_cast<const s8*>(&As[wr*32 + 16 + lrow][lk]);
        s8 bg0 = *reinterpret_cast<const s8*>(&Bs[wc*32 + lrow][lk]);
        s8 bg1 = *reinterpret_cast<const s8*>(&Bs[wc*32 + 16 + lrow][lk]);
        acc[0][0] = __builtin_amdgcn_mfma_f32_16x16x32_bf16(af0, bg0, acc[0][0], 0, 0, 0);
        acc[0][1] = __builtin_amdgcn_mfma_f32_16x16x32_bf16(af0, bg1, acc[0][1], 0, 0, 0);
        acc[1][0] = __builtin_amdgcn_mfma_f32_16x16x32_bf16(af1, bg0, acc[1][0], 0, 0, 0);
        acc[1][1] = __builtin_amdgcn_mfma_f32_16x16x32_bf16(af1, bg1, acc[1][1], 0, 0, 0);
        __syncthreads();
    }
    #pragma unroll
    for (int m = 0; m < 2; ++m) {
        int rbase = m0 + wr*32 + m*16 + (lane >> 4) * 4;
        #pragma unroll
        for (int n = 0; n < 2; ++n) {
            int col = n0 + wc*32 + n*16 + (lane & 15);
            if (col >= N) continue;
            #pragma unroll
            for (int r = 0; r < 4; ++r) {
                int row = rbase + r;
                if (row >= M) continue;
                float v = acc[m][n][r];
                if (bias)  v += bias[col];
                if (pos)   v += pos[(long)(row & 255) * N + col];
                if (resid) v += resid[(long)row * ldc + col];
                if (act == 1) v = 0.5f * v * (1.0f + erff(v * 0.70710678118654752f));
                v *= cscale;
                long ci = coff + (long)row * ldc + col;
                if (Cf) Cf[ci] = v;
                if (Cb) Cb[ci] = f2bf(v);
            }
        }
    }
}

// ============ LayerNorm rows of 768 ============
__global__ __launch_bounds__(256) void ln_k(const float* __restrict__ in,
                                            float* __restrict__ outf,
                                            unsigned short* __restrict__ outb,
                                            const float* __restrict__ g,
                                            const float* __restrict__ bta) {
    constexpr int N = 768;
    int row = blockIdx.x;
    const float* x = in + (size_t)row * N;
    int t = threadIdx.x;
    float v0 = x[t], v1 = x[t+256], v2 = x[t+512];
    float s = v0+v1+v2, s2 = v0*v0+v1*v1+v2*v2;
    #pragma unroll
    for (int off = 32; off > 0; off >>= 1) { s += __shfl_down(s, off); s2 += __shfl_down(s2, off); }
    __shared__ float red[8];
    int wid = t >> 6, lane = t & 63;
    if (lane == 0) { red[wid] = s; red[wid+4] = s2; }
    __syncthreads();
    if (t == 0) {
        float S = red[0]+red[1]+red[2]+red[3];
        float S2 = red[4]+red[5]+red[6]+red[7];
        float mean = S * (1.f/N);
        float var = S2 * (1.f/N) - mean*mean;
        red[0] = mean; red[1] = rsqrtf(var + 1e-5f);
    }
    __syncthreads();
    float mean = red[0], rstd = red[1];
    float y0 = (v0-mean)*rstd*g[t]     + bta[t];
    float y1 = (v1-mean)*rstd*g[t+256] + bta[t+256];
    float y2 = (v2-mean)*rstd*g[t+512] + bta[t+512];
    if (outf) {
        float* y = outf + (size_t)row * N;
        y[t] = y0; y[t+256] = y1; y[t+512] = y2;
    }
    if (outb) {
        unsigned short* y = outb + (size_t)row * N;
        y[t] = f2bf(y0); y[t+256] = f2bf(y1); y[t+512] = f2bf(y2);
    }
}

// ============ V transpose per head (V inside fused QKV buffer, ld 2304, off 1536) ============
__global__ void vt_k(const unsigned short* __restrict__ QKV, unsigned short* __restrict__ Vt) {
    int idx = blockIdx.x*256 + threadIdx.x;
    if (idx >= 72*64*256) return;
    int j = idx & 255, rest = idx >> 8;
    int d = rest & 63, z = rest >> 6;
    Vt[idx] = QKV[((long)(z/12)*256 + j)*2304 + 1536 + (long)(z%12)*64 + d];
}

// ============ row softmax on S[72*256][256] -> bf16 P ============
__global__ __launch_bounds__(256) void softmax_k(const float* __restrict__ S,
                                                 unsigned short* __restrict__ P) {
    int row = blockIdx.x*4 + (threadIdx.x >> 6);
    int lane = threadIdx.x & 63;
    const float4 v = *reinterpret_cast<const float4*>(S + (long)row*256 + lane*4);
    float m = fmaxf(fmaxf(v.x, v.y), fmaxf(v.z, v.w));
    #pragma unroll
    for (int o = 32; o; o >>= 1) m = fmaxf(m, __shfl_xor(m, o));
    float p0 = __expf(v.x - m), p1 = __expf(v.y - m), p2 = __expf(v.z - m), p3 = __expf(v.w - m);
    float l = p0 + p1 + p2 + p3;
    #pragma unroll
    for (int o = 32; o; o >>= 1) l += __shfl_xor(l, o);
    float inv = 1.f / l;
    unsigned b0 = f2bf(p0*inv), b1 = f2bf(p1*inv), b2 = f2bf(p2*inv), b3 = f2bf(p3*inv);
    uint2 pk; pk.x = b0 | (b1 << 16); pk.y = b2 | (b3 << 16);
    *reinterpret_cast<uint2*>(P + (long)row*256 + lane*4) = pk;
}

// ============ cross-attn colsum weights ============
__global__ __launch_bounds__(256) void ca_w_k(const float* __restrict__ QH,
                                              const float* __restrict__ KH,
                                              float* __restrict__ Wout) {
    int bh = blockIdx.x;
    int rowblk = bh / 12, h = bh % 12, b = rowblk & 1;
    __shared__ float qs[77*64];
    __shared__ float red[8];
    int t = threadIdx.x;
    for (int idx = t; idx < 77*64; idx += 256) {
        int i = idx >> 6, c = idx & 63;
        qs[idx] = QH[((long)(b*77 + i))*768 + h*64 + c];
    }
    __syncthreads();
    float kx[64];
    {
        const float4* kp = reinterpret_cast<const float4*>(KH + ((long)(rowblk*256 + t))*768 + h*64);
        #pragma unroll
        for (int i = 0; i < 16; ++i) {
            float4 v = kp[i];
            kx[4*i] = v.x; kx[4*i+1] = v.y; kx[4*i+2] = v.z; kx[4*i+3] = v.w;
        }
    }
    int wid = t >> 6, lane = t & 63;
    float w = 0.f;
    for (int i = 0; i < 77; ++i) {
        float s = 0.f;
        #pragma unroll
        for (int c = 0; c < 64; ++c) s += qs[i*64 + c] * kx[c];
        s *= 0.125f;
        float m = s;
        #pragma unroll
        for (int o = 32; o; o >>= 1) m = fmaxf(m, __shfl_xor(m, o));
        if (lane == 0) red[wid] = m;
        __syncthreads();
        m = fmaxf(fmaxf(red[0], red[1]), fmaxf(red[2], red[3]));
        float p = __expf(s - m);
        float l = p;
        #pragma unroll
        for (int o = 32; o; o >>= 1) l += __shfl_xor(l, o);
        if (lane == 0) red[4 + wid] = l;
        __syncthreads();
        l = red[4] + red[5] + red[6] + red[7];
        w += p / l;
        __syncthreads();
    }
    Wout[(long)bh*256 + t] = w;
}

// ============ O = W * VH (bf16 out) ============
__global__ void ca_apply_k(const float* __restrict__ W, const float* __restrict__ VH,
                           unsigned short* __restrict__ O) {
    int idx = blockIdx.x*256 + threadIdx.x;
    if (idx >= 1536*768) return;
    int row = idx / 768, col = idx - row*768;
    int rowblk = row >> 8, j = row & 255, h = col >> 6;
    O[idx] = f2bf(W[((long)rowblk*12 + h)*256 + j] * VH[idx]);
}

// ============ unpatchify Y -> dense plane, pre-weighted by view_w ============
__global__ void unpatch_k(const float* __restrict__ y, float* __restrict__ A,
                          const float* __restrict__ vw, int vwi,
                          int Wd, int p2, int PD, int total) {
    int idx = blockIdx.x*256 + threadIdx.x;
    if (idx >= total) return;
    int w = idx % Wd; int r = idx / Wd;
    int h = r % 112; r /= 112;
    int c = r % 32; int b = r / 32;
    int src = (b*256 + (h/7)*16 + (w/p2))*PD + ((h%7)*p2 + (w%p2))*32 + c;
    A[idx] = vw[vwi] * y[src];
}

// ============ streaming final combine ============
__global__ __launch_bounds__(256) void final_k(const float* __restrict__ img,
                                               const float* __restrict__ Aax,
                                               const float* __restrict__ Asag,
                                               const float* __restrict__ Acor,
                                               float* __restrict__ out) {
    int blk = blockIdx.x;                 // bc*112 + d
    int bc = blk / 112;
    const float4* ip = reinterpret_cast<const float4*>(img + (size_t)blk * 8960);
    const float4* ap = reinterpret_cast<const float4*>(Aax + (size_t)bc * 8960);
    const float4* sp = reinterpret_cast<const float4*>(Asag + (size_t)blk * 80);
    const float*  cp = Acor + (size_t)blk * 112;
    float4* op = reinterpret_cast<float4*>(out + (size_t)blk * 8960);
    int t = threadIdx.x;
    for (int q = t; q < 2240; q += 256) {
        int h = q / 20, w4 = q % 20;
        float4 iv = ip[q], av = ap[q], sv = sp[w4];
        float cv = cp[h];
        float4 o;
        o.x = iv.x + av.x + sv.x + cv;
        o.y = iv.y + av.y + sv.y + cv;
        o.z = iv.z + av.z + sv.z + cv;
        o.w = iv.w + av.w + sv.w + cv;
        op[q] = o;
    }
}

extern "C" void kernel_launch(void* const* d_in, const int* in_sizes, int n_in,
                              void* d_out, int out_size, void* d_ws, size_t ws_size,
                              hipStream_t stream) {
    (void)in_sizes; (void)n_in; (void)out_size; (void)ws_size;
    const float* img    = (const float*)d_in[0];
    const float* txt    = (const float*)d_in[1];
    const float* pe_w[3] = {(const float*)d_in[2], (const float*)d_in[4], (const float*)d_in[6]};
    const float* pe_b[3] = {(const float*)d_in[3], (const float*)d_in[5], (const float*)d_in[7]};
    const float* pos[3]  = {(const float*)d_in[8], (const float*)d_in[9], (const float*)d_in[10]};
    const float* qw = (const float*)d_in[11];
    const float* kw = (const float*)d_in[12];
    const float* vw_attn = (const float*)d_in[13];
    const float* pw = (const float*)d_in[14];
    const float* pb = (const float*)d_in[15];
    const float* caq_w = (const float*)d_in[16];
    const float* caq_b = (const float*)d_in[17];
    const float* cak_w = (const float*)d_in[18];
    const float* cak_b = (const float*)d_in[19];
    const float* cav_w = (const float*)d_in[20];
    const float* cav_b = (const float*)d_in[21];
    const float* cao_w = (const float*)d_in[22];
    const float* cao_b = (const float*)d_in[23];
    const float* mlp_w1 = (const float*)d_in[24];
    const float* mlp_b1 = (const float*)d_in[25];
    const float* mlp_w2 = (const float*)d_in[26];
    const float* mlp_b2 = (const float*)d_in[27];
    const float* ow[3] = {(const float*)d_in[28], (const float*)d_in[30], (const float*)d_in[32]};
    const float* ob[3] = {(const float*)d_in[29], (const float*)d_in[31], (const float*)d_in[33]};
    const float* view_w = (const float*)d_in[34];
    const float* n_g[3] = {(const float*)d_in[35], (const float*)d_in[36], (const float*)d_in[37]};
    const float* n_b[3] = {(const float*)d_in[38], (const float*)d_in[39], (const float*)d_in[40]};

    typedef unsigned short u16;
    // ---- big scratch lives in d_out (fully rewritten by final_k) ----
    unsigned char* sb = (unsigned char*)d_out;
    size_t off = 0;
    auto B = [&](size_t bytes) -> void* {
        void* p = sb + off; off += (bytes + 511) & ~(size_t)511; return p;
    };
    u16* qkvT = (u16*)B((size_t)2304*768*2);    // fused [Q;K;V] weights, [N][K]
    u16* pwT  = (u16*)B(768*768*2);
    u16* caqT = (u16*)B(768*768*2);
    u16* cakT = (u16*)B(768*768*2);
    u16* cavT = (u16*)B(768*768*2);
    u16* caoT = (u16*)B(768*768*2);
    u16* mlp1T = (u16*)B((size_t)3072*768*2);
    u16* mlp2T = (u16*)B((size_t)768*3072*2);
    u16* peT[3]; peT[0] = (u16*)B((size_t)768*1120*2); peT[1] = (u16*)B((size_t)768*1120*2); peT[2] = (u16*)B((size_t)768*1568*2);
    u16* owT[3]; owT[0] = (u16*)B((size_t)1120*768*2); owT[1] = (u16*)B((size_t)1120*768*2); owT[2] = (u16*)B((size_t)1568*768*2);
    u16* txtb = (u16*)B(154*768*2);
    float* axp   = (float*)B((size_t)16*573440*4);   // ax partial planes
    float* m_ax  = (float*)B(573440*4);
    float* m_sag = (float*)B(573440*4);
    float* m_cor = (float*)B(802816*4);
    u16* Pb = (u16*)B((size_t)512*1568*2);
    float* X0  = (float*)B((size_t)1536*768*4);
    float* X1f = (float*)B((size_t)1536*768*4);
    float* X2  = (float*)B((size_t)1536*768*4);
    float* X3f = (float*)B((size_t)1536*768*4);
    float* X4  = (float*)B((size_t)1536*768*4);
    u16* X1b = (u16*)B((size_t)1536*768*2);
    u16* X3b = (u16*)B((size_t)1536*768*2);
    u16* X5b = (u16*)B((size_t)1536*768*2);
    u16* X6b = (u16*)B((size_t)1536*768*2);
    u16* QKVb = (u16*)B((size_t)1536*2304*2);
    u16* Obf = (u16*)B((size_t)1536*768*2);
    u16* Vt  = (u16*)B((size_t)72*64*256*2);
    u16* Hb  = (u16*)B((size_t)1536*3072*2);
    float* S  = (float*)B((size_t)72*256*256*4);
    u16* Pat = (u16*)B((size_t)72*256*256*2);
    float* KHf = (float*)B((size_t)1536*768*4);
    float* VHf = (float*)B((size_t)1536*768*4);
    float* QHf = (float*)B((size_t)154*768*4);
    float* Wb  = (float*)B((size_t)72*256*4);
    float* Y[3];
    Y[0] = (float*)B(573440*4);
    Y[1] = (float*)B(573440*4);
    Y[2] = (float*)B(802816*4);

    // ---- dense view planes live in d_ws ----
    float* ws = (float*)d_ws;
    float* Aax  = ws;
    float* Asag = ws + 573440;
    float* Acor = ws + 1146880;

    auto tc = [&](const float* in, u16* out, int K, int N) {
        dim3 g(N/32, K/32);
        transp_cvt<<<g, 256, 0, stream>>>(in, out, K, N);
    };
    tc(qw, qkvT, 768, 768); tc(kw, qkvT + 768*768, 768, 768); tc(vw_attn, qkvT + 2*768*768, 768, 768);
    tc(pw, pwT, 768, 768);
    tc(caq_w, caqT, 768, 768); tc(cak_w, cakT, 768, 768); tc(cav_w, cavT, 768, 768); tc(cao_w, caoT, 768, 768);
    tc(mlp_w1, mlp1T, 768, 3072); tc(mlp_w2, mlp2T, 3072, 768);
    tc(pe_w[0], peT[0], 1120, 768); tc(pe_w[1], peT[1], 1120, 768); tc(pe_w[2], peT[2], 1568, 768);
    tc(ow[0], owT[0], 768, 1120); tc(ow[1], owT[1], 768, 1120); tc(ow[2], owT[2], 768, 1568);
    cvt_k<<<(154*768 + 255)/256, 256, 0, stream>>>(txt, txtb, 154*768);

    mean3_k<<<1024, 256, 0, stream>>>(img, axp, m_sag, m_cor);
    axred_k<<<560, 256, 0, stream>>>(axp, m_ax);

    auto gemm = [&](const u16* A, const u16* Bt, float* Cf, u16* Cb,
                    int M, int N, int K, int lda, int ldb, int ldc,
                    const float* bias, const float* posp, const float* resid,
                    int act, float cscale, int mode, int batch) {
        dim3 g((N+63)/64, (M+63)/64, batch);
        gemm_bf<<<g, 256, 0, stream>>>(A, Bt, Cf, Cb, M, N, K, lda, ldb, ldc,
                                       bias, posp, resid, act, cscale, mode);
    };

    gemm(txtb, caqT, QHf, nullptr, 154, 768, 768, 768, 768, 768,
         caq_b, nullptr, nullptr, 0, 1.f, 0, 1);

    const float* v2d[3] = {m_ax, m_sag, m_cor};
    const int p1a[3] = {7,7,7}, p2a[3] = {5,5,7};
    const int PDa[3] = {1120,1120,1568};
    for (int br = 0; br < 3; ++br) {
        int PD = PDa[br];
        patchify_k<<<(2*256*PD+255)/256, 256, 0, stream>>>(v2d[br], Pb, p1a[br], p2a[br], PD);
        gemm(Pb, peT[br], X0 + (size_t)br*512*768, nullptr, 512, 768, PD, PD, PD, 768,
             pe_b[br], pos[br], nullptr, 0, 1.f, 0, 1);
    }

    ln_k<<<1536, 256, 0, stream>>>(X0, X1f, X1b, n_g[0], n_b[0]);
    // fused QKV projection: [1536][2304]
    gemm(X1b, qkvT, nullptr, QKVb, 1536, 2304, 768, 768, 768, 2304,
         nullptr, nullptr, nullptr, 0, 1.f, 0, 1);
    vt_k<<<(72*64*256 + 255)/256, 256, 0, stream>>>(QKVb, Vt);
    // S = (Q K^T) * 0.125 per head
    gemm(QKVb, QKVb + 768, S, nullptr, 256, 256, 64, 2304, 2304, 256,
         nullptr, nullptr, nullptr, 0, 0.125f, 1, 72);
    softmax_k<<<72*256/4, 256, 0, stream>>>(S, Pat);
    gemm(Pat, Vt, nullptr, Obf, 256, 64, 256, 256, 256, 768,
         nullptr, nullptr, nullptr, 0, 1.f, 2, 72);
    gemm(Obf, pwT, X2, nullptr, 1536, 768, 768, 768, 768, 768, pb, nullptr, X1f, 0, 1.f, 0, 1);
    ln_k<<<1536, 256, 0, stream>>>(X2, X3f, X3b, n_g[1], n_b[1]);
    gemm(X3b, cakT, KHf, nullptr, 1536, 768, 768, 768, 768, 768, cak_b, nullptr, nullptr, 0, 1.f, 0, 1);
    gemm(X3b, cavT, VHf, nullptr, 1536, 768, 768, 768, 768, 768, cav_b, nullptr, nullptr, 0, 1.f, 0, 1);
    ca_w_k<<<72, 256, 0, stream>>>(QHf, KHf, Wb);
    ca_apply_k<<<(1536*768 + 255)/256, 256, 0, stream>>>(Wb, VHf, Obf);
    gemm(Obf, caoT, X4, nullptr, 1536, 768, 768, 768, 768, 768, cao_b, nullptr, X3f, 0, 1.f, 0, 1);
    ln_k<<<1536, 256, 0, stream>>>(X4, nullptr, X5b, n_g[2], n_b[2]);
    gemm(X5b, mlp1T, nullptr, Hb, 1536, 3072, 768, 768, 768, 3072, mlp_b1, nullptr, nullptr, 1, 1.f, 0, 1);
    gemm(Hb, mlp2T, nullptr, X6b, 1536, 768, 3072, 3072, 3072, 768, mlp_b2, nullptr, X4, 0, 1.f, 0, 1);
    for (int br = 0; br < 3; ++br) {
        int PD = PDa[br];
        gemm(X6b + (size_t)br*512*768, owT[br], Y[br], nullptr, 512, PD, 768, 768, 768, PD,
             ob[br], nullptr, nullptr, 0, 1.f, 0, 1);
    }

    unpatch_k<<<(573440+255)/256, 256, 0, stream>>>(Y[0], Aax,  view_w, 0,  80, 5, 1120, 573440);
    unpatch_k<<<(573440+255)/256, 256, 0, stream>>>(Y[1], Asag, view_w, 1,  80, 5, 1120, 573440);
    unpatch_k<<<(802816+255)/256, 256, 0, stream>>>(Y[2], Acor, view_w, 2, 112, 7, 1568, 802816);

    final_k<<<7168, 256, 0, stream>>>(img, Aax, Asag, Acor, (float*)d_out);
}

// Round 5
// 544.122 us; speedup vs baseline: 14.1152x; 1.4025x over previous
//
#include <hip/hip_runtime.h>
#include <math.h>

typedef __attribute__((ext_vector_type(8))) short s8;
typedef __attribute__((ext_vector_type(4))) float f4;
typedef unsigned short u16;

__device__ inline u16 f2bf(float f) {
    unsigned u = __float_as_uint(f);
    u += 0x7fffu + ((u >> 16) & 1u);
    return (u16)(u >> 16);
}
__device__ inline float bf2f(u16 x) {
    return __uint_as_float(((unsigned)x) << 16);
}

// ============ fused axis means, no atomics ============
__global__ __launch_bounds__(256) void mean3_k(const float* __restrict__ img,
                                               float* __restrict__ axp,
                                               float* __restrict__ sag,
                                               float* __restrict__ cor) {
    __shared__ float sl[112*81];
    int blk = blockIdx.x;
    int dc = blk & 15, bc = blk >> 4;
    int d0 = dc * 7;
    int t = threadIdx.x;
    f4 axr[9];
    #pragma unroll
    for (int k = 0; k < 9; ++k) axr[k] = (f4){0.f,0.f,0.f,0.f};
    const float* base = img + (size_t)bc * 1003520 + (size_t)d0 * 8960;
    for (int sidx = 0; sidx < 7; ++sidx) {
        const f4* sp = reinterpret_cast<const f4*>(base + (size_t)sidx * 8960);
        #pragma unroll
        for (int k = 0; k < 9; ++k) {
            int q = t + k * 256;
            if (q < 2240) {
                f4 v = sp[q];
                axr[k] += v;
                int h = q / 20, w4 = q % 20;
                float* row = &sl[h * 81 + w4 * 4];
                row[0] = v[0]; row[1] = v[1]; row[2] = v[2]; row[3] = v[3];
            }
        }
        __syncthreads();
        if (t < 112) {
            float acc = 0.f;
            #pragma unroll 8
            for (int w = 0; w < 80; ++w) acc += sl[t * 81 + w];
            cor[((size_t)bc * 112 + d0 + sidx) * 112 + t] = acc * (1.f / 80.f);
        } else if (t < 192) {
            int w = t - 112;
            float acc = 0.f;
            #pragma unroll 8
            for (int h = 0; h < 112; ++h) acc += sl[h * 81 + w];
            sag[((size_t)bc * 112 + d0 + sidx) * 80 + w] = acc * (1.f / 112.f);
        }
        __syncthreads();
    }
    float* axo = axp + ((size_t)dc * 64 + bc) * 8960;
    #pragma unroll
    for (int k = 0; k < 9; ++k) {
        int q = t + k * 256;
        if (q < 2240) *reinterpret_cast<f4*>(axo + q * 4) = axr[k];
    }
}

__global__ void axred_k(const float* __restrict__ axp, float* __restrict__ ax) {
    int idx = blockIdx.x * 256 + threadIdx.x;
    if (idx >= 143360) return;
    f4 s = (f4){0.f,0.f,0.f,0.f};
    #pragma unroll
    for (int i = 0; i < 16; ++i)
        s += *reinterpret_cast<const f4*>(axp + (size_t)i * 573440 + (size_t)idx * 4);
    s *= (1.f / 112.f);
    *reinterpret_cast<f4*>(ax + (size_t)idx * 4) = s;
}

// ============ batched transpose-convert: f32 [K][N] -> bf16 [N][K] ============
struct TT {
    const float* in[16];
    u16* out[16];
    int K[16];
    int N[16];
    int start[16];
};

__global__ __launch_bounds__(256) void transp_all(TT tab) {
    __shared__ float tl[32][33];
    int bid = blockIdx.x;
    int e = 0;
    #pragma unroll
    for (int i = 1; i < 16; ++i) if (bid >= tab.start[i]) e = i;
    const float* in = tab.in[e];
    u16* out = tab.out[e];
    int K = tab.K[e], N = tab.N[e];
    int tid = bid - tab.start[e];
    int nt = N >> 5;
    int k0 = (tid / nt) * 32, n0 = (tid % nt) * 32;
    int t = threadIdx.x;
    int r = t >> 5, c = t & 31;
    #pragma unroll
    for (int i = 0; i < 4; ++i) tl[r + i*8][c] = in[(long)(k0 + r + i*8)*N + n0 + c];
    __syncthreads();
    #pragma unroll
    for (int i = 0; i < 4; ++i) out[(long)(n0 + r + i*8)*K + k0 + c] = f2bf(tl[c][r + i*8]);
}

// ============ misc: txt cvt + kv bias concat ============
__global__ void misc_k(const float* __restrict__ txt, u16* __restrict__ txtb,
                       const float* __restrict__ cak_b, const float* __restrict__ cav_b,
                       float* __restrict__ kvb) {
    int idx = blockIdx.x*256 + threadIdx.x;
    if (idx < 118272) { txtb[idx] = f2bf(txt[idx]); return; }
    int i2 = idx - 118272;
    if (i2 < 768) kvb[i2] = cak_b[i2];
    else if (i2 < 1536) kvb[i2] = cav_b[i2 - 768];
}

// ============ patchify (LDS transpose, coalesced), 3 branches ============
__global__ __launch_bounds__(256) void patchify3_k(const float* __restrict__ m_ax,
                                                   const float* __restrict__ m_sag,
                                                   const float* __restrict__ m_cor,
                                                   u16* __restrict__ P0, u16* __restrict__ P1,
                                                   u16* __restrict__ P2) {
    __shared__ float sl[32][113];
    int br = blockIdx.y;
    int X = blockIdx.x;                       // 224 = b(2) * hh(16) * pp1(7)
    int b = X / 112, rem = X % 112;
    int hh = rem / 7, pp1 = rem % 7;
    const float* src; u16* dst; int Wt, p2, PD;
    if (br == 0)      { src = m_ax;  dst = P0; Wt = 80;  p2 = 5; PD = 1120; }
    else if (br == 1) { src = m_sag; dst = P1; Wt = 80;  p2 = 5; PD = 1120; }
    else              { src = m_cor; dst = P2; Wt = 112; p2 = 7; PD = 1568; }
    int t = threadIdx.x;
    int row = hh*7 + pp1;
    int wq = Wt >> 2;
    for (int i = t; i < 32*wq; i += 256) {
        int c = i / wq, w4 = i % wq;
        float4 v = *reinterpret_cast<const float4*>(
            src + ((size_t)(b*32 + c)*112 + row)*Wt + w4*4);
        sl[c][w4*4+0] = v.x; sl[c][w4*4+1] = v.y; sl[c][w4*4+2] = v.z; sl[c][w4*4+3] = v.w;
    }
    __syncthreads();
    int tot = 16 * p2 * 32;
    for (int o = t; o < tot; o += 256) {
        int ww = o / (p2*32), rest = o % (p2*32);
        int pp2 = rest >> 5, c = rest & 31;
        dst[((size_t)(b*256 + hh*16 + ww))*PD + (pp1*p2 + pp2)*32 + c]
            = f2bf(sl[c][ww*p2 + pp2]);
    }
}

// ============ bf16 MFMA GEMM, BK=64: C = A(MxK) @ Bt(NxK)^T + epilogue ============
__global__ __launch_bounds__(256) void gemm_bf(
    const u16* __restrict__ A, const u16* __restrict__ Bt,
    float* __restrict__ Cf, u16* __restrict__ Cb,
    int M, int N, int K, int lda, int ldb, int ldc,
    const float* __restrict__ bias, const float* __restrict__ resid,
    int act, float cscale, int mode)
{
    __shared__ u16 As[64][72];
    __shared__ u16 Bs[64][72];
    const u16* Ab = A;
    const u16* Bb = Bt;
    long coff = 0;
    int z = blockIdx.z;
    if (mode == 1) {           // self-attn QK^T inside QKV buffer
        long o = (long)(z / 12) * 256 * lda + (long)(z % 12) * 64;
        Ab += o; Bb += o; coff = (long)z * 256 * ldc;
    } else if (mode == 2) {    // PV
        Ab += (long)z * 65536; Bb += (long)z * 16384;
        coff = (long)(z / 12) * 256 * ldc + (long)(z % 12) * 64;
    } else if (mode == 3) {    // cross-attn S2 = QH @ KH^T
        int rowblk = z / 12, h = z % 12;
        Ab += (long)(rowblk & 1) * 77 * lda + (long)h * 64;
        Bb += (long)rowblk * 256 * ldb + (long)h * 64;
        coff = (long)z * 77 * 256;
    }
    int t = threadIdx.x;
    int m0 = blockIdx.y * 64, n0 = blockIdx.x * 64;
    int wave = t >> 6, lane = t & 63;
    int wr = wave >> 1, wc = wave & 1;
    int lrow = lane & 15;
    f4 acc[2][2];
    #pragma unroll
    for (int m = 0; m < 2; ++m)
        #pragma unroll
        for (int n = 0; n < 2; ++n)
            #pragma unroll
            for (int r = 0; r < 4; ++r) acc[m][n][r] = 0.f;
    for (int k0 = 0; k0 < K; k0 += 64) {
        #pragma unroll
        for (int i = 0; i < 2; ++i) {
            int idx = t + i*256;
            int row = idx >> 3, c8 = (idx & 7) * 8;
            s8 av, bv;
            #pragma unroll
            for (int q = 0; q < 8; ++q) { av[q] = 0; bv[q] = 0; }
            if (m0 + row < M) av = *reinterpret_cast<const s8*>(Ab + (long)(m0 + row)*lda + k0 + c8);
            if (n0 + row < N) bv = *reinterpret_cast<const s8*>(Bb + (long)(n0 + row)*ldb + k0 + c8);
            *reinterpret_cast<s8*>(&As[row][c8]) = av;
            *reinterpret_cast<s8*>(&Bs[row][c8]) = bv;
        }
        __syncthreads();
        #pragma unroll
        for (int kh = 0; kh < 2; ++kh) {
            int lk = kh*32 + (lane >> 4) * 8;
            s8 af0 = *reinterpret_cast<const s8*>(&As[wr*32 + lrow][lk]);
            s8 af1 = *reinterpret_cast<const s8*>(&As[wr*32 + 16 + lrow][lk]);
            s8 bg0 = *reinterpret_cast<const s8*>(&Bs[wc*32 + lrow][lk]);
            s8 bg1 = *reinterpret_cast<const s8*>(&Bs[wc*32 + 16 + lrow][lk]);
            acc[0][0] = __builtin_amdgcn_mfma_f32_16x16x32_bf16(af0, bg0, acc[0][0], 0, 0, 0);
            acc[0][1] = __builtin_amdgcn_mfma_f32_16x16x32_bf16(af0, bg1, acc[0][1], 0, 0, 0);
            acc[1][0] = __builtin_amdgcn_mfma_f32_16x16x32_bf16(af1, bg0, acc[1][0], 0, 0, 0);
            acc[1][1] = __builtin_amdgcn_mfma_f32_16x16x32_bf16(af1, bg1, acc[1][1], 0, 0, 0);
        }
        __syncthreads();
    }
    #pragma unroll
    for (int m = 0; m < 2; ++m) {
        int rbase = m0 + wr*32 + m*16 + (lane >> 4) * 4;
        #pragma unroll
        for (int n = 0; n < 2; ++n) {
            int col = n0 + wc*32 + n*16 + (lane & 15);
            if (col >= N) continue;
            #pragma unroll
            for (int r = 0; r < 4; ++r) {
                int row = rbase + r;
                if (row >= M) continue;
                float v = acc[m][n][r];
                if (bias)  v += bias[col];
                if (resid) v += resid[(long)row * ldc + col];
                if (act == 1) v = 0.5f * v * (1.0f + erff(v * 0.70710678118654752f));
                v *= cscale;
                long ci = coff + (long)row * ldc + col;
                if (Cf) Cf[ci] = v;
                if (Cb) Cb[ci] = f2bf(v);
            }
        }
    }
}

// ============ batched patch-embed GEMM: X0[z] = P[z] @ peT[z] + bias + pos ============
struct PeDesc {
    const u16* A[3];
    const u16* Bt[3];
    const float* bias[3];
    const float* pos[3];
    int K[3];
};

__global__ __launch_bounds__(256) void gemm_pe(PeDesc d, float* __restrict__ C) {
    __shared__ u16 As[64][72];
    __shared__ u16 Bs[64][72];
    int z = blockIdx.z;
    const u16* Ab = d.A[z];
    const u16* Bb = d.Bt[z];
    const float* bias = d.bias[z];
    const float* pos = d.pos[z];
    int K = d.K[z];
    int t = threadIdx.x;
    int m0 = blockIdx.y * 64, n0 = blockIdx.x * 64;
    int wave = t >> 6, lane = t & 63;
    int wr = wave >> 1, wc = wave & 1;
    int lrow = lane & 15;
    f4 acc[2][2];
    #pragma unroll
    for (int m = 0; m < 2; ++m)
        #pragma unroll
        for (int n = 0; n < 2; ++n)
            #pragma unroll
            for (int r = 0; r < 4; ++r) acc[m][n][r] = 0.f;
    for (int k0 = 0; k0 < K; k0 += 64) {
        #pragma unroll
        for (int i = 0; i < 2; ++i) {
            int idx = t + i*256;
            int row = idx >> 3, c8 = (idx & 7) * 8;
            s8 av, bv;
            #pragma unroll
            for (int q = 0; q < 8; ++q) { av[q] = 0; bv[q] = 0; }
            if (k0 + c8 < K) {
                av = *reinterpret_cast<const s8*>(Ab + (long)(m0 + row)*K + k0 + c8);
                bv = *reinterpret_cast<const s8*>(Bb + (long)(n0 + row)*K + k0 + c8);
            }
            *reinterpret_cast<s8*>(&As[row][c8]) = av;
            *reinterpret_cast<s8*>(&Bs[row][c8]) = bv;
        }
        __syncthreads();
        #pragma unroll
        for (int kh = 0; kh < 2; ++kh) {
            int lk = kh*32 + (lane >> 4) * 8;
            s8 af0 = *reinterpret_cast<const s8*>(&As[wr*32 + lrow][lk]);
            s8 af1 = *reinterpret_cast<const s8*>(&As[wr*32 + 16 + lrow][lk]);
            s8 bg0 = *reinterpret_cast<const s8*>(&Bs[wc*32 + lrow][lk]);
            s8 bg1 = *reinterpret_cast<const s8*>(&Bs[wc*32 + 16 + lrow][lk]);
            acc[0][0] = __builtin_amdgcn_mfma_f32_16x16x32_bf16(af0, bg0, acc[0][0], 0, 0, 0);
            acc[0][1] = __builtin_amdgcn_mfma_f32_16x16x32_bf16(af0, bg1, acc[0][1], 0, 0, 0);
            acc[1][0] = __builtin_amdgcn_mfma_f32_16x16x32_bf16(af1, bg0, acc[1][0], 0, 0, 0);
            acc[1][1] = __builtin_amdgcn_mfma_f32_16x16x32_bf16(af1, bg1, acc[1][1], 0, 0, 0);
        }
        __syncthreads();
    }
    float* Cz = C + (long)z * 512 * 768;
    #pragma unroll
    for (int m = 0; m < 2; ++m) {
        int rbase = m0 + wr*32 + m*16 + (lane >> 4) * 4;
        #pragma unroll
        for (int n = 0; n < 2; ++n) {
            int col = n0 + wc*32 + n*16 + (lane & 15);
            #pragma unroll
            for (int r = 0; r < 4; ++r) {
                int row = rbase + r;
                float v = acc[m][n][r] + bias[col] + pos[(long)(row & 255)*768 + col];
                Cz[(long)row * 768 + col] = v;
            }
        }
    }
}

// ============ batched output-proj GEMM: Y[z] = X6b[z] @ owT[z] + bias ============
struct OwDesc {
    const u16* Bt[3];
    float* C[3];
    const float* bias[3];
    int N[3];
};

__global__ __launch_bounds__(256) void gemm_ow(OwDesc d, const u16* __restrict__ A) {
    int z = blockIdx.z;
    int N = d.N[z];
    int n0 = blockIdx.x * 64;
    if (n0 >= N) return;
    __shared__ u16 As[64][72];
    __shared__ u16 Bs[64][72];
    const u16* Ab = A + (long)z * 512 * 768;
    const u16* Bb = d.Bt[z];
    int t = threadIdx.x;
    int m0 = blockIdx.y * 64;
    int wave = t >> 6, lane = t & 63;
    int wr = wave >> 1, wc = wave & 1;
    int lrow = lane & 15;
    f4 acc[2][2];
    #pragma unroll
    for (int m = 0; m < 2; ++m)
        #pragma unroll
        for (int n = 0; n < 2; ++n)
            #pragma unroll
            for (int r = 0; r < 4; ++r) acc[m][n][r] = 0.f;
    for (int k0 = 0; k0 < 768; k0 += 64) {
        #pragma unroll
        for (int i = 0; i < 2; ++i) {
            int idx = t + i*256;
            int row = idx >> 3, c8 = (idx & 7) * 8;
            s8 av, bv;
            #pragma unroll
            for (int q = 0; q < 8; ++q) { av[q] = 0; bv[q] = 0; }
            av = *reinterpret_cast<const s8*>(Ab + (long)(m0 + row)*768 + k0 + c8);
            if (n0 + row < N) bv = *reinterpret_cast<const s8*>(Bb + (long)(n0 + row)*768 + k0 + c8);
            *reinterpret_cast<s8*>(&As[row][c8]) = av;
            *reinterpret_cast<s8*>(&Bs[row][c8]) = bv;
        }
        __syncthreads();
        #pragma unroll
        for (int kh = 0; kh < 2; ++kh) {
            int lk = kh*32 + (lane >> 4) * 8;
            s8 af0 = *reinterpret_cast<const s8*>(&As[wr*32 + lrow][lk]);
            s8 af1 = *reinterpret_cast<const s8*>(&As[wr*32 + 16 + lrow][lk]);
            s8 bg0 = *reinterpret_cast<const s8*>(&Bs[wc*32 + lrow][lk]);
            s8 bg1 = *reinterpret_cast<const s8*>(&Bs[wc*32 + 16 + lrow][lk]);
            acc[0][0] = __builtin_amdgcn_mfma_f32_16x16x32_bf16(af0, bg0, acc[0][0], 0, 0, 0);
            acc[0][1] = __builtin_amdgcn_mfma_f32_16x16x32_bf16(af0, bg1, acc[0][1], 0, 0, 0);
            acc[1][0] = __builtin_amdgcn_mfma_f32_16x16x32_bf16(af1, bg0, acc[1][0], 0, 0, 0);
            acc[1][1] = __builtin_amdgcn_mfma_f32_16x16x32_bf16(af1, bg1, acc[1][1], 0, 0, 0);
        }
        __syncthreads();
    }
    float* Cz = d.C[z];
    const float* bias = d.bias[z];
    #pragma unroll
    for (int m = 0; m < 2; ++m) {
        int rbase = m0 + wr*32 + m*16 + (lane >> 4) * 4;
        #pragma unroll
        for (int n = 0; n < 2; ++n) {
            int col = n0 + wc*32 + n*16 + (lane & 15);
            if (col >= N) continue;
            #pragma unroll
            for (int r = 0; r < 4; ++r) {
                int row = rbase + r;
                Cz[(long)row * N + col] = acc[m][n][r] + bias[col];
            }
        }
    }
}

// ============ LayerNorm rows of 768 ============
__global__ __launch_bounds__(256) void ln_k(const float* __restrict__ in,
                                            float* __restrict__ outf,
                                            u16* __restrict__ outb,
                                            const float* __restrict__ g,
                                            const float* __restrict__ bta) {
    constexpr int N = 768;
    int row = blockIdx.x;
    const float* x = in + (size_t)row * N;
    int t = threadIdx.x;
    float v0 = x[t], v1 = x[t+256], v2 = x[t+512];
    float s = v0+v1+v2, s2 = v0*v0+v1*v1+v2*v2;
    #pragma unroll
    for (int off = 32; off > 0; off >>= 1) { s += __shfl_down(s, off); s2 += __shfl_down(s2, off); }
    __shared__ float red[8];
    int wid = t >> 6, lane = t & 63;
    if (lane == 0) { red[wid] = s; red[wid+4] = s2; }
    __syncthreads();
    if (t == 0) {
        float S = red[0]+red[1]+red[2]+red[3];
        float S2 = red[4]+red[5]+red[6]+red[7];
        float mean = S * (1.f/N);
        float var = S2 * (1.f/N) - mean*mean;
        red[0] = mean; red[1] = rsqrtf(var + 1e-5f);
    }
    __syncthreads();
    float mean = red[0], rstd = red[1];
    float y0 = (v0-mean)*rstd*g[t]     + bta[t];
    float y1 = (v1-mean)*rstd*g[t+256] + bta[t+256];
    float y2 = (v2-mean)*rstd*g[t+512] + bta[t+512];
    if (outf) {
        float* y = outf + (size_t)row * N;
        y[t] = y0; y[t+256] = y1; y[t+512] = y2;
    }
    if (outb) {
        u16* y = outb + (size_t)row * N;
        y[t] = f2bf(y0); y[t+256] = f2bf(y1); y[t+512] = f2bf(y2);
    }
}

// ============ V transpose per head (inside QKV buffer, ld 2304, V at col 1536) ============
__global__ void vt_k(const u16* __restrict__ QKV, u16* __restrict__ Vt) {
    int idx = blockIdx.x*256 + threadIdx.x;
    if (idx >= 72*64*256) return;
    int j = idx & 255, rest = idx >> 8;
    int d = rest & 63, z = rest >> 6;
    Vt[idx] = QKV[((long)(z/12)*256 + j)*2304 + 1536 + (long)(z%12)*64 + d];
}

// ============ row softmax on S[72*256][256] -> bf16 P ============
__global__ __launch_bounds__(256) void softmax_k(const float* __restrict__ S,
                                                 u16* __restrict__ P) {
    int row = blockIdx.x*4 + (threadIdx.x >> 6);
    int lane = threadIdx.x & 63;
    const float4 v = *reinterpret_cast<const float4*>(S + (long)row*256 + lane*4);
    float m = fmaxf(fmaxf(v.x, v.y), fmaxf(v.z, v.w));
    #pragma unroll
    for (int o = 32; o; o >>= 1) m = fmaxf(m, __shfl_xor(m, o));
    float p0 = __expf(v.x - m), p1 = __expf(v.y - m), p2 = __expf(v.z - m), p3 = __expf(v.w - m);
    float l = p0 + p1 + p2 + p3;
    #pragma unroll
    for (int o = 32; o; o >>= 1) l += __shfl_xor(l, o);
    float inv = 1.f / l;
    unsigned b0 = f2bf(p0*inv), b1 = f2bf(p1*inv), b2 = f2bf(p2*inv), b3 = f2bf(p3*inv);
    uint2 pk; pk.x = b0 | (b1 << 16); pk.y = b2 | (b3 << 16);
    *reinterpret_cast<uint2*>(P + (long)row*256 + lane*4) = pk;
}

// ============ cross-attn colsum-softmax: W[z][j] = sum_i softmax_j(S2[z][i][:]) ============
__global__ __launch_bounds__(256) void ca_cs_k(const float* __restrict__ S2,
                                               float* __restrict__ W) {
    __shared__ float sl[4*256];
    int bh = blockIdx.x;            // 72
    int t = threadIdx.x;
    int w = t >> 6, lane = t & 63;
    float wacc[4] = {0.f, 0.f, 0.f, 0.f};
    for (int i = w; i < 77; i += 4) {
        const float4 v = *reinterpret_cast<const float4*>(S2 + ((long)bh*77 + i)*256 + lane*4);
        float m = fmaxf(fmaxf(v.x, v.y), fmaxf(v.z, v.w));
        #pragma unroll
        for (int o = 32; o; o >>= 1) m = fmaxf(m, __shfl_xor(m, o));
        float p0 = __expf(v.x - m), p1 = __expf(v.y - m), p2 = __expf(v.z - m), p3 = __expf(v.w - m);
        float l = p0 + p1 + p2 + p3;
        #pragma unroll
        for (int o = 32; o; o >>= 1) l += __shfl_xor(l, o);
        float inv = 1.f / l;
        wacc[0] += p0*inv; wacc[1] += p1*inv; wacc[2] += p2*inv; wacc[3] += p3*inv;
    }
    #pragma unroll
    for (int k = 0; k < 4; ++k) sl[w*256 + lane*4 + k] = wacc[k];
    __syncthreads();
    W[(long)bh*256 + t] = sl[t] + sl[256 + t] + sl[512 + t] + sl[768 + t];
}

// ============ O = W * VH (bf16 in/out) ============
__global__ void ca_apply_k(const float* __restrict__ W, const u16* __restrict__ KVHb,
                           u16* __restrict__ O) {
    int idx = blockIdx.x*256 + threadIdx.x;
    if (idx >= 1536*768) return;
    int row = idx / 768, col = idx - row*768;
    int rowblk = row >> 8, j = row & 255, h = col >> 6;
    float vh = bf2f(KVHb[(long)row*1536 + 768 + col]);
    O[idx] = f2bf(W[((long)rowblk*12 + h)*256 + j] * vh);
}

// ============ unpatchify 3 branches -> dense planes, pre-weighted ============
__global__ void unpatch3_k(const float* __restrict__ Y0, const float* __restrict__ Y1,
                           const float* __restrict__ Y2, const float* __restrict__ vw,
                           float* __restrict__ Aax, float* __restrict__ Asag,
                           float* __restrict__ Acor) {
    int idx = blockIdx.x*256 + threadIdx.x;
    if (idx >= 1949696) return;
    const float* y; float* A; float wt; int Wd, p2, PD, p;
    if (idx < 573440)       { y = Y0; A = Aax;  wt = vw[0]; Wd = 80;  p2 = 5; PD = 1120; p = idx; }
    else if (idx < 1146880) { y = Y1; A = Asag; wt = vw[1]; Wd = 80;  p2 = 5; PD = 1120; p = idx - 573440; }
    else                    { y = Y2; A = Acor; wt = vw[2]; Wd = 112; p2 = 7; PD = 1568; p = idx - 1146880; }
    int w = p % Wd; int r = p / Wd;
    int h = r % 112; r /= 112;
    int c = r % 32; int b = r / 32;
    int src = (b*256 + (h/7)*16 + (w/p2))*PD + ((h%7)*p2 + (w%p2))*32 + c;
    A[p] = wt * y[src];
}

// ============ streaming final combine ============
__global__ __launch_bounds__(256) void final_k(const float* __restrict__ img,
                                               const float* __restrict__ Aax,
                                               const float* __restrict__ Asag,
                                               const float* __restrict__ Acor,
                                               float* __restrict__ out) {
    int blk = blockIdx.x;                 // bc*112 + d
    int bc = blk / 112;
    const float4* ip = reinterpret_cast<const float4*>(img + (size_t)blk * 8960);
    const float4* ap = reinterpret_cast<const float4*>(Aax + (size_t)bc * 8960);
    const float4* sp = reinterpret_cast<const float4*>(Asag + (size_t)blk * 80);
    const float*  cp = Acor + (size_t)blk * 112;
    float4* op = reinterpret_cast<float4*>(out + (size_t)blk * 8960);
    int t = threadIdx.x;
    for (int q = t; q < 2240; q += 256) {
        int h = q / 20, w4 = q % 20;
        float4 iv = ip[q], av = ap[q], sv = sp[w4];
        float cv = cp[h];
        float4 o;
        o.x = iv.x + av.x + sv.x + cv;
        o.y = iv.y + av.y + sv.y + cv;
        o.z = iv.z + av.z + sv.z + cv;
        o.w = iv.w + av.w + sv.w + cv;
        op[q] = o;
    }
}

extern "C" void kernel_launch(void* const* d_in, const int* in_sizes, int n_in,
                              void* d_out, int out_size, void* d_ws, size_t ws_size,
                              hipStream_t stream) {
    (void)in_sizes; (void)n_in; (void)out_size; (void)ws_size;
    const float* img    = (const float*)d_in[0];
    const float* txt    = (const float*)d_in[1];
    const float* pe_w[3] = {(const float*)d_in[2], (const float*)d_in[4], (const float*)d_in[6]};
    const float* pe_b[3] = {(const float*)d_in[3], (const float*)d_in[5], (const float*)d_in[7]};
    const float* pos[3]  = {(const float*)d_in[8], (const float*)d_in[9], (const float*)d_in[10]};
    const float* qw = (const float*)d_in[11];
    const float* kw = (const float*)d_in[12];
    const float* vw_attn = (const float*)d_in[13];
    const float* pw = (const float*)d_in[14];
    const float* pb = (const float*)d_in[15];
    const float* caq_w = (const float*)d_in[16];
    const float* caq_b = (const float*)d_in[17];
    const float* cak_w = (const float*)d_in[18];
    const float* cak_b = (const float*)d_in[19];
    const float* cav_w = (const float*)d_in[20];
    const float* cav_b = (const float*)d_in[21];
    const float* cao_w = (const float*)d_in[22];
    const float* cao_b = (const float*)d_in[23];
    const float* mlp_w1 = (const float*)d_in[24];
    const float* mlp_b1 = (const float*)d_in[25];
    const float* mlp_w2 = (const float*)d_in[26];
    const float* mlp_b2 = (const float*)d_in[27];
    const float* ow[3] = {(const float*)d_in[28], (const float*)d_in[30], (const float*)d_in[32]};
    const float* ob[3] = {(const float*)d_in[29], (const float*)d_in[31], (const float*)d_in[33]};
    const float* view_w = (const float*)d_in[34];
    const float* n_g[3] = {(const float*)d_in[35], (const float*)d_in[36], (const float*)d_in[37]};
    const float* n_b[3] = {(const float*)d_in[38], (const float*)d_in[39], (const float*)d_in[40]};

    // ---- big scratch lives in d_out (fully rewritten by final_k) ----
    unsigned char* sb = (unsigned char*)d_out;
    size_t off = 0;
    auto B = [&](size_t bytes) -> void* {
        void* p = sb + off; off += (bytes + 511) & ~(size_t)511; return p;
    };
    u16* qkvT  = (u16*)B((size_t)2304*768*2);
    u16* pwT   = (u16*)B(768*768*2);
    u16* caqT  = (u16*)B(768*768*2);
    u16* cakvT = (u16*)B((size_t)1536*768*2);
    u16* caoT  = (u16*)B(768*768*2);
    u16* mlp1T = (u16*)B((size_t)3072*768*2);
    u16* mlp2T = (u16*)B((size_t)768*3072*2);
    u16* peT[3]; peT[0] = (u16*)B((size_t)768*1120*2); peT[1] = (u16*)B((size_t)768*1120*2); peT[2] = (u16*)B((size_t)768*1568*2);
    u16* owT[3]; owT[0] = (u16*)B((size_t)1120*768*2); owT[1] = (u16*)B((size_t)1120*768*2); owT[2] = (u16*)B((size_t)1568*768*2);
    u16* txtb = (u16*)B(154*768*2);
    float* kvb = (float*)B(1536*4);
    float* axp   = (float*)B((size_t)16*573440*4);
    float* m_ax  = (float*)B(573440*4);
    float* m_sag = (float*)B(573440*4);
    float* m_cor = (float*)B(802816*4);
    u16* P0 = (u16*)B((size_t)512*1120*2);
    u16* P1 = (u16*)B((size_t)512*1120*2);
    u16* P2 = (u16*)B((size_t)512*1568*2);
    float* X0  = (float*)B((size_t)1536*768*4);
    float* X1f = (float*)B((size_t)1536*768*4);
    float* X2  = (float*)B((size_t)1536*768*4);
    float* X3f = (float*)B((size_t)1536*768*4);
    float* X4  = (float*)B((size_t)1536*768*4);
    u16* X1b = (u16*)B((size_t)1536*768*2);
    u16* X3b = (u16*)B((size_t)1536*768*2);
    u16* X5b = (u16*)B((size_t)1536*768*2);
    u16* X6b = (u16*)B((size_t)1536*768*2);
    u16* QKVb = (u16*)B((size_t)1536*2304*2);
    u16* Obf = (u16*)B((size_t)1536*768*2);
    u16* Vt  = (u16*)B((size_t)72*64*256*2);
    u16* Hb  = (u16*)B((size_t)1536*3072*2);
    float* S  = (float*)B((size_t)72*256*256*4);
    u16* Pat = (u16*)B((size_t)72*256*256*2);
    u16* KVHb = (u16*)B((size_t)1536*1536*2);
    u16* QHb  = (u16*)B((size_t)154*768*2);
    float* S2 = (float*)B((size_t)72*77*256*4);
    float* Wb = (float*)B((size_t)72*256*4);
    float* Y[3];
    Y[0] = (float*)B(573440*4);
    Y[1] = (float*)B(573440*4);
    Y[2] = (float*)B(802816*4);

    // ---- dense view planes live in d_ws ----
    float* ws = (float*)d_ws;
    float* Aax  = ws;
    float* Asag = ws + 573440;
    float* Acor = ws + 1146880;

    // ---- batched weight transposes (1 launch) ----
    TT tab;
    {
        const float* ins[16] = {qw, kw, vw_attn, pw, caq_w, cak_w, cav_w, cao_w,
                                mlp_w1, mlp_w2, pe_w[0], pe_w[1], pe_w[2], ow[0], ow[1], ow[2]};
        u16* outs[16] = {qkvT, qkvT + 768*768, qkvT + 2*768*768, pwT, caqT, cakvT,
                         cakvT + 768*768, caoT, mlp1T, mlp2T, peT[0], peT[1], peT[2],
                         owT[0], owT[1], owT[2]};
        int Ks[16] = {768,768,768,768,768,768,768,768, 768,3072, 1120,1120,1568, 768,768,768};
        int Ns[16] = {768,768,768,768,768,768,768,768, 3072,768, 768,768,768, 1120,1120,1568};
        int st = 0;
        for (int i = 0; i < 16; ++i) {
            tab.in[i] = ins[i]; tab.out[i] = outs[i]; tab.K[i] = Ks[i]; tab.N[i] = Ns[i];
            tab.start[i] = st;
            st += (Ks[i] >> 5) * (Ns[i] >> 5);
        }
        transp_all<<<st, 256, 0, stream>>>(tab);
    }
    misc_k<<<468, 256, 0, stream>>>(txt, txtb, cak_b, cav_b, kvb);

    mean3_k<<<1024, 256, 0, stream>>>(img, axp, m_sag, m_cor);
    axred_k<<<560, 256, 0, stream>>>(axp, m_ax);
    patchify3_k<<<dim3(224,3), 256, 0, stream>>>(m_ax, m_sag, m_cor, P0, P1, P2);

    auto gemm = [&](const u16* A, const u16* Bt, float* Cf, u16* Cb,
                    int M, int N, int K, int lda, int ldb, int ldc,
                    const float* bias, const float* resid,
                    int act, float cscale, int mode, int batch) {
        dim3 g((N+63)/64, (M+63)/64, batch);
        gemm_bf<<<g, 256, 0, stream>>>(A, Bt, Cf, Cb, M, N, K, lda, ldb, ldc,
                                       bias, resid, act, cscale, mode);
    };

    // QHb = bf16(txt @ caq_w + caq_b)
    gemm(txtb, caqT, nullptr, QHb, 154, 768, 768, 768, 768, 768,
         caq_b, nullptr, 0, 1.f, 0, 1);

    // patch-embed (batched z=3)
    {
        PeDesc d;
        d.A[0] = P0; d.A[1] = P1; d.A[2] = P2;
        d.Bt[0] = peT[0]; d.Bt[1] = peT[1]; d.Bt[2] = peT[2];
        d.bias[0] = pe_b[0]; d.bias[1] = pe_b[1]; d.bias[2] = pe_b[2];
        d.pos[0] = pos[0]; d.pos[1] = pos[1]; d.pos[2] = pos[2];
        d.K[0] = 1120; d.K[1] = 1120; d.K[2] = 1568;
        gemm_pe<<<dim3(12,8,3), 256, 0, stream>>>(d, X0);
    }

    ln_k<<<1536, 256, 0, stream>>>(X0, X1f, X1b, n_g[0], n_b[0]);
    gemm(X1b, qkvT, nullptr, QKVb, 1536, 2304, 768, 768, 768, 2304,
         nullptr, nullptr, 0, 1.f, 0, 1);
    vt_k<<<4608, 256, 0, stream>>>(QKVb, Vt);
    gemm(QKVb, QKVb + 768, S, nullptr, 256, 256, 64, 2304, 2304, 256,
         nullptr, nullptr, 0, 0.125f, 1, 72);
    softmax_k<<<4608, 256, 0, stream>>>(S, Pat);
    gemm(Pat, Vt, nullptr, Obf, 256, 64, 256, 256, 256, 768,
         nullptr, nullptr, 0, 1.f, 2, 72);
    gemm(Obf, pwT, X2, nullptr, 1536, 768, 768, 768, 768, 768, pb, X1f, 0, 1.f, 0, 1);
    ln_k<<<1536, 256, 0, stream>>>(X2, X3f, X3b, n_g[1], n_b[1]);
    // fused cak||cav
    gemm(X3b, cakvT, nullptr, KVHb, 1536, 1536, 768, 768, 768, 1536,
         kvb, nullptr, 0, 1.f, 0, 1);
    // S2 = QH @ KH^T per (rowblk, head)
    gemm(QHb, KVHb, S2, nullptr, 77, 256, 64, 768, 1536, 256,
         nullptr, nullptr, 0, 0.125f, 3, 72);
    ca_cs_k<<<72, 256, 0, stream>>>(S2, Wb);
    ca_apply_k<<<4608, 256, 0, stream>>>(Wb, KVHb, Obf);
    gemm(Obf, caoT, X4, nullptr, 1536, 768, 768, 768, 768, 768, cao_b, X3f, 0, 1.f, 0, 1);
    ln_k<<<1536, 256, 0, stream>>>(X4, nullptr, X5b, n_g[2], n_b[2]);
    gemm(X5b, mlp1T, nullptr, Hb, 1536, 3072, 768, 768, 768, 3072, mlp_b1, nullptr, 1, 1.f, 0, 1);
    gemm(Hb, mlp2T, nullptr, X6b, 1536, 768, 3072, 3072, 3072, 768, mlp_b2, X4, 0, 1.f, 0, 1);
    // output projections (batched z=3)
    {
        OwDesc d;
        d.Bt[0] = owT[0]; d.Bt[1] = owT[1]; d.Bt[2] = owT[2];
        d.C[0] = Y[0]; d.C[1] = Y[1]; d.C[2] = Y[2];
        d.bias[0] = ob[0]; d.bias[1] = ob[1]; d.bias[2] = ob[2];
        d.N[0] = 1120; d.N[1] = 1120; d.N[2] = 1568;
        gemm_ow<<<dim3(25,8,3), 256, 0, stream>>>(d, X6b);
    }

    unpatch3_k<<<7616, 256, 0, stream>>>(Y[0], Y[1], Y[2], view_w, Aax, Asag, Acor);
    final_k<<<7168, 256, 0, stream>>>(img, Aax, Asag, Acor, (float*)d_out);
}

// Round 6
// 493.073 us; speedup vs baseline: 15.5766x; 1.1035x over previous
//
#include <hip/hip_runtime.h>
#include <math.h>

typedef __attribute__((ext_vector_type(8))) short s8;
typedef __attribute__((ext_vector_type(4))) float f4;
typedef unsigned short u16;

__device__ inline u16 f2bf(float f) {
    unsigned u = __float_as_uint(f);
    u += 0x7fffu + ((u >> 16) & 1u);
    return (u16)(u >> 16);
}
__device__ inline float bf2f(u16 x) {
    return __uint_as_float(((unsigned)x) << 16);
}

// ============ fused axis means, no atomics ============
__global__ __launch_bounds__(256) void mean3_k(const float* __restrict__ img,
                                               float* __restrict__ axp,
                                               float* __restrict__ sag,
                                               float* __restrict__ cor) {
    __shared__ float sl[112*81];
    int blk = blockIdx.x;
    int dc = blk & 15, bc = blk >> 4;
    int d0 = dc * 7;
    int t = threadIdx.x;
    f4 axr[9];
    #pragma unroll
    for (int k = 0; k < 9; ++k) axr[k] = (f4){0.f,0.f,0.f,0.f};
    const float* base = img + (size_t)bc * 1003520 + (size_t)d0 * 8960;
    for (int sidx = 0; sidx < 7; ++sidx) {
        const f4* sp = reinterpret_cast<const f4*>(base + (size_t)sidx * 8960);
        #pragma unroll
        for (int k = 0; k < 9; ++k) {
            int q = t + k * 256;
            if (q < 2240) {
                f4 v = sp[q];
                axr[k] += v;
                int h = q / 20, w4 = q % 20;
                float* row = &sl[h * 81 + w4 * 4];
                row[0] = v[0]; row[1] = v[1]; row[2] = v[2]; row[3] = v[3];
            }
        }
        __syncthreads();
        if (t < 112) {
            float acc = 0.f;
            #pragma unroll 8
            for (int w = 0; w < 80; ++w) acc += sl[t * 81 + w];
            cor[((size_t)bc * 112 + d0 + sidx) * 112 + t] = acc * (1.f / 80.f);
        } else if (t < 192) {
            int w = t - 112;
            float acc = 0.f;
            #pragma unroll 8
            for (int h = 0; h < 112; ++h) acc += sl[h * 81 + w];
            sag[((size_t)bc * 112 + d0 + sidx) * 80 + w] = acc * (1.f / 112.f);
        }
        __syncthreads();
    }
    float* axo = axp + ((size_t)dc * 64 + bc) * 8960;
    #pragma unroll
    for (int k = 0; k < 9; ++k) {
        int q = t + k * 256;
        if (q < 2240) *reinterpret_cast<f4*>(axo + q * 4) = axr[k];
    }
}

__global__ void axred_k(const float* __restrict__ axp, float* __restrict__ ax) {
    int idx = blockIdx.x * 256 + threadIdx.x;
    if (idx >= 143360) return;
    f4 s = (f4){0.f,0.f,0.f,0.f};
    #pragma unroll
    for (int i = 0; i < 16; ++i)
        s += *reinterpret_cast<const f4*>(axp + (size_t)i * 573440 + (size_t)idx * 4);
    s *= (1.f / 112.f);
    *reinterpret_cast<f4*>(ax + (size_t)idx * 4) = s;
}

// ============ batched transpose-convert: f32 [K][N] -> bf16 [N][K] ============
struct TT {
    const float* in[16];
    u16* out[16];
    int K[16];
    int N[16];
    int start[16];
};

__global__ __launch_bounds__(256) void transp_all(TT tab) {
    __shared__ float tl[32][33];
    int bid = blockIdx.x;
    int e = 0;
    #pragma unroll
    for (int i = 1; i < 16; ++i) if (bid >= tab.start[i]) e = i;
    const float* in = tab.in[e];
    u16* out = tab.out[e];
    int K = tab.K[e], N = tab.N[e];
    int tid = bid - tab.start[e];
    int nt = N >> 5;
    int k0 = (tid / nt) * 32, n0 = (tid % nt) * 32;
    int t = threadIdx.x;
    int r = t >> 5, c = t & 31;
    #pragma unroll
    for (int i = 0; i < 4; ++i) tl[r + i*8][c] = in[(long)(k0 + r + i*8)*N + n0 + c];
    __syncthreads();
    #pragma unroll
    for (int i = 0; i < 4; ++i) out[(long)(n0 + r + i*8)*K + k0 + c] = f2bf(tl[c][r + i*8]);
}

// ============ misc: txt cvt + kv bias concat ============
__global__ void misc_k(const float* __restrict__ txt, u16* __restrict__ txtb,
                       const float* __restrict__ cak_b, const float* __restrict__ cav_b,
                       float* __restrict__ kvb) {
    int idx = blockIdx.x*256 + threadIdx.x;
    if (idx < 118272) { txtb[idx] = f2bf(txt[idx]); return; }
    int i2 = idx - 118272;
    if (i2 < 768) kvb[i2] = cak_b[i2];
    else if (i2 < 1536) kvb[i2] = cav_b[i2 - 768];
}

// ============ patchify (LDS transpose, coalesced), 3 branches ============
__global__ __launch_bounds__(256) void patchify3_k(const float* __restrict__ m_ax,
                                                   const float* __restrict__ m_sag,
                                                   const float* __restrict__ m_cor,
                                                   u16* __restrict__ P0, u16* __restrict__ P1,
                                                   u16* __restrict__ P2) {
    __shared__ float sl[32][113];
    int br = blockIdx.y;
    int X = blockIdx.x;                       // 224 = b(2) * hh(16) * pp1(7)
    int b = X / 112, rem = X % 112;
    int hh = rem / 7, pp1 = rem % 7;
    const float* src; u16* dst; int Wt, p2, PD;
    if (br == 0)      { src = m_ax;  dst = P0; Wt = 80;  p2 = 5; PD = 1120; }
    else if (br == 1) { src = m_sag; dst = P1; Wt = 80;  p2 = 5; PD = 1120; }
    else              { src = m_cor; dst = P2; Wt = 112; p2 = 7; PD = 1568; }
    int t = threadIdx.x;
    int row = hh*7 + pp1;
    int wq = Wt >> 2;
    for (int i = t; i < 32*wq; i += 256) {
        int c = i / wq, w4 = i % wq;
        float4 v = *reinterpret_cast<const float4*>(
            src + ((size_t)(b*32 + c)*112 + row)*Wt + w4*4);
        sl[c][w4*4+0] = v.x; sl[c][w4*4+1] = v.y; sl[c][w4*4+2] = v.z; sl[c][w4*4+3] = v.w;
    }
    __syncthreads();
    int tot = 16 * p2 * 32;
    for (int o = t; o < tot; o += 256) {
        int ww = o / (p2*32), rest = o % (p2*32);
        int pp2 = rest >> 5, c = rest & 31;
        dst[((size_t)(b*256 + hh*16 + ww))*PD + (pp1*p2 + pp2)*32 + c]
            = f2bf(sl[c][ww*p2 + pp2]);
    }
}

// ============ GEMM building blocks: BK=128, double-buffered LDS ============
__device__ inline void load_tile(const u16* __restrict__ P, int ld, int nrows, int K,
                                 int r0, int k0, int t, s8 v[4]) {
    #pragma unroll
    for (int i = 0; i < 4; ++i) {
        int chunk = t + i*256;
        int row = chunk >> 4, c8 = (chunk & 15) * 8;
        s8 x;
        #pragma unroll
        for (int q = 0; q < 8; ++q) x[q] = 0;
        if (r0 + row < nrows && k0 + c8 < K)
            x = *reinterpret_cast<const s8*>(P + (long)(r0 + row)*ld + k0 + c8);
        v[i] = x;
    }
}
__device__ inline void write_tile(u16 (*S)[136], int t, const s8 v[4]) {
    #pragma unroll
    for (int i = 0; i < 4; ++i) {
        int chunk = t + i*256;
        *reinterpret_cast<s8*>(&S[chunk >> 4][(chunk & 15)*8]) = v[i];
    }
}
__device__ inline void mfma_tile(const u16 (*As)[136], const u16 (*Bs)[136],
                                 int wr, int wc, int lane, f4 acc[2][2]) {
    int lrow = lane & 15;
    #pragma unroll
    for (int kh = 0; kh < 4; ++kh) {
        int lk = kh*32 + (lane >> 4) * 8;
        s8 af0 = *reinterpret_cast<const s8*>(&As[wr*32 + lrow][lk]);
        s8 af1 = *reinterpret_cast<const s8*>(&As[wr*32 + 16 + lrow][lk]);
        s8 bg0 = *reinterpret_cast<const s8*>(&Bs[wc*32 + lrow][lk]);
        s8 bg1 = *reinterpret_cast<const s8*>(&Bs[wc*32 + 16 + lrow][lk]);
        acc[0][0] = __builtin_amdgcn_mfma_f32_16x16x32_bf16(af0, bg0, acc[0][0], 0, 0, 0);
        acc[0][1] = __builtin_amdgcn_mfma_f32_16x16x32_bf16(af0, bg1, acc[0][1], 0, 0, 0);
        acc[1][0] = __builtin_amdgcn_mfma_f32_16x16x32_bf16(af1, bg0, acc[1][0], 0, 0, 0);
        acc[1][1] = __builtin_amdgcn_mfma_f32_16x16x32_bf16(af1, bg1, acc[1][1], 0, 0, 0);
    }
}

// ============ bf16 MFMA GEMM: C = A(MxK) @ Bt(NxK)^T + epilogue ============
__global__ __launch_bounds__(256) void gemm_bf(
    const u16* __restrict__ A, const u16* __restrict__ Bt,
    float* __restrict__ Cf, u16* __restrict__ Cb,
    int M, int N, int K, int lda, int ldb, int ldc,
    const float* __restrict__ bias, const float* __restrict__ resid,
    int act, float cscale, int mode)
{
    __shared__ u16 As[2][64][136];
    __shared__ u16 Bs[2][64][136];
    const u16* Ab = A;
    const u16* Bb = Bt;
    long coff = 0;
    int z = blockIdx.z;
    if (mode == 1) {           // self-attn QK^T inside QKV buffer
        long o = (long)(z / 12) * 256 * lda + (long)(z % 12) * 64;
        Ab += o; Bb += o; coff = (long)z * 256 * ldc;
    } else if (mode == 2) {    // PV
        Ab += (long)z * 65536; Bb += (long)z * 16384;
        coff = (long)(z / 12) * 256 * ldc + (long)(z % 12) * 64;
    } else if (mode == 3) {    // cross-attn S2 = QH @ KH^T
        int rowblk = z / 12, h = z % 12;
        Ab += (long)(rowblk & 1) * 77 * lda + (long)h * 64;
        Bb += (long)rowblk * 256 * ldb + (long)h * 64;
        coff = (long)z * 77 * 256;
    }
    int t = threadIdx.x;
    int m0 = blockIdx.y * 64, n0 = blockIdx.x * 64;
    int wave = t >> 6, lane = t & 63;
    int wr = wave >> 1, wc = wave & 1;
    f4 acc[2][2];
    #pragma unroll
    for (int m = 0; m < 2; ++m)
        #pragma unroll
        for (int n = 0; n < 2; ++n)
            #pragma unroll
            for (int r = 0; r < 4; ++r) acc[m][n][r] = 0.f;
    int nk = (K + 127) >> 7;
    s8 pa[4], pbv[4];
    load_tile(Ab, lda, M, K, m0, 0, t, pa);
    load_tile(Bb, ldb, N, K, n0, 0, t, pbv);
    write_tile(As[0], t, pa);
    write_tile(Bs[0], t, pbv);
    __syncthreads();
    for (int kt = 0; kt < nk; ++kt) {
        int cur = kt & 1;
        if (kt + 1 < nk) {
            load_tile(Ab, lda, M, K, m0, (kt+1) << 7, t, pa);
            load_tile(Bb, ldb, N, K, n0, (kt+1) << 7, t, pbv);
        }
        mfma_tile(As[cur], Bs[cur], wr, wc, lane, acc);
        if (kt + 1 < nk) {
            write_tile(As[cur^1], t, pa);
            write_tile(Bs[cur^1], t, pbv);
        }
        __syncthreads();
    }
    #pragma unroll
    for (int m = 0; m < 2; ++m) {
        int rbase = m0 + wr*32 + m*16 + (lane >> 4) * 4;
        #pragma unroll
        for (int n = 0; n < 2; ++n) {
            int col = n0 + wc*32 + n*16 + (lane & 15);
            if (col >= N) continue;
            #pragma unroll
            for (int r = 0; r < 4; ++r) {
                int row = rbase + r;
                if (row >= M) continue;
                float v = acc[m][n][r];
                if (bias)  v += bias[col];
                if (resid) v += resid[(long)row * ldc + col];
                if (act == 1) v = 0.5f * v * (1.0f + erff(v * 0.70710678118654752f));
                v *= cscale;
                long ci = coff + (long)row * ldc + col;
                if (Cf) Cf[ci] = v;
                if (Cb) Cb[ci] = f2bf(v);
            }
        }
    }
}

// ============ batched patch-embed GEMM: X0[z] = P[z] @ peT[z] + bias + pos ============
struct PeDesc {
    const u16* A[3];
    const u16* Bt[3];
    const float* bias[3];
    const float* pos[3];
    int K[3];
};

__global__ __launch_bounds__(256) void gemm_pe(PeDesc d, float* __restrict__ C) {
    __shared__ u16 As[2][64][136];
    __shared__ u16 Bs[2][64][136];
    int z = blockIdx.z;
    const u16* Ab = d.A[z];
    const u16* Bb = d.Bt[z];
    const float* bias = d.bias[z];
    const float* pos = d.pos[z];
    int K = d.K[z];
    int t = threadIdx.x;
    int m0 = blockIdx.y * 64, n0 = blockIdx.x * 64;
    int wave = t >> 6, lane = t & 63;
    int wr = wave >> 1, wc = wave & 1;
    f4 acc[2][2];
    #pragma unroll
    for (int m = 0; m < 2; ++m)
        #pragma unroll
        for (int n = 0; n < 2; ++n)
            #pragma unroll
            for (int r = 0; r < 4; ++r) acc[m][n][r] = 0.f;
    int nk = (K + 127) >> 7;
    s8 pa[4], pbv[4];
    load_tile(Ab, K, 512, K, m0, 0, t, pa);
    load_tile(Bb, K, 768, K, n0, 0, t, pbv);
    write_tile(As[0], t, pa);
    write_tile(Bs[0], t, pbv);
    __syncthreads();
    for (int kt = 0; kt < nk; ++kt) {
        int cur = kt & 1;
        if (kt + 1 < nk) {
            load_tile(Ab, K, 512, K, m0, (kt+1) << 7, t, pa);
            load_tile(Bb, K, 768, K, n0, (kt+1) << 7, t, pbv);
        }
        mfma_tile(As[cur], Bs[cur], wr, wc, lane, acc);
        if (kt + 1 < nk) {
            write_tile(As[cur^1], t, pa);
            write_tile(Bs[cur^1], t, pbv);
        }
        __syncthreads();
    }
    float* Cz = C + (long)z * 512 * 768;
    #pragma unroll
    for (int m = 0; m < 2; ++m) {
        int rbase = m0 + wr*32 + m*16 + (lane >> 4) * 4;
        #pragma unroll
        for (int n = 0; n < 2; ++n) {
            int col = n0 + wc*32 + n*16 + (lane & 15);
            #pragma unroll
            for (int r = 0; r < 4; ++r) {
                int row = rbase + r;
                float v = acc[m][n][r] + bias[col] + pos[(long)(row & 255)*768 + col];
                Cz[(long)row * 768 + col] = v;
            }
        }
    }
}

// ============ batched output-proj GEMM: Y[z] = X6b[z] @ owT[z] + bias ============
struct OwDesc {
    const u16* Bt[3];
    float* C[3];
    const float* bias[3];
    int N[3];
};

__global__ __launch_bounds__(256) void gemm_ow(OwDesc d, const u16* __restrict__ A) {
    int z = blockIdx.z;
    int N = d.N[z];
    int n0 = blockIdx.x * 64;
    if (n0 >= N) return;
    __shared__ u16 As[2][64][136];
    __shared__ u16 Bs[2][64][136];
    const u16* Ab = A + (long)z * 512 * 768;
    const u16* Bb = d.Bt[z];
    int t = threadIdx.x;
    int m0 = blockIdx.y * 64;
    int wave = t >> 6, lane = t & 63;
    int wr = wave >> 1, wc = wave & 1;
    f4 acc[2][2];
    #pragma unroll
    for (int m = 0; m < 2; ++m)
        #pragma unroll
        for (int n = 0; n < 2; ++n)
            #pragma unroll
            for (int r = 0; r < 4; ++r) acc[m][n][r] = 0.f;
    s8 pa[4], pbv[4];
    load_tile(Ab, 768, 512, 768, m0, 0, t, pa);
    load_tile(Bb, 768, N, 768, n0, 0, t, pbv);
    write_tile(As[0], t, pa);
    write_tile(Bs[0], t, pbv);
    __syncthreads();
    for (int kt = 0; kt < 6; ++kt) {
        int cur = kt & 1;
        if (kt + 1 < 6) {
            load_tile(Ab, 768, 512, 768, m0, (kt+1) << 7, t, pa);
            load_tile(Bb, 768, N, 768, n0, (kt+1) << 7, t, pbv);
        }
        mfma_tile(As[cur], Bs[cur], wr, wc, lane, acc);
        if (kt + 1 < 6) {
            write_tile(As[cur^1], t, pa);
            write_tile(Bs[cur^1], t, pbv);
        }
        __syncthreads();
    }
    float* Cz = d.C[z];
    const float* bias = d.bias[z];
    #pragma unroll
    for (int m = 0; m < 2; ++m) {
        int rbase = m0 + wr*32 + m*16 + (lane >> 4) * 4;
        #pragma unroll
        for (int n = 0; n < 2; ++n) {
            int col = n0 + wc*32 + n*16 + (lane & 15);
            if (col >= N) continue;
            #pragma unroll
            for (int r = 0; r < 4; ++r) {
                int row = rbase + r;
                Cz[(long)row * N + col] = acc[m][n][r] + bias[col];
            }
        }
    }
}

// ============ LayerNorm rows of 768 ============
__global__ __launch_bounds__(256) void ln_k(const float* __restrict__ in,
                                            float* __restrict__ outf,
                                            u16* __restrict__ outb,
                                            const float* __restrict__ g,
                                            const float* __restrict__ bta) {
    constexpr int N = 768;
    int row = blockIdx.x;
    const float* x = in + (size_t)row * N;
    int t = threadIdx.x;
    float v0 = x[t], v1 = x[t+256], v2 = x[t+512];
    float s = v0+v1+v2, s2 = v0*v0+v1*v1+v2*v2;
    #pragma unroll
    for (int off = 32; off > 0; off >>= 1) { s += __shfl_down(s, off); s2 += __shfl_down(s2, off); }
    __shared__ float red[8];
    int wid = t >> 6, lane = t & 63;
    if (lane == 0) { red[wid] = s; red[wid+4] = s2; }
    __syncthreads();
    if (t == 0) {
        float S = red[0]+red[1]+red[2]+red[3];
        float S2 = red[4]+red[5]+red[6]+red[7];
        float mean = S * (1.f/N);
        float var = S2 * (1.f/N) - mean*mean;
        red[0] = mean; red[1] = rsqrtf(var + 1e-5f);
    }
    __syncthreads();
    float mean = red[0], rstd = red[1];
    float y0 = (v0-mean)*rstd*g[t]     + bta[t];
    float y1 = (v1-mean)*rstd*g[t+256] + bta[t+256];
    float y2 = (v2-mean)*rstd*g[t+512] + bta[t+512];
    if (outf) {
        float* y = outf + (size_t)row * N;
        y[t] = y0; y[t+256] = y1; y[t+512] = y2;
    }
    if (outb) {
        u16* y = outb + (size_t)row * N;
        y[t] = f2bf(y0); y[t+256] = f2bf(y1); y[t+512] = f2bf(y2);
    }
}

// ============ V transpose per head (inside QKV buffer, ld 2304, V at col 1536) ============
__global__ void vt_k(const u16* __restrict__ QKV, u16* __restrict__ Vt) {
    int idx = blockIdx.x*256 + threadIdx.x;
    if (idx >= 72*64*256) return;
    int j = idx & 255, rest = idx >> 8;
    int d = rest & 63, z = rest >> 6;
    Vt[idx] = QKV[((long)(z/12)*256 + j)*2304 + 1536 + (long)(z%12)*64 + d];
}

// ============ row softmax on S[72*256][256] -> bf16 P ============
__global__ __launch_bounds__(256) void softmax_k(const float* __restrict__ S,
                                                 u16* __restrict__ P) {
    int row = blockIdx.x*4 + (threadIdx.x >> 6);
    int lane = threadIdx.x & 63;
    const float4 v = *reinterpret_cast<const float4*>(S + (long)row*256 + lane*4);
    float m = fmaxf(fmaxf(v.x, v.y), fmaxf(v.z, v.w));
    #pragma unroll
    for (int o = 32; o; o >>= 1) m = fmaxf(m, __shfl_xor(m, o));
    float p0 = __expf(v.x - m), p1 = __expf(v.y - m), p2 = __expf(v.z - m), p3 = __expf(v.w - m);
    float l = p0 + p1 + p2 + p3;
    #pragma unroll
    for (int o = 32; o; o >>= 1) l += __shfl_xor(l, o);
    float inv = 1.f / l;
    unsigned b0 = f2bf(p0*inv), b1 = f2bf(p1*inv), b2 = f2bf(p2*inv), b3 = f2bf(p3*inv);
    uint2 pk; pk.x = b0 | (b1 << 16); pk.y = b2 | (b3 << 16);
    *reinterpret_cast<uint2*>(P + (long)row*256 + lane*4) = pk;
}

// ============ cross-attn colsum-softmax: W[z][j] = sum_i softmax_j(S2[z][i][:]) ============
__global__ __launch_bounds__(256) void ca_cs_k(const float* __restrict__ S2,
                                               float* __restrict__ W) {
    __shared__ float sl[4*256];
    int bh = blockIdx.x;            // 72
    int t = threadIdx.x;
    int w = t >> 6, lane = t & 63;
    float wacc[4] = {0.f, 0.f, 0.f, 0.f};
    for (int i = w; i < 77; i += 4) {
        const float4 v = *reinterpret_cast<const float4*>(S2 + ((long)bh*77 + i)*256 + lane*4);
        float m = fmaxf(fmaxf(v.x, v.y), fmaxf(v.z, v.w));
        #pragma unroll
        for (int o = 32; o; o >>= 1) m = fmaxf(m, __shfl_xor(m, o));
        float p0 = __expf(v.x - m), p1 = __expf(v.y - m), p2 = __expf(v.z - m), p3 = __expf(v.w - m);
        float l = p0 + p1 + p2 + p3;
        #pragma unroll
        for (int o = 32; o; o >>= 1) l += __shfl_xor(l, o);
        float inv = 1.f / l;
        wacc[0] += p0*inv; wacc[1] += p1*inv; wacc[2] += p2*inv; wacc[3] += p3*inv;
    }
    #pragma unroll
    for (int k = 0; k < 4; ++k) sl[w*256 + lane*4 + k] = wacc[k];
    __syncthreads();
    W[(long)bh*256 + t] = sl[t] + sl[256 + t] + sl[512 + t] + sl[768 + t];
}

// ============ O = W * VH (bf16 in/out) ============
__global__ void ca_apply_k(const float* __restrict__ W, const u16* __restrict__ KVHb,
                           u16* __restrict__ O) {
    int idx = blockIdx.x*256 + threadIdx.x;
    if (idx >= 1536*768) return;
    int row = idx / 768, col = idx - row*768;
    int rowblk = row >> 8, j = row & 255, h = col >> 6;
    float vh = bf2f(KVHb[(long)row*1536 + 768 + col]);
    O[idx] = f2bf(W[((long)rowblk*12 + h)*256 + j] * vh);
}

// ============ unpatchify 3 branches -> dense planes, pre-weighted ============
__global__ void unpatch3_k(const float* __restrict__ Y0, const float* __restrict__ Y1,
                           const float* __restrict__ Y2, const float* __restrict__ vw,
                           float* __restrict__ Aax, float* __restrict__ Asag,
                           float* __restrict__ Acor) {
    int idx = blockIdx.x*256 + threadIdx.x;
    if (idx >= 1949696) return;
    const float* y; float* A; float wt; int Wd, p2, PD, p;
    if (idx < 573440)       { y = Y0; A = Aax;  wt = vw[0]; Wd = 80;  p2 = 5; PD = 1120; p = idx; }
    else if (idx < 1146880) { y = Y1; A = Asag; wt = vw[1]; Wd = 80;  p2 = 5; PD = 1120; p = idx - 573440; }
    else                    { y = Y2; A = Acor; wt = vw[2]; Wd = 112; p2 = 7; PD = 1568; p = idx - 1146880; }
    int w = p % Wd; int r = p / Wd;
    int h = r % 112; r /= 112;
    int c = r % 32; int b = r / 32;
    int src = (b*256 + (h/7)*16 + (w/p2))*PD + ((h%7)*p2 + (w%p2))*32 + c;
    A[p] = wt * y[src];
}

// ============ streaming final combine ============
__global__ __launch_bounds__(256) void final_k(const float* __restrict__ img,
                                               const float* __restrict__ Aax,
                                               const float* __restrict__ Asag,
                                               const float* __restrict__ Acor,
                                               float* __restrict__ out) {
    int blk = blockIdx.x;                 // bc*112 + d
    int bc = blk / 112;
    const float4* ip = reinterpret_cast<const float4*>(img + (size_t)blk * 8960);
    const float4* ap = reinterpret_cast<const float4*>(Aax + (size_t)bc * 8960);
    const float4* sp = reinterpret_cast<const float4*>(Asag + (size_t)blk * 80);
    const float*  cp = Acor + (size_t)blk * 112;
    float4* op = reinterpret_cast<float4*>(out + (size_t)blk * 8960);
    int t = threadIdx.x;
    for (int q = t; q < 2240; q += 256) {
        int h = q / 20, w4 = q % 20;
        float4 iv = ip[q], av = ap[q], sv = sp[w4];
        float cv = cp[h];
        float4 o;
        o.x = iv.x + av.x + sv.x + cv;
        o.y = iv.y + av.y + sv.y + cv;
        o.z = iv.z + av.z + sv.z + cv;
        o.w = iv.w + av.w + sv.w + cv;
        op[q] = o;
    }
}

extern "C" void kernel_launch(void* const* d_in, const int* in_sizes, int n_in,
                              void* d_out, int out_size, void* d_ws, size_t ws_size,
                              hipStream_t stream) {
    (void)in_sizes; (void)n_in; (void)out_size; (void)ws_size;
    const float* img    = (const float*)d_in[0];
    const float* txt    = (const float*)d_in[1];
    const float* pe_w[3] = {(const float*)d_in[2], (const float*)d_in[4], (const float*)d_in[6]};
    const float* pe_b[3] = {(const float*)d_in[3], (const float*)d_in[5], (const float*)d_in[7]};
    const float* pos[3]  = {(const float*)d_in[8], (const float*)d_in[9], (const float*)d_in[10]};
    const float* qw = (const float*)d_in[11];
    const float* kw = (const float*)d_in[12];
    const float* vw_attn = (const float*)d_in[13];
    const float* pw = (const float*)d_in[14];
    const float* pb = (const float*)d_in[15];
    const float* caq_w = (const float*)d_in[16];
    const float* caq_b = (const float*)d_in[17];
    const float* cak_w = (const float*)d_in[18];
    const float* cak_b = (const float*)d_in[19];
    const float* cav_w = (const float*)d_in[20];
    const float* cav_b = (const float*)d_in[21];
    const float* cao_w = (const float*)d_in[22];
    const float* cao_b = (const float*)d_in[23];
    const float* mlp_w1 = (const float*)d_in[24];
    const float* mlp_b1 = (const float*)d_in[25];
    const float* mlp_w2 = (const float*)d_in[26];
    const float* mlp_b2 = (const float*)d_in[27];
    const float* ow[3] = {(const float*)d_in[28], (const float*)d_in[30], (const float*)d_in[32]};
    const float* ob[3] = {(const float*)d_in[29], (const float*)d_in[31], (const float*)d_in[33]};
    const float* view_w = (const float*)d_in[34];
    const float* n_g[3] = {(const float*)d_in[35], (const float*)d_in[36], (const float*)d_in[37]};
    const float* n_b[3] = {(const float*)d_in[38], (const float*)d_in[39], (const float*)d_in[40]};

    // ---- big scratch lives in d_out (fully rewritten by final_k) ----
    unsigned char* sb = (unsigned char*)d_out;
    size_t off = 0;
    auto B = [&](size_t bytes) -> void* {
        void* p = sb + off; off += (bytes + 511) & ~(size_t)511; return p;
    };
    u16* qkvT  = (u16*)B((size_t)2304*768*2);
    u16* pwT   = (u16*)B(768*768*2);
    u16* caqT  = (u16*)B(768*768*2);
    u16* cakvT = (u16*)B((size_t)1536*768*2);
    u16* caoT  = (u16*)B(768*768*2);
    u16* mlp1T = (u16*)B((size_t)3072*768*2);
    u16* mlp2T = (u16*)B((size_t)768*3072*2);
    u16* peT[3]; peT[0] = (u16*)B((size_t)768*1120*2); peT[1] = (u16*)B((size_t)768*1120*2); peT[2] = (u16*)B((size_t)768*1568*2);
    u16* owT[3]; owT[0] = (u16*)B((size_t)1120*768*2); owT[1] = (u16*)B((size_t)1120*768*2); owT[2] = (u16*)B((size_t)1568*768*2);
    u16* txtb = (u16*)B(154*768*2);
    float* kvb = (float*)B(1536*4);
    float* axp   = (float*)B((size_t)16*573440*4);
    float* m_ax  = (float*)B(573440*4);
    float* m_sag = (float*)B(573440*4);
    float* m_cor = (float*)B(802816*4);
    u16* P0 = (u16*)B((size_t)512*1120*2);
    u16* P1 = (u16*)B((size_t)512*1120*2);
    u16* P2 = (u16*)B((size_t)512*1568*2);
    float* X0  = (float*)B((size_t)1536*768*4);
    float* X1f = (float*)B((size_t)1536*768*4);
    float* X2  = (float*)B((size_t)1536*768*4);
    float* X3f = (float*)B((size_t)1536*768*4);
    float* X4  = (float*)B((size_t)1536*768*4);
    u16* X1b = (u16*)B((size_t)1536*768*2);
    u16* X3b = (u16*)B((size_t)1536*768*2);
    u16* X5b = (u16*)B((size_t)1536*768*2);
    u16* X6b = (u16*)B((size_t)1536*768*2);
    u16* QKVb = (u16*)B((size_t)1536*2304*2);
    u16* Obf = (u16*)B((size_t)1536*768*2);
    u16* Vt  = (u16*)B((size_t)72*64*256*2);
    u16* Hb  = (u16*)B((size_t)1536*3072*2);
    float* S  = (float*)B((size_t)72*256*256*4);
    u16* Pat = (u16*)B((size_t)72*256*256*2);
    u16* KVHb = (u16*)B((size_t)1536*1536*2);
    u16* QHb  = (u16*)B((size_t)154*768*2);
    float* S2 = (float*)B((size_t)72*77*256*4);
    float* Wb = (float*)B((size_t)72*256*4);
    float* Y[3];
    Y[0] = (float*)B(573440*4);
    Y[1] = (float*)B(573440*4);
    Y[2] = (float*)B(802816*4);

    // ---- dense view planes live in d_ws ----
    float* ws = (float*)d_ws;
    float* Aax  = ws;
    float* Asag = ws + 573440;
    float* Acor = ws + 1146880;

    // ---- batched weight transposes (1 launch) ----
    TT tab;
    {
        const float* ins[16] = {qw, kw, vw_attn, pw, caq_w, cak_w, cav_w, cao_w,
                                mlp_w1, mlp_w2, pe_w[0], pe_w[1], pe_w[2], ow[0], ow[1], ow[2]};
        u16* outs[16] = {qkvT, qkvT + 768*768, qkvT + 2*768*768, pwT, caqT, cakvT,
                         cakvT + 768*768, caoT, mlp1T, mlp2T, peT[0], peT[1], peT[2],
                         owT[0], owT[1], owT[2]};
        int Ks[16] = {768,768,768,768,768,768,768,768, 768,3072, 1120,1120,1568, 768,768,768};
        int Ns[16] = {768,768,768,768,768,768,768,768, 3072,768, 768,768,768, 1120,1120,1568};
        int st = 0;
        for (int i = 0; i < 16; ++i) {
            tab.in[i] = ins[i]; tab.out[i] = outs[i]; tab.K[i] = Ks[i]; tab.N[i] = Ns[i];
            tab.start[i] = st;
            st += (Ks[i] >> 5) * (Ns[i] >> 5);
        }
        transp_all<<<st, 256, 0, stream>>>(tab);
    }
    misc_k<<<468, 256, 0, stream>>>(txt, txtb, cak_b, cav_b, kvb);

    mean3_k<<<1024, 256, 0, stream>>>(img, axp, m_sag, m_cor);
    axred_k<<<560, 256, 0, stream>>>(axp, m_ax);
    patchify3_k<<<dim3(224,3), 256, 0, stream>>>(m_ax, m_sag, m_cor, P0, P1, P2);

    auto gemm = [&](const u16* A, const u16* Bt, float* Cf, u16* Cb,
                    int M, int N, int K, int lda, int ldb, int ldc,
                    const float* bias, const float* resid,
                    int act, float cscale, int mode, int batch) {
        dim3 g((N+63)/64, (M+63)/64, batch);
        gemm_bf<<<g, 256, 0, stream>>>(A, Bt, Cf, Cb, M, N, K, lda, ldb, ldc,
                                       bias, resid, act, cscale, mode);
    };

    // QHb = bf16(txt @ caq_w + caq_b)
    gemm(txtb, caqT, nullptr, QHb, 154, 768, 768, 768, 768, 768,
         caq_b, nullptr, 0, 1.f, 0, 1);

    // patch-embed (batched z=3)
    {
        PeDesc d;
        d.A[0] = P0; d.A[1] = P1; d.A[2] = P2;
        d.Bt[0] = peT[0]; d.Bt[1] = peT[1]; d.Bt[2] = peT[2];
        d.bias[0] = pe_b[0]; d.bias[1] = pe_b[1]; d.bias[2] = pe_b[2];
        d.pos[0] = pos[0]; d.pos[1] = pos[1]; d.pos[2] = pos[2];
        d.K[0] = 1120; d.K[1] = 1120; d.K[2] = 1568;
        gemm_pe<<<dim3(12,8,3), 256, 0, stream>>>(d, X0);
    }

    ln_k<<<1536, 256, 0, stream>>>(X0, X1f, X1b, n_g[0], n_b[0]);
    gemm(X1b, qkvT, nullptr, QKVb, 1536, 2304, 768, 768, 768, 2304,
         nullptr, nullptr, 0, 1.f, 0, 1);
    vt_k<<<4608, 256, 0, stream>>>(QKVb, Vt);
    gemm(QKVb, QKVb + 768, S, nullptr, 256, 256, 64, 2304, 2304, 256,
         nullptr, nullptr, 0, 0.125f, 1, 72);
    softmax_k<<<4608, 256, 0, stream>>>(S, Pat);
    gemm(Pat, Vt, nullptr, Obf, 256, 64, 256, 256, 256, 768,
         nullptr, nullptr, 0, 1.f, 2, 72);
    gemm(Obf, pwT, X2, nullptr, 1536, 768, 768, 768, 768, 768, pb, X1f, 0, 1.f, 0, 1);
    ln_k<<<1536, 256, 0, stream>>>(X2, X3f, X3b, n_g[1], n_b[1]);
    // fused cak||cav
    gemm(X3b, cakvT, nullptr, KVHb, 1536, 1536, 768, 768, 768, 1536,
         kvb, nullptr, 0, 1.f, 0, 1);
    // S2 = QH @ KH^T per (rowblk, head)
    gemm(QHb, KVHb, S2, nullptr, 77, 256, 64, 768, 1536, 256,
         nullptr, nullptr, 0, 0.125f, 3, 72);
    ca_cs_k<<<72, 256, 0, stream>>>(S2, Wb);
    ca_apply_k<<<4608, 256, 0, stream>>>(Wb, KVHb, Obf);
    gemm(Obf, caoT, X4, nullptr, 1536, 768, 768, 768, 768, 768, cao_b, X3f, 0, 1.f, 0, 1);
    ln_k<<<1536, 256, 0, stream>>>(X4, nullptr, X5b, n_g[2], n_b[2]);
    gemm(X5b, mlp1T, nullptr, Hb, 1536, 3072, 768, 768, 768, 3072, mlp_b1, nullptr, 1, 1.f, 0, 1);
    gemm(Hb, mlp2T, nullptr, X6b, 1536, 768, 3072, 3072, 3072, 768, mlp_b2, X4, 0, 1.f, 0, 1);
    // output projections (batched z=3)
    {
        OwDesc d;
        d.Bt[0] = owT[0]; d.Bt[1] = owT[1]; d.Bt[2] = owT[2];
        d.C[0] = Y[0]; d.C[1] = Y[1]; d.C[2] = Y[2];
        d.bias[0] = ob[0]; d.bias[1] = ob[1]; d.bias[2] = ob[2];
        d.N[0] = 1120; d.N[1] = 1120; d.N[2] = 1568;
        gemm_ow<<<dim3(25,8,3), 256, 0, stream>>>(d, X6b);
    }

    unpatch3_k<<<7616, 256, 0, stream>>>(Y[0], Y[1], Y[2], view_w, Aax, Asag, Acor);
    final_k<<<7168, 256, 0, stream>>>(img, Aax, Asag, Acor, (float*)d_out);
}

// Round 7
// 489.041 us; speedup vs baseline: 15.7050x; 1.0082x over previous
//
#include <hip/hip_runtime.h>
#include <math.h>

typedef __attribute__((ext_vector_type(8))) short s8;
typedef __attribute__((ext_vector_type(4))) float f4;
typedef unsigned short u16;

__device__ inline u16 f2bf(float f) {
    unsigned u = __float_as_uint(f);
    u += 0x7fffu + ((u >> 16) & 1u);
    return (u16)(u >> 16);
}
__device__ inline float bf2f(u16 x) {
    return __uint_as_float(((unsigned)x) << 16);
}

// ============ fused axis means, no atomics ============
__global__ __launch_bounds__(256) void mean3_k(const float* __restrict__ img,
                                               float* __restrict__ axp,
                                               float* __restrict__ sag,
                                               float* __restrict__ cor) {
    __shared__ float sl[112*81];
    int blk = blockIdx.x;
    int dc = blk & 15, bc = blk >> 4;
    int d0 = dc * 7;
    int t = threadIdx.x;
    f4 axr[9];
    #pragma unroll
    for (int k = 0; k < 9; ++k) axr[k] = (f4){0.f,0.f,0.f,0.f};
    const float* base = img + (size_t)bc * 1003520 + (size_t)d0 * 8960;
    for (int sidx = 0; sidx < 7; ++sidx) {
        const f4* sp = reinterpret_cast<const f4*>(base + (size_t)sidx * 8960);
        #pragma unroll
        for (int k = 0; k < 9; ++k) {
            int q = t + k * 256;
            if (q < 2240) {
                f4 v = sp[q];
                axr[k] += v;
                int h = q / 20, w4 = q % 20;
                float* row = &sl[h * 81 + w4 * 4];
                row[0] = v[0]; row[1] = v[1]; row[2] = v[2]; row[3] = v[3];
            }
        }
        __syncthreads();
        if (t < 112) {
            float acc = 0.f;
            #pragma unroll 8
            for (int w = 0; w < 80; ++w) acc += sl[t * 81 + w];
            cor[((size_t)bc * 112 + d0 + sidx) * 112 + t] = acc * (1.f / 80.f);
        } else if (t < 192) {
            int w = t - 112;
            float acc = 0.f;
            #pragma unroll 8
            for (int h = 0; h < 112; ++h) acc += sl[h * 81 + w];
            sag[((size_t)bc * 112 + d0 + sidx) * 80 + w] = acc * (1.f / 112.f);
        }
        __syncthreads();
    }
    float* axo = axp + ((size_t)dc * 64 + bc) * 8960;
    #pragma unroll
    for (int k = 0; k < 9; ++k) {
        int q = t + k * 256;
        if (q < 2240) *reinterpret_cast<f4*>(axo + q * 4) = axr[k];
    }
}

__global__ void axred_k(const float* __restrict__ axp, float* __restrict__ ax) {
    int idx = blockIdx.x * 256 + threadIdx.x;
    if (idx >= 143360) return;
    f4 s = (f4){0.f,0.f,0.f,0.f};
    #pragma unroll
    for (int i = 0; i < 16; ++i)
        s += *reinterpret_cast<const f4*>(axp + (size_t)i * 573440 + (size_t)idx * 4);
    s *= (1.f / 112.f);
    *reinterpret_cast<f4*>(ax + (size_t)idx * 4) = s;
}

// ============ batched transpose-convert: f32 [K][N] -> bf16 [N][K] ============
struct TT {
    const float* in[16];
    u16* out[16];
    int K[16];
    int N[16];
    int start[16];
};

__global__ __launch_bounds__(256) void transp_all(TT tab) {
    __shared__ float tl[32][33];
    int bid = blockIdx.x;
    int e = 0;
    #pragma unroll
    for (int i = 1; i < 16; ++i) if (bid >= tab.start[i]) e = i;
    const float* in = tab.in[e];
    u16* out = tab.out[e];
    int K = tab.K[e], N = tab.N[e];
    int tid = bid - tab.start[e];
    int nt = N >> 5;
    int k0 = (tid / nt) * 32, n0 = (tid % nt) * 32;
    int t = threadIdx.x;
    int r = t >> 5, c = t & 31;
    #pragma unroll
    for (int i = 0; i < 4; ++i) tl[r + i*8][c] = in[(long)(k0 + r + i*8)*N + n0 + c];
    __syncthreads();
    #pragma unroll
    for (int i = 0; i < 4; ++i) out[(long)(n0 + r + i*8)*K + k0 + c] = f2bf(tl[c][r + i*8]);
}

// ============ misc: txt cvt + kv bias concat ============
__global__ void misc_k(const float* __restrict__ txt, u16* __restrict__ txtb,
                       const float* __restrict__ cak_b, const float* __restrict__ cav_b,
                       float* __restrict__ kvb) {
    int idx = blockIdx.x*256 + threadIdx.x;
    if (idx < 118272) { txtb[idx] = f2bf(txt[idx]); return; }
    int i2 = idx - 118272;
    if (i2 < 768) kvb[i2] = cak_b[i2];
    else if (i2 < 1536) kvb[i2] = cav_b[i2 - 768];
}

// ============ patchify (LDS transpose, coalesced), 3 branches ============
__global__ __launch_bounds__(256) void patchify3_k(const float* __restrict__ m_ax,
                                                   const float* __restrict__ m_sag,
                                                   const float* __restrict__ m_cor,
                                                   u16* __restrict__ P0, u16* __restrict__ P1,
                                                   u16* __restrict__ P2) {
    __shared__ float sl[32][113];
    int br = blockIdx.y;
    int X = blockIdx.x;                       // 224 = b(2) * hh(16) * pp1(7)
    int b = X / 112, rem = X % 112;
    int hh = rem / 7, pp1 = rem % 7;
    const float* src; u16* dst; int Wt, p2, PD;
    if (br == 0)      { src = m_ax;  dst = P0; Wt = 80;  p2 = 5; PD = 1120; }
    else if (br == 1) { src = m_sag; dst = P1; Wt = 80;  p2 = 5; PD = 1120; }
    else              { src = m_cor; dst = P2; Wt = 112; p2 = 7; PD = 1568; }
    int t = threadIdx.x;
    int row = hh*7 + pp1;
    int wq = Wt >> 2;
    for (int i = t; i < 32*wq; i += 256) {
        int c = i / wq, w4 = i % wq;
        float4 v = *reinterpret_cast<const float4*>(
            src + ((size_t)(b*32 + c)*112 + row)*Wt + w4*4);
        sl[c][w4*4+0] = v.x; sl[c][w4*4+1] = v.y; sl[c][w4*4+2] = v.z; sl[c][w4*4+3] = v.w;
    }
    __syncthreads();
    int tot = 16 * p2 * 32;
    for (int o = t; o < tot; o += 256) {
        int ww = o / (p2*32), rest = o % (p2*32);
        int pp2 = rest >> 5, c = rest & 31;
        dst[((size_t)(b*256 + hh*16 + ww))*PD + (pp1*p2 + pp2)*32 + c]
            = f2bf(sl[c][ww*p2 + pp2]);
    }
}

// ============ GEMM building blocks (64-tile): BK=128, double-buffered LDS ============
__device__ inline void load_tile(const u16* __restrict__ P, int ld, int nrows, int K,
                                 int r0, int k0, int t, s8 v[4]) {
    #pragma unroll
    for (int i = 0; i < 4; ++i) {
        int chunk = t + i*256;
        int row = chunk >> 4, c8 = (chunk & 15) * 8;
        s8 x;
        #pragma unroll
        for (int q = 0; q < 8; ++q) x[q] = 0;
        if (r0 + row < nrows && k0 + c8 < K)
            x = *reinterpret_cast<const s8*>(P + (long)(r0 + row)*ld + k0 + c8);
        v[i] = x;
    }
}
__device__ inline void write_tile(u16 (*S)[136], int t, const s8 v[4]) {
    #pragma unroll
    for (int i = 0; i < 4; ++i) {
        int chunk = t + i*256;
        *reinterpret_cast<s8*>(&S[chunk >> 4][(chunk & 15)*8]) = v[i];
    }
}
__device__ inline void mfma_tile(const u16 (*As)[136], const u16 (*Bs)[136],
                                 int wr, int wc, int lane, f4 acc[2][2]) {
    int lrow = lane & 15;
    #pragma unroll
    for (int kh = 0; kh < 4; ++kh) {
        int lk = kh*32 + (lane >> 4) * 8;
        s8 af0 = *reinterpret_cast<const s8*>(&As[wr*32 + lrow][lk]);
        s8 af1 = *reinterpret_cast<const s8*>(&As[wr*32 + 16 + lrow][lk]);
        s8 bg0 = *reinterpret_cast<const s8*>(&Bs[wc*32 + lrow][lk]);
        s8 bg1 = *reinterpret_cast<const s8*>(&Bs[wc*32 + 16 + lrow][lk]);
        acc[0][0] = __builtin_amdgcn_mfma_f32_16x16x32_bf16(af0, bg0, acc[0][0], 0, 0, 0);
        acc[0][1] = __builtin_amdgcn_mfma_f32_16x16x32_bf16(af0, bg1, acc[0][1], 0, 0, 0);
        acc[1][0] = __builtin_amdgcn_mfma_f32_16x16x32_bf16(af1, bg0, acc[1][0], 0, 0, 0);
        acc[1][1] = __builtin_amdgcn_mfma_f32_16x16x32_bf16(af1, bg1, acc[1][1], 0, 0, 0);
    }
}

// ============ bf16 MFMA GEMM (64-tile): C = A(MxK) @ Bt(NxK)^T + epilogue ============
__global__ __launch_bounds__(256) void gemm_bf(
    const u16* __restrict__ A, const u16* __restrict__ Bt,
    float* __restrict__ Cf, u16* __restrict__ Cb,
    int M, int N, int K, int lda, int ldb, int ldc,
    const float* __restrict__ bias, const float* __restrict__ resid,
    int act, float cscale, int mode)
{
    __shared__ u16 As[2][64][136];
    __shared__ u16 Bs[2][64][136];
    const u16* Ab = A;
    const u16* Bb = Bt;
    long coff = 0;
    int z = blockIdx.z;
    if (mode == 1) {           // self-attn QK^T inside QKV buffer
        long o = (long)(z / 12) * 256 * lda + (long)(z % 12) * 64;
        Ab += o; Bb += o; coff = (long)z * 256 * ldc;
    } else if (mode == 2) {    // PV
        Ab += (long)z * 65536; Bb += (long)z * 16384;
        coff = (long)(z / 12) * 256 * ldc + (long)(z % 12) * 64;
    } else if (mode == 3) {    // cross-attn S2 = QH @ KH^T
        int rowblk = z / 12, h = z % 12;
        Ab += (long)(rowblk & 1) * 77 * lda + (long)h * 64;
        Bb += (long)rowblk * 256 * ldb + (long)h * 64;
        coff = (long)z * 77 * 256;
    }
    int t = threadIdx.x;
    int m0 = blockIdx.y * 64, n0 = blockIdx.x * 64;
    int wave = t >> 6, lane = t & 63;
    int wr = wave >> 1, wc = wave & 1;
    f4 acc[2][2];
    #pragma unroll
    for (int m = 0; m < 2; ++m)
        #pragma unroll
        for (int n = 0; n < 2; ++n)
            #pragma unroll
            for (int r = 0; r < 4; ++r) acc[m][n][r] = 0.f;
    int nk = (K + 127) >> 7;
    s8 pa[4], pbv[4];
    load_tile(Ab, lda, M, K, m0, 0, t, pa);
    load_tile(Bb, ldb, N, K, n0, 0, t, pbv);
    write_tile(As[0], t, pa);
    write_tile(Bs[0], t, pbv);
    __syncthreads();
    for (int kt = 0; kt < nk; ++kt) {
        int cur = kt & 1;
        if (kt + 1 < nk) {
            load_tile(Ab, lda, M, K, m0, (kt+1) << 7, t, pa);
            load_tile(Bb, ldb, N, K, n0, (kt+1) << 7, t, pbv);
        }
        mfma_tile(As[cur], Bs[cur], wr, wc, lane, acc);
        if (kt + 1 < nk) {
            write_tile(As[cur^1], t, pa);
            write_tile(Bs[cur^1], t, pbv);
        }
        __syncthreads();
    }
    #pragma unroll
    for (int m = 0; m < 2; ++m) {
        int rbase = m0 + wr*32 + m*16 + (lane >> 4) * 4;
        #pragma unroll
        for (int n = 0; n < 2; ++n) {
            int col = n0 + wc*32 + n*16 + (lane & 15);
            if (col >= N) continue;
            #pragma unroll
            for (int r = 0; r < 4; ++r) {
                int row = rbase + r;
                if (row >= M) continue;
                float v = acc[m][n][r];
                if (bias)  v += bias[col];
                if (resid) v += resid[(long)row * ldc + col];
                if (act == 1) v = 0.5f * v * (1.0f + erff(v * 0.70710678118654752f));
                v *= cscale;
                long ci = coff + (long)row * ldc + col;
                if (Cf) Cf[ci] = v;
                if (Cb) Cb[ci] = f2bf(v);
            }
        }
    }
}

// ============ big-tile GEMM: BM=BN=128, BK=64, dbuf; M,N,K multiples of 128/64 ============
// optional vt: transposed per-head V copy for cols >= 1536 (QKV fusion)
__global__ __launch_bounds__(256) void gemm_big(
    const u16* __restrict__ A, const u16* __restrict__ Bt,
    u16* __restrict__ Cb, u16* __restrict__ vt,
    int N, int K,
    const float* __restrict__ bias, int act)
{
    __shared__ u16 As[2][128][72];
    __shared__ u16 Bs[2][128][72];
    int t = threadIdx.x;
    int m0 = blockIdx.y * 128, n0 = blockIdx.x * 128;
    int wave = t >> 6, lane = t & 63;
    int wr = wave >> 1, wc = wave & 1;
    f4 acc[4][4];
    #pragma unroll
    for (int m = 0; m < 4; ++m)
        #pragma unroll
        for (int n = 0; n < 4; ++n)
            #pragma unroll
            for (int r = 0; r < 4; ++r) acc[m][n][r] = 0.f;
    int nk = K >> 6;
    s8 pa[4], pbv[4];
    // stage: 128 rows x 64 cols per matrix; chunk = t + i*256; row=chunk>>3, c8=(chunk&7)*8
    #pragma unroll
    for (int i = 0; i < 4; ++i) {
        int chunk = t + i*256;
        pa[i]  = *reinterpret_cast<const s8*>(A  + (long)(m0 + (chunk>>3))*K + (chunk&7)*8);
        pbv[i] = *reinterpret_cast<const s8*>(Bt + (long)(n0 + (chunk>>3))*K + (chunk&7)*8);
    }
    #pragma unroll
    for (int i = 0; i < 4; ++i) {
        int chunk = t + i*256;
        *reinterpret_cast<s8*>(&As[0][chunk>>3][(chunk&7)*8]) = pa[i];
        *reinterpret_cast<s8*>(&Bs[0][chunk>>3][(chunk&7)*8]) = pbv[i];
    }
    __syncthreads();
    for (int kt = 0; kt < nk; ++kt) {
        int cur = kt & 1;
        if (kt + 1 < nk) {
            int k0 = (kt+1) << 6;
            #pragma unroll
            for (int i = 0; i < 4; ++i) {
                int chunk = t + i*256;
                pa[i]  = *reinterpret_cast<const s8*>(A  + (long)(m0 + (chunk>>3))*K + k0 + (chunk&7)*8);
                pbv[i] = *reinterpret_cast<const s8*>(Bt + (long)(n0 + (chunk>>3))*K + k0 + (chunk&7)*8);
            }
        }
        #pragma unroll
        for (int kh = 0; kh < 2; ++kh) {
            int lk = kh*32 + (lane >> 4) * 8;
            int lr = lane & 15;
            s8 af[4], bf[4];
            #pragma unroll
            for (int m = 0; m < 4; ++m)
                af[m] = *reinterpret_cast<const s8*>(&As[cur][wr*64 + m*16 + lr][lk]);
            #pragma unroll
            for (int n = 0; n < 4; ++n)
                bf[n] = *reinterpret_cast<const s8*>(&Bs[cur][wc*64 + n*16 + lr][lk]);
            #pragma unroll
            for (int m = 0; m < 4; ++m)
                #pragma unroll
                for (int n = 0; n < 4; ++n)
                    acc[m][n] = __builtin_amdgcn_mfma_f32_16x16x32_bf16(af[m], bf[n], acc[m][n], 0, 0, 0);
        }
        if (kt + 1 < nk) {
            #pragma unroll
            for (int i = 0; i < 4; ++i) {
                int chunk = t + i*256;
                *reinterpret_cast<s8*>(&As[cur^1][chunk>>3][(chunk&7)*8]) = pa[i];
                *reinterpret_cast<s8*>(&Bs[cur^1][chunk>>3][(chunk&7)*8]) = pbv[i];
            }
        }
        __syncthreads();
    }
    #pragma unroll
    for (int m = 0; m < 4; ++m) {
        int rbase = m0 + wr*64 + m*16 + (lane >> 4) * 4;
        #pragma unroll
        for (int n = 0; n < 4; ++n) {
            int col = n0 + wc*64 + n*16 + (lane & 15);
            #pragma unroll
            for (int r = 0; r < 4; ++r) {
                int row = rbase + r;
                float v = acc[m][n][r];
                if (bias) v += bias[col];
                if (act == 1) v = 0.5f * v * (1.0f + erff(v * 0.70710678118654752f));
                u16 b = f2bf(v);
                Cb[(long)row * N + col] = b;
                if (vt && col >= 1536) {
                    int z = (row >> 8) * 12 + ((col - 1536) >> 6);
                    vt[((long)z * 64 + (col & 63)) * 256 + (row & 255)] = b;
                }
            }
        }
    }
}

// ============ batched patch-embed GEMM: X0[z] = P[z] @ peT[z] + bias + pos ============
struct PeDesc {
    const u16* A[3];
    const u16* Bt[3];
    const float* bias[3];
    const float* pos[3];
    int K[3];
};

__global__ __launch_bounds__(256) void gemm_pe(PeDesc d, float* __restrict__ C) {
    __shared__ u16 As[2][64][136];
    __shared__ u16 Bs[2][64][136];
    int z = blockIdx.z;
    const u16* Ab = d.A[z];
    const u16* Bb = d.Bt[z];
    const float* bias = d.bias[z];
    const float* pos = d.pos[z];
    int K = d.K[z];
    int t = threadIdx.x;
    int m0 = blockIdx.y * 64, n0 = blockIdx.x * 64;
    int wave = t >> 6, lane = t & 63;
    int wr = wave >> 1, wc = wave & 1;
    f4 acc[2][2];
    #pragma unroll
    for (int m = 0; m < 2; ++m)
        #pragma unroll
        for (int n = 0; n < 2; ++n)
            #pragma unroll
            for (int r = 0; r < 4; ++r) acc[m][n][r] = 0.f;
    int nk = (K + 127) >> 7;
    s8 pa[4], pbv[4];
    load_tile(Ab, K, 512, K, m0, 0, t, pa);
    load_tile(Bb, K, 768, K, n0, 0, t, pbv);
    write_tile(As[0], t, pa);
    write_tile(Bs[0], t, pbv);
    __syncthreads();
    for (int kt = 0; kt < nk; ++kt) {
        int cur = kt & 1;
        if (kt + 1 < nk) {
            load_tile(Ab, K, 512, K, m0, (kt+1) << 7, t, pa);
            load_tile(Bb, K, 768, K, n0, (kt+1) << 7, t, pbv);
        }
        mfma_tile(As[cur], Bs[cur], wr, wc, lane, acc);
        if (kt + 1 < nk) {
            write_tile(As[cur^1], t, pa);
            write_tile(Bs[cur^1], t, pbv);
        }
        __syncthreads();
    }
    float* Cz = C + (long)z * 512 * 768;
    #pragma unroll
    for (int m = 0; m < 2; ++m) {
        int rbase = m0 + wr*32 + m*16 + (lane >> 4) * 4;
        #pragma unroll
        for (int n = 0; n < 2; ++n) {
            int col = n0 + wc*32 + n*16 + (lane & 15);
            #pragma unroll
            for (int r = 0; r < 4; ++r) {
                int row = rbase + r;
                float v = acc[m][n][r] + bias[col] + pos[(long)(row & 255)*768 + col];
                Cz[(long)row * 768 + col] = v;
            }
        }
    }
}

// ============ batched output-proj GEMM: Y[z] = X6b[z] @ owT[z] + bias ============
struct OwDesc {
    const u16* Bt[3];
    float* C[3];
    const float* bias[3];
    int N[3];
};

__global__ __launch_bounds__(256) void gemm_ow(OwDesc d, const u16* __restrict__ A) {
    int z = blockIdx.z;
    int N = d.N[z];
    int n0 = blockIdx.x * 64;
    if (n0 >= N) return;
    __shared__ u16 As[2][64][136];
    __shared__ u16 Bs[2][64][136];
    const u16* Ab = A + (long)z * 512 * 768;
    const u16* Bb = d.Bt[z];
    int t = threadIdx.x;
    int m0 = blockIdx.y * 64;
    int wave = t >> 6, lane = t & 63;
    int wr = wave >> 1, wc = wave & 1;
    f4 acc[2][2];
    #pragma unroll
    for (int m = 0; m < 2; ++m)
        #pragma unroll
        for (int n = 0; n < 2; ++n)
            #pragma unroll
            for (int r = 0; r < 4; ++r) acc[m][n][r] = 0.f;
    s8 pa[4], pbv[4];
    load_tile(Ab, 768, 512, 768, m0, 0, t, pa);
    load_tile(Bb, 768, N, 768, n0, 0, t, pbv);
    write_tile(As[0], t, pa);
    write_tile(Bs[0], t, pbv);
    __syncthreads();
    for (int kt = 0; kt < 6; ++kt) {
        int cur = kt & 1;
        if (kt + 1 < 6) {
            load_tile(Ab, 768, 512, 768, m0, (kt+1) << 7, t, pa);
            load_tile(Bb, 768, N, 768, n0, (kt+1) << 7, t, pbv);
        }
        mfma_tile(As[cur], Bs[cur], wr, wc, lane, acc);
        if (kt + 1 < 6) {
            write_tile(As[cur^1], t, pa);
            write_tile(Bs[cur^1], t, pbv);
        }
        __syncthreads();
    }
    float* Cz = d.C[z];
    const float* bias = d.bias[z];
    #pragma unroll
    for (int m = 0; m < 2; ++m) {
        int rbase = m0 + wr*32 + m*16 + (lane >> 4) * 4;
        #pragma unroll
        for (int n = 0; n < 2; ++n) {
            int col = n0 + wc*32 + n*16 + (lane & 15);
            if (col >= N) continue;
            #pragma unroll
            for (int r = 0; r < 4; ++r) {
                int row = rbase + r;
                Cz[(long)row * N + col] = acc[m][n][r] + bias[col];
            }
        }
    }
}

// ============ LayerNorm rows of 768 ============
__global__ __launch_bounds__(256) void ln_k(const float* __restrict__ in,
                                            float* __restrict__ outf,
                                            u16* __restrict__ outb,
                                            const float* __restrict__ g,
                                            const float* __restrict__ bta) {
    constexpr int N = 768;
    int row = blockIdx.x;
    const float* x = in + (size_t)row * N;
    int t = threadIdx.x;
    float v0 = x[t], v1 = x[t+256], v2 = x[t+512];
    float s = v0+v1+v2, s2 = v0*v0+v1*v1+v2*v2;
    #pragma unroll
    for (int off = 32; off > 0; off >>= 1) { s += __shfl_down(s, off); s2 += __shfl_down(s2, off); }
    __shared__ float red[8];
    int wid = t >> 6, lane = t & 63;
    if (lane == 0) { red[wid] = s; red[wid+4] = s2; }
    __syncthreads();
    if (t == 0) {
        float S = red[0]+red[1]+red[2]+red[3];
        float S2 = red[4]+red[5]+red[6]+red[7];
        float mean = S * (1.f/N);
        float var = S2 * (1.f/N) - mean*mean;
        red[0] = mean; red[1] = rsqrtf(var + 1e-5f);
    }
    __syncthreads();
    float mean = red[0], rstd = red[1];
    float y0 = (v0-mean)*rstd*g[t]     + bta[t];
    float y1 = (v1-mean)*rstd*g[t+256] + bta[t+256];
    float y2 = (v2-mean)*rstd*g[t+512] + bta[t+512];
    if (outf) {
        float* y = outf + (size_t)row * N;
        y[t] = y0; y[t+256] = y1; y[t+512] = y2;
    }
    if (outb) {
        u16* y = outb + (size_t)row * N;
        y[t] = f2bf(y0); y[t+256] = f2bf(y1); y[t+512] = f2bf(y2);
    }
}

// ============ row softmax on S[72*256][256] -> bf16 P ============
__global__ __launch_bounds__(256) void softmax_k(const float* __restrict__ S,
                                                 u16* __restrict__ P) {
    int row = blockIdx.x*4 + (threadIdx.x >> 6);
    int lane = threadIdx.x & 63;
    const float4 v = *reinterpret_cast<const float4*>(S + (long)row*256 + lane*4);
    float m = fmaxf(fmaxf(v.x, v.y), fmaxf(v.z, v.w));
    #pragma unroll
    for (int o = 32; o; o >>= 1) m = fmaxf(m, __shfl_xor(m, o));
    float p0 = __expf(v.x - m), p1 = __expf(v.y - m), p2 = __expf(v.z - m), p3 = __expf(v.w - m);
    float l = p0 + p1 + p2 + p3;
    #pragma unroll
    for (int o = 32; o; o >>= 1) l += __shfl_xor(l, o);
    float inv = 1.f / l;
    unsigned b0 = f2bf(p0*inv), b1 = f2bf(p1*inv), b2 = f2bf(p2*inv), b3 = f2bf(p3*inv);
    uint2 pk; pk.x = b0 | (b1 << 16); pk.y = b2 | (b3 << 16);
    *reinterpret_cast<uint2*>(P + (long)row*256 + lane*4) = pk;
}

// ============ fused cross-attn: colsum-softmax weights + apply (1 launch) ============
__global__ __launch_bounds__(256) void ca_k(const float* __restrict__ S2,
                                            const u16* __restrict__ KVHb,
                                            u16* __restrict__ O) {
    __shared__ float sl[4*256];
    __shared__ float wj[256];
    int bh = blockIdx.x;            // 72 = rowblk(6) * head(12)
    int rowblk = bh / 12, h = bh % 12;
    int t = threadIdx.x;
    int w = t >> 6, lane = t & 63;
    float wacc[4] = {0.f, 0.f, 0.f, 0.f};
    for (int i = w; i < 77; i += 4) {
        const float4 v = *reinterpret_cast<const float4*>(S2 + ((long)bh*77 + i)*256 + lane*4);
        float m = fmaxf(fmaxf(v.x, v.y), fmaxf(v.z, v.w));
        #pragma unroll
        for (int o = 32; o; o >>= 1) m = fmaxf(m, __shfl_xor(m, o));
        float p0 = __expf(v.x - m), p1 = __expf(v.y - m), p2 = __expf(v.z - m), p3 = __expf(v.w - m);
        float l = p0 + p1 + p2 + p3;
        #pragma unroll
        for (int o = 32; o; o >>= 1) l += __shfl_xor(l, o);
        float inv = 1.f / l;
        wacc[0] += p0*inv; wacc[1] += p1*inv; wacc[2] += p2*inv; wacc[3] += p3*inv;
    }
    #pragma unroll
    for (int k = 0; k < 4; ++k) sl[w*256 + lane*4 + k] = wacc[k];
    __syncthreads();
    wj[t] = sl[t] + sl[256 + t] + sl[512 + t] + sl[768 + t];
    __syncthreads();
    int d = t & 63;
    #pragma unroll 4
    for (int it = 0; it < 64; ++it) {
        int j = it*4 + (t >> 6);
        long row = (long)rowblk*256 + j;
        float vh = bf2f(KVHb[row*1536 + 768 + h*64 + d]);
        O[row*768 + h*64 + d] = f2bf(wj[j] * vh);
    }
}

// ============ unpatchify 3 branches -> dense planes, pre-weighted ============
__global__ void unpatch3_k(const float* __restrict__ Y0, const float* __restrict__ Y1,
                           const float* __restrict__ Y2, const float* __restrict__ vw,
                           float* __restrict__ Aax, float* __restrict__ Asag,
                           float* __restrict__ Acor) {
    int idx = blockIdx.x*256 + threadIdx.x;
    if (idx >= 1949696) return;
    const float* y; float* A; float wt; int Wd, p2, PD, p;
    if (idx < 573440)       { y = Y0; A = Aax;  wt = vw[0]; Wd = 80;  p2 = 5; PD = 1120; p = idx; }
    else if (idx < 1146880) { y = Y1; A = Asag; wt = vw[1]; Wd = 80;  p2 = 5; PD = 1120; p = idx - 573440; }
    else                    { y = Y2; A = Acor; wt = vw[2]; Wd = 112; p2 = 7; PD = 1568; p = idx - 1146880; }
    int w = p % Wd; int r = p / Wd;
    int h = r % 112; r /= 112;
    int c = r % 32; int b = r / 32;
    int src = (b*256 + (h/7)*16 + (w/p2))*PD + ((h%7)*p2 + (w%p2))*32 + c;
    A[p] = wt * y[src];
}

// ============ streaming final combine ============
__global__ __launch_bounds__(256) void final_k(const float* __restrict__ img,
                                               const float* __restrict__ Aax,
                                               const float* __restrict__ Asag,
                                               const float* __restrict__ Acor,
                                               float* __restrict__ out) {
    int blk = blockIdx.x;                 // bc*112 + d
    int bc = blk / 112;
    const float4* ip = reinterpret_cast<const float4*>(img + (size_t)blk * 8960);
    const float4* ap = reinterpret_cast<const float4*>(Aax + (size_t)bc * 8960);
    const float4* sp = reinterpret_cast<const float4*>(Asag + (size_t)blk * 80);
    const float*  cp = Acor + (size_t)blk * 112;
    float4* op = reinterpret_cast<float4*>(out + (size_t)blk * 8960);
    int t = threadIdx.x;
    for (int q = t; q < 2240; q += 256) {
        int h = q / 20, w4 = q % 20;
        float4 iv = ip[q], av = ap[q], sv = sp[w4];
        float cv = cp[h];
        float4 o;
        o.x = iv.x + av.x + sv.x + cv;
        o.y = iv.y + av.y + sv.y + cv;
        o.z = iv.z + av.z + sv.z + cv;
        o.w = iv.w + av.w + sv.w + cv;
        op[q] = o;
    }
}

extern "C" void kernel_launch(void* const* d_in, const int* in_sizes, int n_in,
                              void* d_out, int out_size, void* d_ws, size_t ws_size,
                              hipStream_t stream) {
    (void)in_sizes; (void)n_in; (void)out_size; (void)ws_size;
    const float* img    = (const float*)d_in[0];
    const float* txt    = (const float*)d_in[1];
    const float* pe_w[3] = {(const float*)d_in[2], (const float*)d_in[4], (const float*)d_in[6]};
    const float* pe_b[3] = {(const float*)d_in[3], (const float*)d_in[5], (const float*)d_in[7]};
    const float* pos[3]  = {(const float*)d_in[8], (const float*)d_in[9], (const float*)d_in[10]};
    const float* qw = (const float*)d_in[11];
    const float* kw = (const float*)d_in[12];
    const float* vw_attn = (const float*)d_in[13];
    const float* pw = (const float*)d_in[14];
    const float* pb = (const float*)d_in[15];
    const float* caq_w = (const float*)d_in[16];
    const float* caq_b = (const float*)d_in[17];
    const float* cak_w = (const float*)d_in[18];
    const float* cak_b = (const float*)d_in[19];
    const float* cav_w = (const float*)d_in[20];
    const float* cav_b = (const float*)d_in[21];
    const float* cao_w = (const float*)d_in[22];
    const float* cao_b = (const float*)d_in[23];
    const float* mlp_w1 = (const float*)d_in[24];
    const float* mlp_b1 = (const float*)d_in[25];
    const float* mlp_w2 = (const float*)d_in[26];
    const float* mlp_b2 = (const float*)d_in[27];
    const float* ow[3] = {(const float*)d_in[28], (const float*)d_in[30], (const float*)d_in[32]};
    const float* ob[3] = {(const float*)d_in[29], (const float*)d_in[31], (const float*)d_in[33]};
    const float* view_w = (const float*)d_in[34];
    const float* n_g[3] = {(const float*)d_in[35], (const float*)d_in[36], (const float*)d_in[37]};
    const float* n_b[3] = {(const float*)d_in[38], (const float*)d_in[39], (const float*)d_in[40]};

    // ---- big scratch lives in d_out (fully rewritten by final_k) ----
    unsigned char* sb = (unsigned char*)d_out;
    size_t off = 0;
    auto B = [&](size_t bytes) -> void* {
        void* p = sb + off; off += (bytes + 511) & ~(size_t)511; return p;
    };
    u16* qkvT  = (u16*)B((size_t)2304*768*2);
    u16* pwT   = (u16*)B(768*768*2);
    u16* caqT  = (u16*)B(768*768*2);
    u16* cakvT = (u16*)B((size_t)1536*768*2);
    u16* caoT  = (u16*)B(768*768*2);
    u16* mlp1T = (u16*)B((size_t)3072*768*2);
    u16* mlp2T = (u16*)B((size_t)768*3072*2);
    u16* peT[3]; peT[0] = (u16*)B((size_t)768*1120*2); peT[1] = (u16*)B((size_t)768*1120*2); peT[2] = (u16*)B((size_t)768*1568*2);
    u16* owT[3]; owT[0] = (u16*)B((size_t)1120*768*2); owT[1] = (u16*)B((size_t)1120*768*2); owT[2] = (u16*)B((size_t)1568*768*2);
    u16* txtb = (u16*)B(154*768*2);
    float* kvb = (float*)B(1536*4);
    float* axp   = (float*)B((size_t)16*573440*4);
    float* m_ax  = (float*)B(573440*4);
    float* m_sag = (float*)B(573440*4);
    float* m_cor = (float*)B(802816*4);
    u16* P0 = (u16*)B((size_t)512*1120*2);
    u16* P1 = (u16*)B((size_t)512*1120*2);
    u16* P2 = (u16*)B((size_t)512*1568*2);
    float* X0  = (float*)B((size_t)1536*768*4);
    float* X1f = (float*)B((size_t)1536*768*4);
    float* X2  = (float*)B((size_t)1536*768*4);
    float* X3f = (float*)B((size_t)1536*768*4);
    float* X4  = (float*)B((size_t)1536*768*4);
    u16* X1b = (u16*)B((size_t)1536*768*2);
    u16* X3b = (u16*)B((size_t)1536*768*2);
    u16* X5b = (u16*)B((size_t)1536*768*2);
    u16* X6b = (u16*)B((size_t)1536*768*2);
    u16* QKVb = (u16*)B((size_t)1536*2304*2);
    u16* Obf = (u16*)B((size_t)1536*768*2);
    u16* Vt  = (u16*)B((size_t)72*64*256*2);
    u16* Hb  = (u16*)B((size_t)1536*3072*2);
    float* S  = (float*)B((size_t)72*256*256*4);
    u16* Pat = (u16*)B((size_t)72*256*256*2);
    u16* KVHb = (u16*)B((size_t)1536*1536*2);
    u16* QHb  = (u16*)B((size_t)154*768*2);
    float* S2 = (float*)B((size_t)72*77*256*4);
    float* Y[3];
    Y[0] = (float*)B(573440*4);
    Y[1] = (float*)B(573440*4);
    Y[2] = (float*)B(802816*4);

    // ---- dense view planes live in d_ws ----
    float* ws = (float*)d_ws;
    float* Aax  = ws;
    float* Asag = ws + 573440;
    float* Acor = ws + 1146880;

    // ---- batched weight transposes (1 launch) ----
    TT tab;
    {
        const float* ins[16] = {qw, kw, vw_attn, pw, caq_w, cak_w, cav_w, cao_w,
                                mlp_w1, mlp_w2, pe_w[0], pe_w[1], pe_w[2], ow[0], ow[1], ow[2]};
        u16* outs[16] = {qkvT, qkvT + 768*768, qkvT + 2*768*768, pwT, caqT, cakvT,
                         cakvT + 768*768, caoT, mlp1T, mlp2T, peT[0], peT[1], peT[2],
                         owT[0], owT[1], owT[2]};
        int Ks[16] = {768,768,768,768,768,768,768,768, 768,3072, 1120,1120,1568, 768,768,768};
        int Ns[16] = {768,768,768,768,768,768,768,768, 3072,768, 768,768,768, 1120,1120,1568};
        int st = 0;
        for (int i = 0; i < 16; ++i) {
            tab.in[i] = ins[i]; tab.out[i] = outs[i]; tab.K[i] = Ks[i]; tab.N[i] = Ns[i];
            tab.start[i] = st;
            st += (Ks[i] >> 5) * (Ns[i] >> 5);
        }
        transp_all<<<st, 256, 0, stream>>>(tab);
    }
    misc_k<<<468, 256, 0, stream>>>(txt, txtb, cak_b, cav_b, kvb);

    mean3_k<<<1024, 256, 0, stream>>>(img, axp, m_sag, m_cor);
    axred_k<<<560, 256, 0, stream>>>(axp, m_ax);
    patchify3_k<<<dim3(224,3), 256, 0, stream>>>(m_ax, m_sag, m_cor, P0, P1, P2);

    auto gemm = [&](const u16* A, const u16* Bt, float* Cf, u16* Cb,
                    int M, int N, int K, int lda, int ldb, int ldc,
                    const float* bias, const float* resid,
                    int act, float cscale, int mode, int batch) {
        dim3 g((N+63)/64, (M+63)/64, batch);
        gemm_bf<<<g, 256, 0, stream>>>(A, Bt, Cf, Cb, M, N, K, lda, ldb, ldc,
                                       bias, resid, act, cscale, mode);
    };

    // QHb = bf16(txt @ caq_w + caq_b)
    gemm(txtb, caqT, nullptr, QHb, 154, 768, 768, 768, 768, 768,
         caq_b, nullptr, 0, 1.f, 0, 1);

    // patch-embed (batched z=3)
    {
        PeDesc d;
        d.A[0] = P0; d.A[1] = P1; d.A[2] = P2;
        d.Bt[0] = peT[0]; d.Bt[1] = peT[1]; d.Bt[2] = peT[2];
        d.bias[0] = pe_b[0]; d.bias[1] = pe_b[1]; d.bias[2] = pe_b[2];
        d.pos[0] = pos[0]; d.pos[1] = pos[1]; d.pos[2] = pos[2];
        d.K[0] = 1120; d.K[1] = 1120; d.K[2] = 1568;
        gemm_pe<<<dim3(12,8,3), 256, 0, stream>>>(d, X0);
    }

    ln_k<<<1536, 256, 0, stream>>>(X0, X1f, X1b, n_g[0], n_b[0]);
    // fused QKV projection (big tile) + fused per-head V transpose
    gemm_big<<<dim3(18,12), 256, 0, stream>>>(X1b, qkvT, QKVb, Vt, 2304, 768, nullptr, 0);
    gemm(QKVb, QKVb + 768, S, nullptr, 256, 256, 64, 2304, 2304, 256,
         nullptr, nullptr, 0, 0.125f, 1, 72);
    softmax_k<<<4608, 256, 0, stream>>>(S, Pat);
    gemm(Pat, Vt, nullptr, Obf, 256, 64, 256, 256, 256, 768,
         nullptr, nullptr, 0, 1.f, 2, 72);
    gemm(Obf, pwT, X2, nullptr, 1536, 768, 768, 768, 768, 768, pb, X1f, 0, 1.f, 0, 1);
    ln_k<<<1536, 256, 0, stream>>>(X2, X3f, X3b, n_g[1], n_b[1]);
    // fused cak||cav (big tile)
    gemm_big<<<dim3(12,12), 256, 0, stream>>>(X3b, cakvT, KVHb, nullptr, 1536, 768, kvb, 0);
    // S2 = QH @ KH^T per (rowblk, head)
    gemm(QHb, KVHb, S2, nullptr, 77, 256, 64, 768, 1536, 256,
         nullptr, nullptr, 0, 0.125f, 3, 72);
    // fused colsum-softmax + apply
    ca_k<<<72, 256, 0, stream>>>(S2, KVHb, Obf);
    gemm(Obf, caoT, X4, nullptr, 1536, 768, 768, 768, 768, 768, cao_b, X3f, 0, 1.f, 0, 1);
    ln_k<<<1536, 256, 0, stream>>>(X4, nullptr, X5b, n_g[2], n_b[2]);
    // MLP1 (big tile, gelu)
    gemm_big<<<dim3(24,12), 256, 0, stream>>>(X5b, mlp1T, Hb, nullptr, 3072, 768, mlp_b1, 1);
    gemm(Hb, mlp2T, nullptr, X6b, 1536, 768, 3072, 3072, 3072, 768, mlp_b2, X4, 0, 1.f, 0, 1);
    // output projections (batched z=3)
    {
        OwDesc d;
        d.Bt[0] = owT[0]; d.Bt[1] = owT[1]; d.Bt[2] = owT[2];
        d.C[0] = Y[0]; d.C[1] = Y[1]; d.C[2] = Y[2];
        d.bias[0] = ob[0]; d.bias[1] = ob[1]; d.bias[2] = ob[2];
        d.N[0] = 1120; d.N[1] = 1120; d.N[2] = 1568;
        gemm_ow<<<dim3(25,8,3), 256, 0, stream>>>(d, X6b);
    }

    unpatch3_k<<<7616, 256, 0, stream>>>(Y[0], Y[1], Y[2], view_w, Aax, Asag, Acor);
    final_k<<<7168, 256, 0, stream>>>(img, Aax, Asag, Acor, (float*)d_out);
}

// Round 8
// 451.470 us; speedup vs baseline: 17.0120x; 1.0832x over previous
//
#include <hip/hip_runtime.h>
#include <math.h>

typedef __attribute__((ext_vector_type(8))) short s8;
typedef __attribute__((ext_vector_type(4))) float f4;
typedef unsigned short u16;

__device__ inline u16 f2bf(float f) {
    unsigned u = __float_as_uint(f);
    u += 0x7fffu + ((u >> 16) & 1u);
    return (u16)(u >> 16);
}
__device__ inline float bf2f(u16 x) {
    return __uint_as_float(((unsigned)x) << 16);
}
#define MFMA16(a, b, c) __builtin_amdgcn_mfma_f32_16x16x32_bf16(a, b, c, 0, 0, 0)

// ============ fused axis means, no atomics ============
__global__ __launch_bounds__(256) void mean3_k(const float* __restrict__ img,
                                               float* __restrict__ axp,
                                               float* __restrict__ sag,
                                               float* __restrict__ cor) {
    __shared__ float sl[112*81];
    int blk = blockIdx.x;
    int dc = blk & 15, bc = blk >> 4;
    int d0 = dc * 7;
    int t = threadIdx.x;
    f4 axr[9];
    #pragma unroll
    for (int k = 0; k < 9; ++k) axr[k] = (f4){0.f,0.f,0.f,0.f};
    const float* base = img + (size_t)bc * 1003520 + (size_t)d0 * 8960;
    for (int sidx = 0; sidx < 7; ++sidx) {
        const f4* sp = reinterpret_cast<const f4*>(base + (size_t)sidx * 8960);
        #pragma unroll
        for (int k = 0; k < 9; ++k) {
            int q = t + k * 256;
            if (q < 2240) {
                f4 v = sp[q];
                axr[k] += v;
                int h = q / 20, w4 = q % 20;
                float* row = &sl[h * 81 + w4 * 4];
                row[0] = v[0]; row[1] = v[1]; row[2] = v[2]; row[3] = v[3];
            }
        }
        __syncthreads();
        if (t < 112) {
            float acc = 0.f;
            #pragma unroll 8
            for (int w = 0; w < 80; ++w) acc += sl[t * 81 + w];
            cor[((size_t)bc * 112 + d0 + sidx) * 112 + t] = acc * (1.f / 80.f);
        } else if (t < 192) {
            int w = t - 112;
            float acc = 0.f;
            #pragma unroll 8
            for (int h = 0; h < 112; ++h) acc += sl[h * 81 + w];
            sag[((size_t)bc * 112 + d0 + sidx) * 80 + w] = acc * (1.f / 112.f);
        }
        __syncthreads();
    }
    float* axo = axp + ((size_t)dc * 64 + bc) * 8960;
    #pragma unroll
    for (int k = 0; k < 9; ++k) {
        int q = t + k * 256;
        if (q < 2240) *reinterpret_cast<f4*>(axo + q * 4) = axr[k];
    }
}

// ============ batched transpose-convert: f32 [K][N] -> bf16 [N][K] ============
struct TT {
    const float* in[16];
    u16* out[16];
    int K[16];
    int N[16];
    int start[16];
};

__global__ __launch_bounds__(256) void transp_all(TT tab) {
    __shared__ float tl[32][33];
    int bid = blockIdx.x;
    int e = 0;
    #pragma unroll
    for (int i = 1; i < 16; ++i) if (bid >= tab.start[i]) e = i;
    const float* in = tab.in[e];
    u16* out = tab.out[e];
    int K = tab.K[e], N = tab.N[e];
    int tid = bid - tab.start[e];
    int nt = N >> 5;
    int k0 = (tid / nt) * 32, n0 = (tid % nt) * 32;
    int t = threadIdx.x;
    int r = t >> 5, c = t & 31;
    #pragma unroll
    for (int i = 0; i < 4; ++i) tl[r + i*8][c] = in[(long)(k0 + r + i*8)*N + n0 + c];
    __syncthreads();
    #pragma unroll
    for (int i = 0; i < 4; ++i) out[(long)(n0 + r + i*8)*K + k0 + c] = f2bf(tl[c][r + i*8]);
}

// ============ misc: txt cvt + kv bias concat ============
__global__ void misc_k(const float* __restrict__ txt, u16* __restrict__ txtb,
                       const float* __restrict__ cak_b, const float* __restrict__ cav_b,
                       float* __restrict__ kvb) {
    int idx = blockIdx.x*256 + threadIdx.x;
    if (idx < 118272) { txtb[idx] = f2bf(txt[idx]); return; }
    int i2 = idx - 118272;
    if (i2 < 768) kvb[i2] = cak_b[i2];
    else if (i2 < 1536) kvb[i2] = cav_b[i2 - 768];
}

// ============ patchify (LDS transpose, coalesced), 3 branches; br0 sums ax partials ============
__global__ __launch_bounds__(256) void patchify3_k(const float* __restrict__ axp,
                                                   const float* __restrict__ m_sag,
                                                   const float* __restrict__ m_cor,
                                                   u16* __restrict__ P0, u16* __restrict__ P1,
                                                   u16* __restrict__ P2) {
    __shared__ float sl[32][113];
    int br = blockIdx.y;
    int X = blockIdx.x;                       // 224 = b(2) * hh(16) * pp1(7)
    int b = X / 112, rem = X % 112;
    int hh = rem / 7, pp1 = rem % 7;
    const float* src; u16* dst; int Wt, p2, PD;
    if (br == 0)      { src = nullptr; dst = P0; Wt = 80;  p2 = 5; PD = 1120; }
    else if (br == 1) { src = m_sag;   dst = P1; Wt = 80;  p2 = 5; PD = 1120; }
    else              { src = m_cor;   dst = P2; Wt = 112; p2 = 7; PD = 1568; }
    int t = threadIdx.x;
    int row = hh*7 + pp1;
    int wq = Wt >> 2;
    if (br == 0) {
        for (int i = t; i < 32*20; i += 256) {
            int c = i / 20, w4 = i % 20;
            f4 s = (f4){0.f,0.f,0.f,0.f};
            size_t base = ((size_t)(b*32 + c)*112 + row)*80 + w4*4;
            #pragma unroll
            for (int p = 0; p < 16; ++p)
                s += *reinterpret_cast<const f4*>(axp + (size_t)p*573440 + base);
            s *= (1.f/112.f);
            sl[c][w4*4+0] = s[0]; sl[c][w4*4+1] = s[1]; sl[c][w4*4+2] = s[2]; sl[c][w4*4+3] = s[3];
        }
    } else {
        for (int i = t; i < 32*wq; i += 256) {
            int c = i / wq, w4 = i % wq;
            float4 v = *reinterpret_cast<const float4*>(
                src + ((size_t)(b*32 + c)*112 + row)*Wt + w4*4);
            sl[c][w4*4+0] = v.x; sl[c][w4*4+1] = v.y; sl[c][w4*4+2] = v.z; sl[c][w4*4+3] = v.w;
        }
    }
    __syncthreads();
    int tot = 16 * p2 * 32;
    for (int o = t; o < tot; o += 256) {
        int ww = o / (p2*32), rest = o % (p2*32);
        int pp2 = rest >> 5, c = rest & 31;
        dst[((size_t)(b*256 + hh*16 + ww))*PD + (pp1*p2 + pp2)*32 + c]
            = f2bf(sl[c][ww*p2 + pp2]);
    }
}

// ============ GEMM building blocks (64-tile): BK=128, double-buffered LDS ============
__device__ inline void load_tile(const u16* __restrict__ P, int ld, int nrows, int K,
                                 int r0, int k0, int t, s8 v[4]) {
    #pragma unroll
    for (int i = 0; i < 4; ++i) {
        int chunk = t + i*256;
        int row = chunk >> 4, c8 = (chunk & 15) * 8;
        s8 x;
        #pragma unroll
        for (int q = 0; q < 8; ++q) x[q] = 0;
        if (r0 + row < nrows && k0 + c8 < K)
            x = *reinterpret_cast<const s8*>(P + (long)(r0 + row)*ld + k0 + c8);
        v[i] = x;
    }
}
__device__ inline void write_tile(u16 (*S)[136], int t, const s8 v[4]) {
    #pragma unroll
    for (int i = 0; i < 4; ++i) {
        int chunk = t + i*256;
        *reinterpret_cast<s8*>(&S[chunk >> 4][(chunk & 15)*8]) = v[i];
    }
}
__device__ inline void mfma_tile(const u16 (*As)[136], const u16 (*Bs)[136],
                                 int wr, int wc, int lane, f4 acc[2][2]) {
    int lrow = lane & 15;
    #pragma unroll
    for (int kh = 0; kh < 4; ++kh) {
        int lk = kh*32 + (lane >> 4) * 8;
        s8 af0 = *reinterpret_cast<const s8*>(&As[wr*32 + lrow][lk]);
        s8 af1 = *reinterpret_cast<const s8*>(&As[wr*32 + 16 + lrow][lk]);
        s8 bg0 = *reinterpret_cast<const s8*>(&Bs[wc*32 + lrow][lk]);
        s8 bg1 = *reinterpret_cast<const s8*>(&Bs[wc*32 + 16 + lrow][lk]);
        acc[0][0] = MFMA16(af0, bg0, acc[0][0]);
        acc[0][1] = MFMA16(af0, bg1, acc[0][1]);
        acc[1][0] = MFMA16(af1, bg0, acc[1][0]);
        acc[1][1] = MFMA16(af1, bg1, acc[1][1]);
    }
}

// ============ bf16 MFMA GEMM (64-tile, plain): C = A(MxK) @ Bt(NxK)^T + epilogue ============
__global__ __launch_bounds__(256) void gemm_bf(
    const u16* __restrict__ A, const u16* __restrict__ Bt,
    float* __restrict__ Cf, u16* __restrict__ Cb,
    int M, int N, int K,
    const float* __restrict__ bias, const float* __restrict__ resid,
    int act)
{
    __shared__ u16 As[2][64][136];
    __shared__ u16 Bs[2][64][136];
    int t = threadIdx.x;
    int m0 = blockIdx.y * 64, n0 = blockIdx.x * 64;
    int wave = t >> 6, lane = t & 63;
    int wr = wave >> 1, wc = wave & 1;
    f4 acc[2][2];
    #pragma unroll
    for (int m = 0; m < 2; ++m)
        #pragma unroll
        for (int n = 0; n < 2; ++n)
            #pragma unroll
            for (int r = 0; r < 4; ++r) acc[m][n][r] = 0.f;
    int nk = (K + 127) >> 7;
    s8 pa[4], pbv[4];
    load_tile(A, K, M, K, m0, 0, t, pa);
    load_tile(Bt, K, N, K, n0, 0, t, pbv);
    write_tile(As[0], t, pa);
    write_tile(Bs[0], t, pbv);
    __syncthreads();
    for (int kt = 0; kt < nk; ++kt) {
        int cur = kt & 1;
        if (kt + 1 < nk) {
            load_tile(A, K, M, K, m0, (kt+1) << 7, t, pa);
            load_tile(Bt, K, N, K, n0, (kt+1) << 7, t, pbv);
        }
        mfma_tile(As[cur], Bs[cur], wr, wc, lane, acc);
        if (kt + 1 < nk) {
            write_tile(As[cur^1], t, pa);
            write_tile(Bs[cur^1], t, pbv);
        }
        __syncthreads();
    }
    #pragma unroll
    for (int m = 0; m < 2; ++m) {
        int rbase = m0 + wr*32 + m*16 + (lane >> 4) * 4;
        #pragma unroll
        for (int n = 0; n < 2; ++n) {
            int col = n0 + wc*32 + n*16 + (lane & 15);
            if (col >= N) continue;
            #pragma unroll
            for (int r = 0; r < 4; ++r) {
                int row = rbase + r;
                if (row >= M) continue;
                float v = acc[m][n][r];
                if (bias)  v += bias[col];
                if (resid) v += resid[(long)row * N + col];
                if (act == 1) v = 0.5f * v * (1.0f + erff(v * 0.70710678118654752f));
                long ci = (long)row * N + col;
                if (Cf) Cf[ci] = v;
                if (Cb) Cb[ci] = f2bf(v);
            }
        }
    }
}

// ============ big-tile GEMM: BM=BN=128, BK=64, dbuf ============
__global__ __launch_bounds__(256) void gemm_big(
    const u16* __restrict__ A, const u16* __restrict__ Bt,
    u16* __restrict__ Cb, u16* __restrict__ vt,
    int N, int K,
    const float* __restrict__ bias, int act)
{
    __shared__ u16 As[2][128][72];
    __shared__ u16 Bs[2][128][72];
    int t = threadIdx.x;
    int m0 = blockIdx.y * 128, n0 = blockIdx.x * 128;
    int wave = t >> 6, lane = t & 63;
    int wr = wave >> 1, wc = wave & 1;
    f4 acc[4][4];
    #pragma unroll
    for (int m = 0; m < 4; ++m)
        #pragma unroll
        for (int n = 0; n < 4; ++n)
            #pragma unroll
            for (int r = 0; r < 4; ++r) acc[m][n][r] = 0.f;
    int nk = K >> 6;
    s8 pa[4], pbv[4];
    #pragma unroll
    for (int i = 0; i < 4; ++i) {
        int chunk = t + i*256;
        pa[i]  = *reinterpret_cast<const s8*>(A  + (long)(m0 + (chunk>>3))*K + (chunk&7)*8);
        pbv[i] = *reinterpret_cast<const s8*>(Bt + (long)(n0 + (chunk>>3))*K + (chunk&7)*8);
    }
    #pragma unroll
    for (int i = 0; i < 4; ++i) {
        int chunk = t + i*256;
        *reinterpret_cast<s8*>(&As[0][chunk>>3][(chunk&7)*8]) = pa[i];
        *reinterpret_cast<s8*>(&Bs[0][chunk>>3][(chunk&7)*8]) = pbv[i];
    }
    __syncthreads();
    for (int kt = 0; kt < nk; ++kt) {
        int cur = kt & 1;
        if (kt + 1 < nk) {
            int k0 = (kt+1) << 6;
            #pragma unroll
            for (int i = 0; i < 4; ++i) {
                int chunk = t + i*256;
                pa[i]  = *reinterpret_cast<const s8*>(A  + (long)(m0 + (chunk>>3))*K + k0 + (chunk&7)*8);
                pbv[i] = *reinterpret_cast<const s8*>(Bt + (long)(n0 + (chunk>>3))*K + k0 + (chunk&7)*8);
            }
        }
        #pragma unroll
        for (int kh = 0; kh < 2; ++kh) {
            int lk = kh*32 + (lane >> 4) * 8;
            int lr = lane & 15;
            s8 af[4], bf[4];
            #pragma unroll
            for (int m = 0; m < 4; ++m)
                af[m] = *reinterpret_cast<const s8*>(&As[cur][wr*64 + m*16 + lr][lk]);
            #pragma unroll
            for (int n = 0; n < 4; ++n)
                bf[n] = *reinterpret_cast<const s8*>(&Bs[cur][wc*64 + n*16 + lr][lk]);
            #pragma unroll
            for (int m = 0; m < 4; ++m)
                #pragma unroll
                for (int n = 0; n < 4; ++n)
                    acc[m][n] = MFMA16(af[m], bf[n], acc[m][n]);
        }
        if (kt + 1 < nk) {
            #pragma unroll
            for (int i = 0; i < 4; ++i) {
                int chunk = t + i*256;
                *reinterpret_cast<s8*>(&As[cur^1][chunk>>3][(chunk&7)*8]) = pa[i];
                *reinterpret_cast<s8*>(&Bs[cur^1][chunk>>3][(chunk&7)*8]) = pbv[i];
            }
        }
        __syncthreads();
    }
    #pragma unroll
    for (int m = 0; m < 4; ++m) {
        int rbase = m0 + wr*64 + m*16 + (lane >> 4) * 4;
        #pragma unroll
        for (int n = 0; n < 4; ++n) {
            int col = n0 + wc*64 + n*16 + (lane & 15);
            #pragma unroll
            for (int r = 0; r < 4; ++r) {
                int row = rbase + r;
                float v = acc[m][n][r];
                if (bias) v += bias[col];
                if (act == 1) v = 0.5f * v * (1.0f + erff(v * 0.70710678118654752f));
                u16 b = f2bf(v);
                Cb[(long)row * N + col] = b;
                if (vt && col >= 1536) {
                    int z = (row >> 8) * 12 + ((col - 1536) >> 6);
                    vt[((long)z * 64 + (col & 63)) * 256 + (row & 255)] = b;
                }
            }
        }
    }
}

// ============ batched patch-embed (+QH) GEMM ============
struct PeDesc {
    const u16* A[4];
    const u16* Bt[4];
    const float* bias[4];
    const float* pos[4];
    int K[4];
    int M[4];
};

__global__ __launch_bounds__(256) void gemm_pe(PeDesc d, float* __restrict__ C,
                                               u16* __restrict__ QHb) {
    int z = blockIdx.z;
    int M = d.M[z], K = d.K[z];
    int m0 = blockIdx.y * 64, n0 = blockIdx.x * 64;
    if (m0 >= M) return;
    __shared__ u16 As[2][64][136];
    __shared__ u16 Bs[2][64][136];
    const u16* Ab = d.A[z];
    const u16* Bb = d.Bt[z];
    const float* bias = d.bias[z];
    const float* pos = d.pos[z];
    int t = threadIdx.x;
    int wave = t >> 6, lane = t & 63;
    int wr = wave >> 1, wc = wave & 1;
    f4 acc[2][2];
    #pragma unroll
    for (int m = 0; m < 2; ++m)
        #pragma unroll
        for (int n = 0; n < 2; ++n)
            #pragma unroll
            for (int r = 0; r < 4; ++r) acc[m][n][r] = 0.f;
    int nk = (K + 127) >> 7;
    s8 pa[4], pbv[4];
    load_tile(Ab, K, M, K, m0, 0, t, pa);
    load_tile(Bb, K, 768, K, n0, 0, t, pbv);
    write_tile(As[0], t, pa);
    write_tile(Bs[0], t, pbv);
    __syncthreads();
    for (int kt = 0; kt < nk; ++kt) {
        int cur = kt & 1;
        if (kt + 1 < nk) {
            load_tile(Ab, K, M, K, m0, (kt+1) << 7, t, pa);
            load_tile(Bb, K, 768, K, n0, (kt+1) << 7, t, pbv);
        }
        mfma_tile(As[cur], Bs[cur], wr, wc, lane, acc);
        if (kt + 1 < nk) {
            write_tile(As[cur^1], t, pa);
            write_tile(Bs[cur^1], t, pbv);
        }
        __syncthreads();
    }
    #pragma unroll
    for (int m = 0; m < 2; ++m) {
        int rbase = m0 + wr*32 + m*16 + (lane >> 4) * 4;
        #pragma unroll
        for (int n = 0; n < 2; ++n) {
            int col = n0 + wc*32 + n*16 + (lane & 15);
            #pragma unroll
            for (int r = 0; r < 4; ++r) {
                int row = rbase + r;
                if (row >= M) continue;
                float v = acc[m][n][r] + bias[col];
                if (z < 3) {
                    v += pos[(long)(row & 255)*768 + col];
                    C[((long)z*512 + row) * 768 + col] = v;
                } else {
                    QHb[(long)row * 768 + col] = f2bf(v);
                }
            }
        }
    }
}

// ============ batched output-proj GEMM: Y[z] = X6b[z] @ owT[z] + bias ============
struct OwDesc {
    const u16* Bt[3];
    float* C[3];
    const float* bias[3];
    int N[3];
};

__global__ __launch_bounds__(256) void gemm_ow(OwDesc d, const u16* __restrict__ A) {
    int z = blockIdx.z;
    int N = d.N[z];
    int n0 = blockIdx.x * 64;
    if (n0 >= N) return;
    __shared__ u16 As[2][64][136];
    __shared__ u16 Bs[2][64][136];
    const u16* Ab = A + (long)z * 512 * 768;
    const u16* Bb = d.Bt[z];
    int t = threadIdx.x;
    int m0 = blockIdx.y * 64;
    int wave = t >> 6, lane = t & 63;
    int wr = wave >> 1, wc = wave & 1;
    f4 acc[2][2];
    #pragma unroll
    for (int m = 0; m < 2; ++m)
        #pragma unroll
        for (int n = 0; n < 2; ++n)
            #pragma unroll
            for (int r = 0; r < 4; ++r) acc[m][n][r] = 0.f;
    s8 pa[4], pbv[4];
    load_tile(Ab, 768, 512, 768, m0, 0, t, pa);
    load_tile(Bb, 768, N, 768, n0, 0, t, pbv);
    write_tile(As[0], t, pa);
    write_tile(Bs[0], t, pbv);
    __syncthreads();
    for (int kt = 0; kt < 6; ++kt) {
        int cur = kt & 1;
        if (kt + 1 < 6) {
            load_tile(Ab, 768, 512, 768, m0, (kt+1) << 7, t, pa);
            load_tile(Bb, 768, N, 768, n0, (kt+1) << 7, t, pbv);
        }
        mfma_tile(As[cur], Bs[cur], wr, wc, lane, acc);
        if (kt + 1 < 6) {
            write_tile(As[cur^1], t, pa);
            write_tile(Bs[cur^1], t, pbv);
        }
        __syncthreads();
    }
    float* Cz = d.C[z];
    const float* bias = d.bias[z];
    #pragma unroll
    for (int m = 0; m < 2; ++m) {
        int rbase = m0 + wr*32 + m*16 + (lane >> 4) * 4;
        #pragma unroll
        for (int n = 0; n < 2; ++n) {
            int col = n0 + wc*32 + n*16 + (lane & 15);
            if (col >= N) continue;
            #pragma unroll
            for (int r = 0; r < 4; ++r) {
                int row = rbase + r;
                Cz[(long)row * N + col] = acc[m][n][r] + bias[col];
            }
        }
    }
}

// ============ LayerNorm rows of 768 ============
__global__ __launch_bounds__(256) void ln_k(const float* __restrict__ in,
                                            float* __restrict__ outf,
                                            u16* __restrict__ outb,
                                            const float* __restrict__ g,
                                            const float* __restrict__ bta) {
    constexpr int N = 768;
    int row = blockIdx.x;
    const float* x = in + (size_t)row * N;
    int t = threadIdx.x;
    float v0 = x[t], v1 = x[t+256], v2 = x[t+512];
    float s = v0+v1+v2, s2 = v0*v0+v1*v1+v2*v2;
    #pragma unroll
    for (int off = 32; off > 0; off >>= 1) { s += __shfl_down(s, off); s2 += __shfl_down(s2, off); }
    __shared__ float red[8];
    int wid = t >> 6, lane = t & 63;
    if (lane == 0) { red[wid] = s; red[wid+4] = s2; }
    __syncthreads();
    if (t == 0) {
        float S = red[0]+red[1]+red[2]+red[3];
        float S2 = red[4]+red[5]+red[6]+red[7];
        float mean = S * (1.f/N);
        float var = S2 * (1.f/N) - mean*mean;
        red[0] = mean; red[1] = rsqrtf(var + 1e-5f);
    }
    __syncthreads();
    float mean = red[0], rstd = red[1];
    float y0 = (v0-mean)*rstd*g[t]     + bta[t];
    float y1 = (v1-mean)*rstd*g[t+256] + bta[t+256];
    float y2 = (v2-mean)*rstd*g[t+512] + bta[t+512];
    if (outf) {
        float* y = outf + (size_t)row * N;
        y[t] = y0; y[t+256] = y1; y[t+512] = y2;
    }
    if (outb) {
        u16* y = outb + (size_t)row * N;
        y[t] = f2bf(y0); y[t+256] = f2bf(y1); y[t+512] = f2bf(y2);
    }
}

// ============ fully fused self-attention: QK^T + softmax + PV ============
// grid 144: zz = bh*2 + half; bh = bb*12 + h (bb in 0..5); 128 Q rows per block
__global__ __launch_bounds__(256) void attn_k(const u16* __restrict__ QKV,
                                              const u16* __restrict__ Vt,
                                              u16* __restrict__ O) {
    __shared__ u16 Ks[256][72];     // 36,864 B
    __shared__ u16 Ps[128][264];    // 67,584 B
    __shared__ u16 Vs[64][264];     // 33,792 B
    int zz = blockIdx.x;
    int bh = zz >> 1, half = zz & 1;
    int bb = bh / 12, h = bh % 12;
    long qrow0 = (long)bb*256 + half*128;
    int hcol = h*64;
    int t = threadIdx.x;
    int wave = t >> 6, lane = t & 63;
    int lr = lane & 15, lg = lane >> 4;
    #pragma unroll
    for (int i = 0; i < 8; ++i) {
        int chunk = t + i*256;
        int row = chunk >> 3, c8 = (chunk & 7)*8;
        *reinterpret_cast<s8*>(&Ks[row][c8]) =
            *reinterpret_cast<const s8*>(QKV + ((long)bb*256 + row)*2304 + 768 + hcol + c8);
    }
    #pragma unroll
    for (int i = 0; i < 8; ++i) {
        int chunk = t + i*256;
        int d = chunk >> 5, j8 = (chunk & 31)*8;
        *reinterpret_cast<s8*>(&Vs[d][j8]) =
            *reinterpret_cast<const s8*>(Vt + (long)bh*16384 + (long)d*256 + j8);
    }
    __syncthreads();
    // QK^T: wave rows wave*32..+32; acc[2][16]
    f4 acc[2][16];
    #pragma unroll
    for (int m = 0; m < 2; ++m)
        #pragma unroll
        for (int n = 0; n < 16; ++n)
            #pragma unroll
            for (int r = 0; r < 4; ++r) acc[m][n][r] = 0.f;
    #pragma unroll
    for (int kh = 0; kh < 2; ++kh) {
        s8 af0 = *reinterpret_cast<const s8*>(QKV + (qrow0 + wave*32 + lr)*2304 + hcol + kh*32 + lg*8);
        s8 af1 = *reinterpret_cast<const s8*>(QKV + (qrow0 + wave*32 + 16 + lr)*2304 + hcol + kh*32 + lg*8);
        #pragma unroll
        for (int n = 0; n < 16; ++n) {
            s8 bf = *reinterpret_cast<const s8*>(&Ks[n*16 + lr][kh*32 + lg*8]);
            acc[0][n] = MFMA16(af0, bf, acc[0][n]);
            acc[1][n] = MFMA16(af1, bf, acc[1][n]);
        }
    }
    // in-register softmax (row lives across 16-lane group: reduce over lr)
    #pragma unroll
    for (int m = 0; m < 2; ++m)
        #pragma unroll
        for (int r = 0; r < 4; ++r) {
            float mx = -1e30f;
            #pragma unroll
            for (int n = 0; n < 16; ++n) mx = fmaxf(mx, acc[m][n][r]);
            #pragma unroll
            for (int o = 8; o; o >>= 1) mx = fmaxf(mx, __shfl_xor(mx, o));
            float l = 0.f;
            float p[16];
            #pragma unroll
            for (int n = 0; n < 16; ++n) {
                p[n] = __expf((acc[m][n][r] - mx) * 0.125f);
                l += p[n];
            }
            #pragma unroll
            for (int o = 8; o; o >>= 1) l += __shfl_xor(l, o);
            float inv = 1.f / l;
            int prow = wave*32 + m*16 + lg*4 + r;
            #pragma unroll
            for (int n = 0; n < 16; ++n)
                Ps[prow][n*16 + lr] = f2bf(p[n] * inv);
        }
    __syncthreads();
    // PV: wave rows wave*32..+32, cols 64; K=256
    f4 o2[2][4];
    #pragma unroll
    for (int m = 0; m < 2; ++m)
        #pragma unroll
        for (int n = 0; n < 4; ++n)
            #pragma unroll
            for (int r = 0; r < 4; ++r) o2[m][n][r] = 0.f;
    #pragma unroll
    for (int kh = 0; kh < 8; ++kh) {
        s8 pf0 = *reinterpret_cast<const s8*>(&Ps[wave*32 + lr][kh*32 + lg*8]);
        s8 pf1 = *reinterpret_cast<const s8*>(&Ps[wave*32 + 16 + lr][kh*32 + lg*8]);
        #pragma unroll
        for (int n = 0; n < 4; ++n) {
            s8 vf = *reinterpret_cast<const s8*>(&Vs[n*16 + lr][kh*32 + lg*8]);
            o2[0][n] = MFMA16(pf0, vf, o2[0][n]);
            o2[1][n] = MFMA16(pf1, vf, o2[1][n]);
        }
    }
    #pragma unroll
    for (int m = 0; m < 2; ++m)
        #pragma unroll
        for (int n = 0; n < 4; ++n)
            #pragma unroll
            for (int r = 0; r < 4; ++r)
                O[(qrow0 + wave*32 + m*16 + lg*4 + r)*768 + hcol + n*16 + lr] = f2bf(o2[m][n][r]);
}

// ============ fully fused cross-attention: S2 + colsum-softmax + apply ============
// grid 72: bh = rowblk*12 + h
__global__ __launch_bounds__(256) void ca_fused(const u16* __restrict__ QHb,
                                                const u16* __restrict__ KVHb,
                                                u16* __restrict__ O) {
    __shared__ u16 QHs[80][72];
    __shared__ u16 KHs[256][72];
    __shared__ float rmax[80][4];
    __shared__ float rsum[80][4];
    __shared__ float Wj[256];
    int bh = blockIdx.x;
    int rowblk = bh / 12, h = bh % 12;
    int bsel = rowblk & 1;
    int t = threadIdx.x;
    int wave = t >> 6, lane = t & 63;
    int lr = lane & 15, lg = lane >> 4;
    #pragma unroll
    for (int i = 0; i < 3; ++i) {
        int chunk = t + i*256;
        if (chunk < 640) {
            int row = chunk >> 3, c8 = (chunk & 7)*8;
            s8 v;
            #pragma unroll
            for (int q = 0; q < 8; ++q) v[q] = 0;
            if (row < 77)
                v = *reinterpret_cast<const s8*>(QHb + ((long)(bsel*77 + row))*768 + h*64 + c8);
            *reinterpret_cast<s8*>(&QHs[row][c8]) = v;
        }
    }
    #pragma unroll
    for (int i = 0; i < 8; ++i) {
        int chunk = t + i*256;
        int row = chunk >> 3, c8 = (chunk & 7)*8;
        *reinterpret_cast<s8*>(&KHs[row][c8]) =
            *reinterpret_cast<const s8*>(KVHb + ((long)rowblk*256 + row)*1536 + h*64 + c8);
    }
    __syncthreads();
    // S2: 80 x 256; wave owns 64-col strip; acc[5][4]
    f4 acc[5][4];
    #pragma unroll
    for (int m = 0; m < 5; ++m)
        #pragma unroll
        for (int n = 0; n < 4; ++n)
            #pragma unroll
            for (int r = 0; r < 4; ++r) acc[m][n][r] = 0.f;
    #pragma unroll
    for (int kh = 0; kh < 2; ++kh) {
        s8 af[5], bf[4];
        #pragma unroll
        for (int m = 0; m < 5; ++m)
            af[m] = *reinterpret_cast<const s8*>(&QHs[m*16 + lr][kh*32 + lg*8]);
        #pragma unroll
        for (int n = 0; n < 4; ++n)
            bf[n] = *reinterpret_cast<const s8*>(&KHs[wave*64 + n*16 + lr][kh*32 + lg*8]);
        #pragma unroll
        for (int m = 0; m < 5; ++m)
            #pragma unroll
            for (int n = 0; n < 4; ++n)
                acc[m][n] = MFMA16(af[m], bf[n], acc[m][n]);
    }
    // pass 1: per-wave row max over its 64 cols
    #pragma unroll
    for (int m = 0; m < 5; ++m)
        #pragma unroll
        for (int r = 0; r < 4; ++r) {
            float mx = -1e30f;
            #pragma unroll
            for (int n = 0; n < 4; ++n) mx = fmaxf(mx, acc[m][n][r]);
            #pragma unroll
            for (int o = 8; o; o >>= 1) mx = fmaxf(mx, __shfl_xor(mx, o));
            if (lr == 0) rmax[m*16 + lg*4 + r][wave] = mx;
        }
    __syncthreads();
    // pass 2: per-wave row sum of exp with global max
    #pragma unroll
    for (int m = 0; m < 5; ++m)
        #pragma unroll
        for (int r = 0; r < 4; ++r) {
            int i = m*16 + lg*4 + r;
            float mi = fmaxf(fmaxf(rmax[i][0], rmax[i][1]), fmaxf(rmax[i][2], rmax[i][3]));
            float s = 0.f;
            #pragma unroll
            for (int n = 0; n < 4; ++n) s += __expf((acc[m][n][r] - mi) * 0.125f);
            #pragma unroll
            for (int o = 8; o; o >>= 1) s += __shfl_xor(s, o);
            if (lr == 0) rsum[i][wave] = s;
        }
    __syncthreads();
    // pass 3: colsum of normalized p over rows i < 77
    float wn[4] = {0.f, 0.f, 0.f, 0.f};
    #pragma unroll
    for (int m = 0; m < 5; ++m)
        #pragma unroll
        for (int r = 0; r < 4; ++r) {
            int i = m*16 + lg*4 + r;
            if (i < 77) {
                float mi = fmaxf(fmaxf(rmax[i][0], rmax[i][1]), fmaxf(rmax[i][2], rmax[i][3]));
                float li = rsum[i][0] + rsum[i][1] + rsum[i][2] + rsum[i][3];
                float inv = 1.f / li;
                #pragma unroll
                for (int n = 0; n < 4; ++n)
                    wn[n] += __expf((acc[m][n][r] - mi) * 0.125f) * inv;
            }
        }
    #pragma unroll
    for (int n = 0; n < 4; ++n) {
        wn[n] += __shfl_xor(wn[n], 16);
        wn[n] += __shfl_xor(wn[n], 32);
    }
    if (lane < 16) {
        #pragma unroll
        for (int n = 0; n < 4; ++n) Wj[wave*64 + n*16 + lr] = wn[n];
    }
    __syncthreads();
    // apply: O[row, h*64+d] = W[j] * VH[row, h*64+d]
    int d = t & 63;
    #pragma unroll 4
    for (int it = 0; it < 64; ++it) {
        int j = it*4 + (t >> 6);
        long row = (long)rowblk*256 + j;
        float vh = bf2f(KVHb[row*1536 + 768 + h*64 + d]);
        O[row*768 + h*64 + d] = f2bf(Wj[j] * vh);
    }
}

// ============ unpatchify 3 branches -> dense planes, pre-weighted ============
__global__ void unpatch3_k(const float* __restrict__ Y0, const float* __restrict__ Y1,
                           const float* __restrict__ Y2, const float* __restrict__ vw,
                           float* __restrict__ Aax, float* __restrict__ Asag,
                           float* __restrict__ Acor) {
    int idx = blockIdx.x*256 + threadIdx.x;
    if (idx >= 1949696) return;
    const float* y; float* A; float wt; int Wd, p2, PD, p;
    if (idx < 573440)       { y = Y0; A = Aax;  wt = vw[0]; Wd = 80;  p2 = 5; PD = 1120; p = idx; }
    else if (idx < 1146880) { y = Y1; A = Asag; wt = vw[1]; Wd = 80;  p2 = 5; PD = 1120; p = idx - 573440; }
    else                    { y = Y2; A = Acor; wt = vw[2]; Wd = 112; p2 = 7; PD = 1568; p = idx - 1146880; }
    int w = p % Wd; int r = p / Wd;
    int h = r % 112; r /= 112;
    int c = r % 32; int b = r / 32;
    int src = (b*256 + (h/7)*16 + (w/p2))*PD + ((h%7)*p2 + (w%p2))*32 + c;
    A[p] = wt * y[src];
}

// ============ streaming final combine ============
__global__ __launch_bounds__(256) void final_k(const float* __restrict__ img,
                                               const float* __restrict__ Aax,
                                               const float* __restrict__ Asag,
                                               const float* __restrict__ Acor,
                                               float* __restrict__ out) {
    int blk = blockIdx.x;                 // bc*112 + d
    int bc = blk / 112;
    const float4* ip = reinterpret_cast<const float4*>(img + (size_t)blk * 8960);
    const float4* ap = reinterpret_cast<const float4*>(Aax + (size_t)bc * 8960);
    const float4* sp = reinterpret_cast<const float4*>(Asag + (size_t)blk * 80);
    const float*  cp = Acor + (size_t)blk * 112;
    float4* op = reinterpret_cast<float4*>(out + (size_t)blk * 8960);
    int t = threadIdx.x;
    for (int q = t; q < 2240; q += 256) {
        int h = q / 20, w4 = q % 20;
        float4 iv = ip[q], av = ap[q], sv = sp[w4];
        float cv = cp[h];
        float4 o;
        o.x = iv.x + av.x + sv.x + cv;
        o.y = iv.y + av.y + sv.y + cv;
        o.z = iv.z + av.z + sv.z + cv;
        o.w = iv.w + av.w + sv.w + cv;
        op[q] = o;
    }
}

extern "C" void kernel_launch(void* const* d_in, const int* in_sizes, int n_in,
                              void* d_out, int out_size, void* d_ws, size_t ws_size,
                              hipStream_t stream) {
    (void)in_sizes; (void)n_in; (void)out_size; (void)ws_size;
    const float* img    = (const float*)d_in[0];
    const float* txt    = (const float*)d_in[1];
    const float* pe_w[3] = {(const float*)d_in[2], (const float*)d_in[4], (const float*)d_in[6]};
    const float* pe_b[3] = {(const float*)d_in[3], (const float*)d_in[5], (const float*)d_in[7]};
    const float* pos[3]  = {(const float*)d_in[8], (const float*)d_in[9], (const float*)d_in[10]};
    const float* qw = (const float*)d_in[11];
    const float* kw = (const float*)d_in[12];
    const float* vw_attn = (const float*)d_in[13];
    const float* pw = (const float*)d_in[14];
    const float* pb = (const float*)d_in[15];
    const float* caq_w = (const float*)d_in[16];
    const float* caq_b = (const float*)d_in[17];
    const float* cak_w = (const float*)d_in[18];
    const float* cak_b = (const float*)d_in[19];
    const float* cav_w = (const float*)d_in[20];
    const float* cav_b = (const float*)d_in[21];
    const float* cao_w = (const float*)d_in[22];
    const float* cao_b = (const float*)d_in[23];
    const float* mlp_w1 = (const float*)d_in[24];
    const float* mlp_b1 = (const float*)d_in[25];
    const float* mlp_w2 = (const float*)d_in[26];
    const float* mlp_b2 = (const float*)d_in[27];
    const float* ow[3] = {(const float*)d_in[28], (const float*)d_in[30], (const float*)d_in[32]};
    const float* ob[3] = {(const float*)d_in[29], (const float*)d_in[31], (const float*)d_in[33]};
    const float* view_w = (const float*)d_in[34];
    const float* n_g[3] = {(const float*)d_in[35], (const float*)d_in[36], (const float*)d_in[37]};
    const float* n_b[3] = {(const float*)d_in[38], (const float*)d_in[39], (const float*)d_in[40]};

    // ---- big scratch lives in d_out (fully rewritten by final_k) ----
    unsigned char* sb = (unsigned char*)d_out;
    size_t off = 0;
    auto B = [&](size_t bytes) -> void* {
        void* p = sb + off; off += (bytes + 511) & ~(size_t)511; return p;
    };
    u16* qkvT  = (u16*)B((size_t)2304*768*2);
    u16* pwT   = (u16*)B(768*768*2);
    u16* caqT  = (u16*)B(768*768*2);
    u16* cakvT = (u16*)B((size_t)1536*768*2);
    u16* caoT  = (u16*)B(768*768*2);
    u16* mlp1T = (u16*)B((size_t)3072*768*2);
    u16* mlp2T = (u16*)B((size_t)768*3072*2);
    u16* peT[3]; peT[0] = (u16*)B((size_t)768*1120*2); peT[1] = (u16*)B((size_t)768*1120*2); peT[2] = (u16*)B((size_t)768*1568*2);
    u16* owT[3]; owT[0] = (u16*)B((size_t)1120*768*2); owT[1] = (u16*)B((size_t)1120*768*2); owT[2] = (u16*)B((size_t)1568*768*2);
    u16* txtb = (u16*)B(154*768*2);
    float* kvb = (float*)B(1536*4);
    float* axp   = (float*)B((size_t)16*573440*4);
    float* m_sag = (float*)B(573440*4);
    float* m_cor = (float*)B(802816*4);
    u16* P0 = (u16*)B((size_t)512*1120*2);
    u16* P1 = (u16*)B((size_t)512*1120*2);
    u16* P2 = (u16*)B((size_t)512*1568*2);
    float* X0  = (float*)B((size_t)1536*768*4);
    float* X1f = (float*)B((size_t)1536*768*4);
    float* X2  = (float*)B((size_t)1536*768*4);
    float* X3f = (float*)B((size_t)1536*768*4);
    float* X4  = (float*)B((size_t)1536*768*4);
    u16* X1b = (u16*)B((size_t)1536*768*2);
    u16* X3b = (u16*)B((size_t)1536*768*2);
    u16* X5b = (u16*)B((size_t)1536*768*2);
    u16* X6b = (u16*)B((size_t)1536*768*2);
    u16* QKVb = (u16*)B((size_t)1536*2304*2);
    u16* Obf = (u16*)B((size_t)1536*768*2);
    u16* Vt  = (u16*)B((size_t)72*64*256*2);
    u16* Hb  = (u16*)B((size_t)1536*3072*2);
    u16* KVHb = (u16*)B((size_t)1536*1536*2);
    u16* QHb  = (u16*)B((size_t)154*768*2);
    float* Y[3];
    Y[0] = (float*)B(573440*4);
    Y[1] = (float*)B(573440*4);
    Y[2] = (float*)B(802816*4);

    // ---- dense view planes live in d_ws ----
    float* ws = (float*)d_ws;
    float* Aax  = ws;
    float* Asag = ws + 573440;
    float* Acor = ws + 1146880;

    // ---- batched weight transposes (1 launch) ----
    TT tab;
    {
        const float* ins[16] = {qw, kw, vw_attn, pw, caq_w, cak_w, cav_w, cao_w,
                                mlp_w1, mlp_w2, pe_w[0], pe_w[1], pe_w[2], ow[0], ow[1], ow[2]};
        u16* outs[16] = {qkvT, qkvT + 768*768, qkvT + 2*768*768, pwT, caqT, cakvT,
                         cakvT + 768*768, caoT, mlp1T, mlp2T, peT[0], peT[1], peT[2],
                         owT[0], owT[1], owT[2]};
        int Ks[16] = {768,768,768,768,768,768,768,768, 768,3072, 1120,1120,1568, 768,768,768};
        int Ns[16] = {768,768,768,768,768,768,768,768, 3072,768, 768,768,768, 1120,1120,1568};
        int st = 0;
        for (int i = 0; i < 16; ++i) {
            tab.in[i] = ins[i]; tab.out[i] = outs[i]; tab.K[i] = Ks[i]; tab.N[i] = Ns[i];
            tab.start[i] = st;
            st += (Ks[i] >> 5) * (Ns[i] >> 5);
        }
        transp_all<<<st, 256, 0, stream>>>(tab);
    }
    misc_k<<<468, 256, 0, stream>>>(txt, txtb, cak_b, cav_b, kvb);

    mean3_k<<<1024, 256, 0, stream>>>(img, axp, m_sag, m_cor);
    patchify3_k<<<dim3(224,3), 256, 0, stream>>>(axp, m_sag, m_cor, P0, P1, P2);

    auto gemm = [&](const u16* A, const u16* Bt, float* Cf, u16* Cb,
                    int M, int N, int K, const float* bias, const float* resid, int act) {
        dim3 g((N+63)/64, (M+63)/64, 1);
        gemm_bf<<<g, 256, 0, stream>>>(A, Bt, Cf, Cb, M, N, K, bias, resid, act);
    };

    // patch-embed (z=0..2) + QH projection (z=3), one launch
    {
        PeDesc d;
        d.A[0] = P0; d.A[1] = P1; d.A[2] = P2; d.A[3] = txtb;
        d.Bt[0] = peT[0]; d.Bt[1] = peT[1]; d.Bt[2] = peT[2]; d.Bt[3] = caqT;
        d.bias[0] = pe_b[0]; d.bias[1] = pe_b[1]; d.bias[2] = pe_b[2]; d.bias[3] = caq_b;
        d.pos[0] = pos[0]; d.pos[1] = pos[1]; d.pos[2] = pos[2]; d.pos[3] = nullptr;
        d.K[0] = 1120; d.K[1] = 1120; d.K[2] = 1568; d.K[3] = 768;
        d.M[0] = 512; d.M[1] = 512; d.M[2] = 512; d.M[3] = 154;
        gemm_pe<<<dim3(12,8,4), 256, 0, stream>>>(d, X0, QHb);
    }

    ln_k<<<1536, 256, 0, stream>>>(X0, X1f, X1b, n_g[0], n_b[0]);
    // fused QKV projection (big tile) + per-head V transpose
    gemm_big<<<dim3(18,12), 256, 0, stream>>>(X1b, qkvT, QKVb, Vt, 2304, 768, nullptr, 0);
    // fully fused self-attention
    attn_k<<<144, 256, 0, stream>>>(QKVb, Vt, Obf);
    gemm(Obf, pwT, X2, nullptr, 1536, 768, 768, pb, X1f, 0);
    ln_k<<<1536, 256, 0, stream>>>(X2, X3f, X3b, n_g[1], n_b[1]);
    // fused cak||cav (big tile)
    gemm_big<<<dim3(12,12), 256, 0, stream>>>(X3b, cakvT, KVHb, nullptr, 1536, 768, kvb, 0);
    // fully fused cross-attention
    ca_fused<<<72, 256, 0, stream>>>(QHb, KVHb, Obf);
    gemm(Obf, caoT, X4, nullptr, 1536, 768, 768, cao_b, X3f, 0);
    ln_k<<<1536, 256, 0, stream>>>(X4, nullptr, X5b, n_g[2], n_b[2]);
    // MLP
    gemm_big<<<dim3(24,12), 256, 0, stream>>>(X5b, mlp1T, Hb, nullptr, 3072, 768, mlp_b1, 1);
    gemm(Hb, mlp2T, nullptr, X6b, 1536, 768, 3072, mlp_b2, X4, 0);
    // output projections (batched z=3)
    {
        OwDesc d;
        d.Bt[0] = owT[0]; d.Bt[1] = owT[1]; d.Bt[2] = owT[2];
        d.C[0] = Y[0]; d.C[1] = Y[1]; d.C[2] = Y[2];
        d.bias[0] = ob[0]; d.bias[1] = ob[1]; d.bias[2] = ob[2];
        d.N[0] = 1120; d.N[1] = 1120; d.N[2] = 1568;
        gemm_ow<<<dim3(25,8,3), 256, 0, stream>>>(d, X6b);
    }

    unpatch3_k<<<7616, 256, 0, stream>>>(Y[0], Y[1], Y[2], view_w, Aax, Asag, Acor);
    final_k<<<7168, 256, 0, stream>>>(img, Aax, Asag, Acor, (float*)d_out);
}

// Round 9
// 445.874 us; speedup vs baseline: 17.2255x; 1.0125x over previous
//
#include <hip/hip_runtime.h>
#include <math.h>

typedef __attribute__((ext_vector_type(8))) short s8;
typedef __attribute__((ext_vector_type(4))) float f4;
typedef unsigned short u16;

__device__ inline u16 f2bf(float f) {
    unsigned u = __float_as_uint(f);
    u += 0x7fffu + ((u >> 16) & 1u);
    return (u16)(u >> 16);
}
__device__ inline float bf2f(u16 x) {
    return __uint_as_float(((unsigned)x) << 16);
}
#define MFMA16(a, b, c) __builtin_amdgcn_mfma_f32_16x16x32_bf16(a, b, c, 0, 0, 0)

// ============ fused axis means, no atomics ============
__global__ __launch_bounds__(256) void mean3_k(const float* __restrict__ img,
                                               float* __restrict__ axp,
                                               float* __restrict__ sag,
                                               float* __restrict__ cor) {
    __shared__ float sl[112*81];
    int blk = blockIdx.x;
    int dc = blk & 15, bc = blk >> 4;
    int d0 = dc * 7;
    int t = threadIdx.x;
    f4 axr[9];
    #pragma unroll
    for (int k = 0; k < 9; ++k) axr[k] = (f4){0.f,0.f,0.f,0.f};
    const float* base = img + (size_t)bc * 1003520 + (size_t)d0 * 8960;
    for (int sidx = 0; sidx < 7; ++sidx) {
        const f4* sp = reinterpret_cast<const f4*>(base + (size_t)sidx * 8960);
        #pragma unroll
        for (int k = 0; k < 9; ++k) {
            int q = t + k * 256;
            if (q < 2240) {
                f4 v = sp[q];
                axr[k] += v;
                int h = q / 20, w4 = q % 20;
                float* row = &sl[h * 81 + w4 * 4];
                row[0] = v[0]; row[1] = v[1]; row[2] = v[2]; row[3] = v[3];
            }
        }
        __syncthreads();
        if (t < 112) {
            float acc = 0.f;
            #pragma unroll 8
            for (int w = 0; w < 80; ++w) acc += sl[t * 81 + w];
            cor[((size_t)bc * 112 + d0 + sidx) * 112 + t] = acc * (1.f / 80.f);
        } else if (t < 192) {
            int w = t - 112;
            float acc = 0.f;
            #pragma unroll 8
            for (int h = 0; h < 112; ++h) acc += sl[h * 81 + w];
            sag[((size_t)bc * 112 + d0 + sidx) * 80 + w] = acc * (1.f / 112.f);
        }
        __syncthreads();
    }
    float* axo = axp + ((size_t)dc * 64 + bc) * 8960;
    #pragma unroll
    for (int k = 0; k < 9; ++k) {
        int q = t + k * 256;
        if (q < 2240) *reinterpret_cast<f4*>(axo + q * 4) = axr[k];
    }
}

// ============ batched transpose-convert: f32 [K][N] -> bf16 [N][K] ============
struct TT {
    const float* in[16];
    u16* out[16];
    int K[16];
    int N[16];
    int start[16];
};

__global__ __launch_bounds__(256) void transp_all(TT tab) {
    __shared__ float tl[32][33];
    int bid = blockIdx.x;
    int e = 0;
    #pragma unroll
    for (int i = 1; i < 16; ++i) if (bid >= tab.start[i]) e = i;
    const float* in = tab.in[e];
    u16* out = tab.out[e];
    int K = tab.K[e], N = tab.N[e];
    int tid = bid - tab.start[e];
    int nt = N >> 5;
    int k0 = (tid / nt) * 32, n0 = (tid % nt) * 32;
    int t = threadIdx.x;
    int r = t >> 5, c = t & 31;
    #pragma unroll
    for (int i = 0; i < 4; ++i) tl[r + i*8][c] = in[(long)(k0 + r + i*8)*N + n0 + c];
    __syncthreads();
    #pragma unroll
    for (int i = 0; i < 4; ++i) out[(long)(n0 + r + i*8)*K + k0 + c] = f2bf(tl[c][r + i*8]);
}

// ============ patchify (LDS transpose, coalesced), 3 branches; br0 sums ax partials ============
__global__ __launch_bounds__(256) void patchify3_k(const float* __restrict__ axp,
                                                   const float* __restrict__ m_sag,
                                                   const float* __restrict__ m_cor,
                                                   u16* __restrict__ P0, u16* __restrict__ P1,
                                                   u16* __restrict__ P2) {
    __shared__ float sl[32][113];
    int br = blockIdx.y;
    int X = blockIdx.x;                       // 224 = b(2) * hh(16) * pp1(7)
    int b = X / 112, rem = X % 112;
    int hh = rem / 7, pp1 = rem % 7;
    const float* src; u16* dst; int Wt, p2, PD;
    if (br == 0)      { src = nullptr; dst = P0; Wt = 80;  p2 = 5; PD = 1120; }
    else if (br == 1) { src = m_sag;   dst = P1; Wt = 80;  p2 = 5; PD = 1120; }
    else              { src = m_cor;   dst = P2; Wt = 112; p2 = 7; PD = 1568; }
    int t = threadIdx.x;
    int row = hh*7 + pp1;
    int wq = Wt >> 2;
    if (br == 0) {
        for (int i = t; i < 32*20; i += 256) {
            int c = i / 20, w4 = i % 20;
            f4 s = (f4){0.f,0.f,0.f,0.f};
            size_t base = ((size_t)(b*32 + c)*112 + row)*80 + w4*4;
            #pragma unroll
            for (int p = 0; p < 16; ++p)
                s += *reinterpret_cast<const f4*>(axp + (size_t)p*573440 + base);
            s *= (1.f/112.f);
            sl[c][w4*4+0] = s[0]; sl[c][w4*4+1] = s[1]; sl[c][w4*4+2] = s[2]; sl[c][w4*4+3] = s[3];
        }
    } else {
        for (int i = t; i < 32*wq; i += 256) {
            int c = i / wq, w4 = i % wq;
            float4 v = *reinterpret_cast<const float4*>(
                src + ((size_t)(b*32 + c)*112 + row)*Wt + w4*4);
            sl[c][w4*4+0] = v.x; sl[c][w4*4+1] = v.y; sl[c][w4*4+2] = v.z; sl[c][w4*4+3] = v.w;
        }
    }
    __syncthreads();
    int tot = 16 * p2 * 32;
    for (int o = t; o < tot; o += 256) {
        int ww = o / (p2*32), rest = o % (p2*32);
        int pp2 = rest >> 5, c = rest & 31;
        dst[((size_t)(b*256 + hh*16 + ww))*PD + (pp1*p2 + pp2)*32 + c]
            = f2bf(sl[c][ww*p2 + pp2]);
    }
}

// ============ GEMM building blocks (64-tile): BK=128, double-buffered LDS ============
__device__ inline void load_tile(const u16* __restrict__ P, int ld, int nrows, int K,
                                 int r0, int k0, int t, s8 v[4]) {
    #pragma unroll
    for (int i = 0; i < 4; ++i) {
        int chunk = t + i*256;
        int row = chunk >> 4, c8 = (chunk & 15) * 8;
        s8 x;
        #pragma unroll
        for (int q = 0; q < 8; ++q) x[q] = 0;
        if (r0 + row < nrows && k0 + c8 < K)
            x = *reinterpret_cast<const s8*>(P + (long)(r0 + row)*ld + k0 + c8);
        v[i] = x;
    }
}
__device__ inline void load_tile_f32(const float* __restrict__ P, int ld, int nrows, int K,
                                     int r0, int k0, int t, s8 v[4]) {
    #pragma unroll
    for (int i = 0; i < 4; ++i) {
        int chunk = t + i*256;
        int row = chunk >> 4, c8 = (chunk & 15) * 8;
        s8 x;
        #pragma unroll
        for (int q = 0; q < 8; ++q) x[q] = 0;
        if (r0 + row < nrows && k0 + c8 < K) {
            const float* src = P + (long)(r0 + row)*ld + k0 + c8;
            #pragma unroll
            for (int q = 0; q < 8; ++q) x[q] = (short)f2bf(src[q]);
        }
        v[i] = x;
    }
}
__device__ inline void write_tile(u16 (*S)[136], int t, const s8 v[4]) {
    #pragma unroll
    for (int i = 0; i < 4; ++i) {
        int chunk = t + i*256;
        *reinterpret_cast<s8*>(&S[chunk >> 4][(chunk & 15)*8]) = v[i];
    }
}
__device__ inline void mfma_tile(const u16 (*As)[136], const u16 (*Bs)[136],
                                 int wr, int wc, int lane, f4 acc[2][2]) {
    int lrow = lane & 15;
    #pragma unroll
    for (int kh = 0; kh < 4; ++kh) {
        int lk = kh*32 + (lane >> 4) * 8;
        s8 af0 = *reinterpret_cast<const s8*>(&As[wr*32 + lrow][lk]);
        s8 af1 = *reinterpret_cast<const s8*>(&As[wr*32 + 16 + lrow][lk]);
        s8 bg0 = *reinterpret_cast<const s8*>(&Bs[wc*32 + lrow][lk]);
        s8 bg1 = *reinterpret_cast<const s8*>(&Bs[wc*32 + 16 + lrow][lk]);
        acc[0][0] = MFMA16(af0, bg0, acc[0][0]);
        acc[0][1] = MFMA16(af0, bg1, acc[0][1]);
        acc[1][0] = MFMA16(af1, bg0, acc[1][0]);
        acc[1][1] = MFMA16(af1, bg1, acc[1][1]);
    }
}

// ============ bf16 MFMA GEMM (64-tile, plain) ============
__global__ __launch_bounds__(256) void gemm_bf(
    const u16* __restrict__ A, const u16* __restrict__ Bt,
    float* __restrict__ Cf, u16* __restrict__ Cb,
    int M, int N, int K,
    const float* __restrict__ bias, const float* __restrict__ resid,
    int act)
{
    __shared__ u16 As[2][64][136];
    __shared__ u16 Bs[2][64][136];
    int t = threadIdx.x;
    int m0 = blockIdx.y * 64, n0 = blockIdx.x * 64;
    int wave = t >> 6, lane = t & 63;
    int wr = wave >> 1, wc = wave & 1;
    f4 acc[2][2];
    #pragma unroll
    for (int m = 0; m < 2; ++m)
        #pragma unroll
        for (int n = 0; n < 2; ++n)
            #pragma unroll
            for (int r = 0; r < 4; ++r) acc[m][n][r] = 0.f;
    int nk = (K + 127) >> 7;
    s8 pa[4], pbv[4];
    load_tile(A, K, M, K, m0, 0, t, pa);
    load_tile(Bt, K, N, K, n0, 0, t, pbv);
    write_tile(As[0], t, pa);
    write_tile(Bs[0], t, pbv);
    __syncthreads();
    for (int kt = 0; kt < nk; ++kt) {
        int cur = kt & 1;
        if (kt + 1 < nk) {
            load_tile(A, K, M, K, m0, (kt+1) << 7, t, pa);
            load_tile(Bt, K, N, K, n0, (kt+1) << 7, t, pbv);
        }
        mfma_tile(As[cur], Bs[cur], wr, wc, lane, acc);
        if (kt + 1 < nk) {
            write_tile(As[cur^1], t, pa);
            write_tile(Bs[cur^1], t, pbv);
        }
        __syncthreads();
    }
    #pragma unroll
    for (int m = 0; m < 2; ++m) {
        int rbase = m0 + wr*32 + m*16 + (lane >> 4) * 4;
        #pragma unroll
        for (int n = 0; n < 2; ++n) {
            int col = n0 + wc*32 + n*16 + (lane & 15);
            if (col >= N) continue;
            #pragma unroll
            for (int r = 0; r < 4; ++r) {
                int row = rbase + r;
                if (row >= M) continue;
                float v = acc[m][n][r];
                if (bias)  v += bias[col];
                if (resid) v += resid[(long)row * N + col];
                if (act == 1) v = 0.5f * v * (1.0f + erff(v * 0.70710678118654752f));
                long ci = (long)row * N + col;
                if (Cf) Cf[ci] = v;
                if (Cb) Cb[ci] = f2bf(v);
            }
        }
    }
}

// ============ big-tile GEMM: BM=BN=128, BK=64, dbuf; split bias pair ============
__global__ __launch_bounds__(256) void gemm_big(
    const u16* __restrict__ A, const u16* __restrict__ Bt,
    u16* __restrict__ Cb, u16* __restrict__ vt,
    int N, int K,
    const float* __restrict__ bias, const float* __restrict__ bias2, int act)
{
    __shared__ u16 As[2][128][72];
    __shared__ u16 Bs[2][128][72];
    int t = threadIdx.x;
    int m0 = blockIdx.y * 128, n0 = blockIdx.x * 128;
    int wave = t >> 6, lane = t & 63;
    int wr = wave >> 1, wc = wave & 1;
    f4 acc[4][4];
    #pragma unroll
    for (int m = 0; m < 4; ++m)
        #pragma unroll
        for (int n = 0; n < 4; ++n)
            #pragma unroll
            for (int r = 0; r < 4; ++r) acc[m][n][r] = 0.f;
    int nk = K >> 6;
    s8 pa[4], pbv[4];
    #pragma unroll
    for (int i = 0; i < 4; ++i) {
        int chunk = t + i*256;
        pa[i]  = *reinterpret_cast<const s8*>(A  + (long)(m0 + (chunk>>3))*K + (chunk&7)*8);
        pbv[i] = *reinterpret_cast<const s8*>(Bt + (long)(n0 + (chunk>>3))*K + (chunk&7)*8);
    }
    #pragma unroll
    for (int i = 0; i < 4; ++i) {
        int chunk = t + i*256;
        *reinterpret_cast<s8*>(&As[0][chunk>>3][(chunk&7)*8]) = pa[i];
        *reinterpret_cast<s8*>(&Bs[0][chunk>>3][(chunk&7)*8]) = pbv[i];
    }
    __syncthreads();
    for (int kt = 0; kt < nk; ++kt) {
        int cur = kt & 1;
        if (kt + 1 < nk) {
            int k0 = (kt+1) << 6;
            #pragma unroll
            for (int i = 0; i < 4; ++i) {
                int chunk = t + i*256;
                pa[i]  = *reinterpret_cast<const s8*>(A  + (long)(m0 + (chunk>>3))*K + k0 + (chunk&7)*8);
                pbv[i] = *reinterpret_cast<const s8*>(Bt + (long)(n0 + (chunk>>3))*K + k0 + (chunk&7)*8);
            }
        }
        #pragma unroll
        for (int kh = 0; kh < 2; ++kh) {
            int lk = kh*32 + (lane >> 4) * 8;
            int lr = lane & 15;
            s8 af[4], bf[4];
            #pragma unroll
            for (int m = 0; m < 4; ++m)
                af[m] = *reinterpret_cast<const s8*>(&As[cur][wr*64 + m*16 + lr][lk]);
            #pragma unroll
            for (int n = 0; n < 4; ++n)
                bf[n] = *reinterpret_cast<const s8*>(&Bs[cur][wc*64 + n*16 + lr][lk]);
            #pragma unroll
            for (int m = 0; m < 4; ++m)
                #pragma unroll
                for (int n = 0; n < 4; ++n)
                    acc[m][n] = MFMA16(af[m], bf[n], acc[m][n]);
        }
        if (kt + 1 < nk) {
            #pragma unroll
            for (int i = 0; i < 4; ++i) {
                int chunk = t + i*256;
                *reinterpret_cast<s8*>(&As[cur^1][chunk>>3][(chunk&7)*8]) = pa[i];
                *reinterpret_cast<s8*>(&Bs[cur^1][chunk>>3][(chunk&7)*8]) = pbv[i];
            }
        }
        __syncthreads();
    }
    #pragma unroll
    for (int m = 0; m < 4; ++m) {
        int rbase = m0 + wr*64 + m*16 + (lane >> 4) * 4;
        #pragma unroll
        for (int n = 0; n < 4; ++n) {
            int col = n0 + wc*64 + n*16 + (lane & 15);
            #pragma unroll
            for (int r = 0; r < 4; ++r) {
                int row = rbase + r;
                float v = acc[m][n][r];
                if (bias) {
                    float bb = bias2 ? ((col < 768) ? bias[col] : bias2[col - 768]) : bias[col];
                    v += bb;
                }
                if (act == 1) v = 0.5f * v * (1.0f + erff(v * 0.70710678118654752f));
                u16 b = f2bf(v);
                Cb[(long)row * N + col] = b;
                if (vt && col >= 1536) {
                    int z = (row >> 8) * 12 + ((col - 1536) >> 6);
                    vt[((long)z * 64 + (col & 63)) * 256 + (row & 255)] = b;
                }
            }
        }
    }
}

// ============ batched patch-embed (+QH from fp32 txt) GEMM ============
struct PeDesc {
    const u16* A[3];
    const u16* Bt[4];
    const float* bias[4];
    const float* pos[3];
    int K[4];
    int M[4];
};

__global__ __launch_bounds__(256) void gemm_pe(PeDesc d, const float* __restrict__ txtf,
                                               float* __restrict__ C, u16* __restrict__ QHb) {
    int z = blockIdx.z;
    int M = d.M[z], K = d.K[z];
    int m0 = blockIdx.y * 64, n0 = blockIdx.x * 64;
    if (m0 >= M) return;
    __shared__ u16 As[2][64][136];
    __shared__ u16 Bs[2][64][136];
    const u16* Bb = d.Bt[z];
    const float* bias = d.bias[z];
    int t = threadIdx.x;
    int wave = t >> 6, lane = t & 63;
    int wr = wave >> 1, wc = wave & 1;
    f4 acc[2][2];
    #pragma unroll
    for (int m = 0; m < 2; ++m)
        #pragma unroll
        for (int n = 0; n < 2; ++n)
            #pragma unroll
            for (int r = 0; r < 4; ++r) acc[m][n][r] = 0.f;
    int nk = (K + 127) >> 7;
    s8 pa[4], pbv[4];
    if (z < 3) load_tile(d.A[z], K, M, K, m0, 0, t, pa);
    else       load_tile_f32(txtf, K, M, K, m0, 0, t, pa);
    load_tile(Bb, K, 768, K, n0, 0, t, pbv);
    write_tile(As[0], t, pa);
    write_tile(Bs[0], t, pbv);
    __syncthreads();
    for (int kt = 0; kt < nk; ++kt) {
        int cur = kt & 1;
        if (kt + 1 < nk) {
            if (z < 3) load_tile(d.A[z], K, M, K, m0, (kt+1) << 7, t, pa);
            else       load_tile_f32(txtf, K, M, K, m0, (kt+1) << 7, t, pa);
            load_tile(Bb, K, 768, K, n0, (kt+1) << 7, t, pbv);
        }
        mfma_tile(As[cur], Bs[cur], wr, wc, lane, acc);
        if (kt + 1 < nk) {
            write_tile(As[cur^1], t, pa);
            write_tile(Bs[cur^1], t, pbv);
        }
        __syncthreads();
    }
    #pragma unroll
    for (int m = 0; m < 2; ++m) {
        int rbase = m0 + wr*32 + m*16 + (lane >> 4) * 4;
        #pragma unroll
        for (int n = 0; n < 2; ++n) {
            int col = n0 + wc*32 + n*16 + (lane & 15);
            #pragma unroll
            for (int r = 0; r < 4; ++r) {
                int row = rbase + r;
                if (row >= M) continue;
                float v = acc[m][n][r] + bias[col];
                if (z < 3) {
                    v += d.pos[z][(long)(row & 255)*768 + col];
                    C[((long)z*512 + row) * 768 + col] = v;
                } else {
                    QHb[(long)row * 768 + col] = f2bf(v);
                }
            }
        }
    }
}

// ============ output-proj GEMM + fused unpatchify: plane = vw[z]*(X6b[z] @ owT[z] + bias) ============
struct OwDesc {
    const u16* Bt[3];
    float* plane[3];
    const float* bias[3];
    int N[3];
    int p2[3];
    int Wd[3];
};

__global__ __launch_bounds__(256) void gemm_ow(OwDesc d, const u16* __restrict__ A,
                                               const float* __restrict__ vwp) {
    int z = blockIdx.z;
    int N = d.N[z];
    int n0 = blockIdx.x * 64;
    if (n0 >= N) return;
    __shared__ u16 As[2][64][136];
    __shared__ u16 Bs[2][64][136];
    const u16* Ab = A + (long)z * 512 * 768;
    const u16* Bb = d.Bt[z];
    int t = threadIdx.x;
    int m0 = blockIdx.y * 64;
    int wave = t >> 6, lane = t & 63;
    int wr = wave >> 1, wc = wave & 1;
    f4 acc[2][2];
    #pragma unroll
    for (int m = 0; m < 2; ++m)
        #pragma unroll
        for (int n = 0; n < 2; ++n)
            #pragma unroll
            for (int r = 0; r < 4; ++r) acc[m][n][r] = 0.f;
    s8 pa[4], pbv[4];
    load_tile(Ab, 768, 512, 768, m0, 0, t, pa);
    load_tile(Bb, 768, N, 768, n0, 0, t, pbv);
    write_tile(As[0], t, pa);
    write_tile(Bs[0], t, pbv);
    __syncthreads();
    for (int kt = 0; kt < 6; ++kt) {
        int cur = kt & 1;
        if (kt + 1 < 6) {
            load_tile(Ab, 768, 512, 768, m0, (kt+1) << 7, t, pa);
            load_tile(Bb, 768, N, 768, n0, (kt+1) << 7, t, pbv);
        }
        mfma_tile(As[cur], Bs[cur], wr, wc, lane, acc);
        if (kt + 1 < 6) {
            write_tile(As[cur^1], t, pa);
            write_tile(Bs[cur^1], t, pbv);
        }
        __syncthreads();
    }
    float* plane = d.plane[z];
    const float* bias = d.bias[z];
    int p2 = d.p2[z], Wd = d.Wd[z];
    float wt = vwp[z];
    #pragma unroll
    for (int m = 0; m < 2; ++m) {
        int rbase = m0 + wr*32 + m*16 + (lane >> 4) * 4;
        #pragma unroll
        for (int n = 0; n < 2; ++n) {
            int col = n0 + wc*32 + n*16 + (lane & 15);
            if (col >= N) continue;
            int pp = col >> 5, c = col & 31;
            int pp1 = pp / p2, pp2 = pp % p2;
            float bv = bias[col];
            #pragma unroll
            for (int r = 0; r < 4; ++r) {
                int row = rbase + r;
                int b = row >> 8, nn = row & 255;
                int hh = nn >> 4, ww = nn & 15;
                int ho = hh*7 + pp1, wo = ww*p2 + pp2;
                plane[((long)(b*32 + c)*112 + ho)*Wd + wo] = wt * (acc[m][n][r] + bv);
            }
        }
    }
}

// ============ LayerNorm rows of 768 ============
__global__ __launch_bounds__(256) void ln_k(const float* __restrict__ in,
                                            float* __restrict__ outf,
                                            u16* __restrict__ outb,
                                            const float* __restrict__ g,
                                            const float* __restrict__ bta) {
    constexpr int N = 768;
    int row = blockIdx.x;
    const float* x = in + (size_t)row * N;
    int t = threadIdx.x;
    float v0 = x[t], v1 = x[t+256], v2 = x[t+512];
    float s = v0+v1+v2, s2 = v0*v0+v1*v1+v2*v2;
    #pragma unroll
    for (int off = 32; off > 0; off >>= 1) { s += __shfl_down(s, off); s2 += __shfl_down(s2, off); }
    __shared__ float red[8];
    int wid = t >> 6, lane = t & 63;
    if (lane == 0) { red[wid] = s; red[wid+4] = s2; }
    __syncthreads();
    if (t == 0) {
        float S = red[0]+red[1]+red[2]+red[3];
        float S2 = red[4]+red[5]+red[6]+red[7];
        float mean = S * (1.f/N);
        float var = S2 * (1.f/N) - mean*mean;
        red[0] = mean; red[1] = rsqrtf(var + 1e-5f);
    }
    __syncthreads();
    float mean = red[0], rstd = red[1];
    float y0 = (v0-mean)*rstd*g[t]     + bta[t];
    float y1 = (v1-mean)*rstd*g[t+256] + bta[t+256];
    float y2 = (v2-mean)*rstd*g[t+512] + bta[t+512];
    if (outf) {
        float* y = outf + (size_t)row * N;
        y[t] = y0; y[t+256] = y1; y[t+512] = y2;
    }
    if (outb) {
        u16* y = outb + (size_t)row * N;
        y[t] = f2bf(y0); y[t+256] = f2bf(y1); y[t+512] = f2bf(y2);
    }
}

// ============ fully fused self-attention: QK^T + softmax + PV ============
__global__ __launch_bounds__(256) void attn_k(const u16* __restrict__ QKV,
                                              const u16* __restrict__ Vt,
                                              u16* __restrict__ O) {
    __shared__ u16 Ks[256][72];
    __shared__ u16 Ps[128][264];
    __shared__ u16 Vs[64][264];
    int zz = blockIdx.x;
    int bh = zz >> 1, half = zz & 1;
    int bb = bh / 12, h = bh % 12;
    long qrow0 = (long)bb*256 + half*128;
    int hcol = h*64;
    int t = threadIdx.x;
    int wave = t >> 6, lane = t & 63;
    int lr = lane & 15, lg = lane >> 4;
    #pragma unroll
    for (int i = 0; i < 8; ++i) {
        int chunk = t + i*256;
        int row = chunk >> 3, c8 = (chunk & 7)*8;
        *reinterpret_cast<s8*>(&Ks[row][c8]) =
            *reinterpret_cast<const s8*>(QKV + ((long)bb*256 + row)*2304 + 768 + hcol + c8);
    }
    #pragma unroll
    for (int i = 0; i < 8; ++i) {
        int chunk = t + i*256;
        int d = chunk >> 5, j8 = (chunk & 31)*8;
        *reinterpret_cast<s8*>(&Vs[d][j8]) =
            *reinterpret_cast<const s8*>(Vt + (long)bh*16384 + (long)d*256 + j8);
    }
    __syncthreads();
    f4 acc[2][16];
    #pragma unroll
    for (int m = 0; m < 2; ++m)
        #pragma unroll
        for (int n = 0; n < 16; ++n)
            #pragma unroll
            for (int r = 0; r < 4; ++r) acc[m][n][r] = 0.f;
    #pragma unroll
    for (int kh = 0; kh < 2; ++kh) {
        s8 af0 = *reinterpret_cast<const s8*>(QKV + (qrow0 + wave*32 + lr)*2304 + hcol + kh*32 + lg*8);
        s8 af1 = *reinterpret_cast<const s8*>(QKV + (qrow0 + wave*32 + 16 + lr)*2304 + hcol + kh*32 + lg*8);
        #pragma unroll
        for (int n = 0; n < 16; ++n) {
            s8 bf = *reinterpret_cast<const s8*>(&Ks[n*16 + lr][kh*32 + lg*8]);
            acc[0][n] = MFMA16(af0, bf, acc[0][n]);
            acc[1][n] = MFMA16(af1, bf, acc[1][n]);
        }
    }
    #pragma unroll
    for (int m = 0; m < 2; ++m)
        #pragma unroll
        for (int r = 0; r < 4; ++r) {
            float mx = -1e30f;
            #pragma unroll
            for (int n = 0; n < 16; ++n) mx = fmaxf(mx, acc[m][n][r]);
            #pragma unroll
            for (int o = 8; o; o >>= 1) mx = fmaxf(mx, __shfl_xor(mx, o));
            float l = 0.f;
            float p[16];
            #pragma unroll
            for (int n = 0; n < 16; ++n) {
                p[n] = __expf((acc[m][n][r] - mx) * 0.125f);
                l += p[n];
            }
            #pragma unroll
            for (int o = 8; o; o >>= 1) l += __shfl_xor(l, o);
            float inv = 1.f / l;
            int prow = wave*32 + m*16 + lg*4 + r;
            #pragma unroll
            for (int n = 0; n < 16; ++n)
                Ps[prow][n*16 + lr] = f2bf(p[n] * inv);
        }
    __syncthreads();
    f4 o2[2][4];
    #pragma unroll
    for (int m = 0; m < 2; ++m)
        #pragma unroll
        for (int n = 0; n < 4; ++n)
            #pragma unroll
            for (int r = 0; r < 4; ++r) o2[m][n][r] = 0.f;
    #pragma unroll
    for (int kh = 0; kh < 8; ++kh) {
        s8 pf0 = *reinterpret_cast<const s8*>(&Ps[wave*32 + lr][kh*32 + lg*8]);
        s8 pf1 = *reinterpret_cast<const s8*>(&Ps[wave*32 + 16 + lr][kh*32 + lg*8]);
        #pragma unroll
        for (int n = 0; n < 4; ++n) {
            s8 vf = *reinterpret_cast<const s8*>(&Vs[n*16 + lr][kh*32 + lg*8]);
            o2[0][n] = MFMA16(pf0, vf, o2[0][n]);
            o2[1][n] = MFMA16(pf1, vf, o2[1][n]);
        }
    }
    #pragma unroll
    for (int m = 0; m < 2; ++m)
        #pragma unroll
        for (int n = 0; n < 4; ++n)
            #pragma unroll
            for (int r = 0; r < 4; ++r)
                O[(qrow0 + wave*32 + m*16 + lg*4 + r)*768 + hcol + n*16 + lr] = f2bf(o2[m][n][r]);
}

// ============ fully fused cross-attention: S2 + colsum-softmax + apply ============
__global__ __launch_bounds__(256) void ca_fused(const u16* __restrict__ QHb,
                                                const u16* __restrict__ KVHb,
                                                u16* __restrict__ O) {
    __shared__ u16 QHs[80][72];
    __shared__ u16 KHs[256][72];
    __shared__ float rmax[80][4];
    __shared__ float rsum[80][4];
    __shared__ float Wj[256];
    int bh = blockIdx.x;
    int rowblk = bh / 12, h = bh % 12;
    int bsel = rowblk & 1;
    int t = threadIdx.x;
    int wave = t >> 6, lane = t & 63;
    int lr = lane & 15, lg = lane >> 4;
    #pragma unroll
    for (int i = 0; i < 3; ++i) {
        int chunk = t + i*256;
        if (chunk < 640) {
            int row = chunk >> 3, c8 = (chunk & 7)*8;
            s8 v;
            #pragma unroll
            for (int q = 0; q < 8; ++q) v[q] = 0;
            if (row < 77)
                v = *reinterpret_cast<const s8*>(QHb + ((long)(bsel*77 + row))*768 + h*64 + c8);
            *reinterpret_cast<s8*>(&QHs[row][c8]) = v;
        }
    }
    #pragma unroll
    for (int i = 0; i < 8; ++i) {
        int chunk = t + i*256;
        int row = chunk >> 3, c8 = (chunk & 7)*8;
        *reinterpret_cast<s8*>(&KHs[row][c8]) =
            *reinterpret_cast<const s8*>(KVHb + ((long)rowblk*256 + row)*1536 + h*64 + c8);
    }
    __syncthreads();
    f4 acc[5][4];
    #pragma unroll
    for (int m = 0; m < 5; ++m)
        #pragma unroll
        for (int n = 0; n < 4; ++n)
            #pragma unroll
            for (int r = 0; r < 4; ++r) acc[m][n][r] = 0.f;
    #pragma unroll
    for (int kh = 0; kh < 2; ++kh) {
        s8 af[5], bf[4];
        #pragma unroll
        for (int m = 0; m < 5; ++m)
            af[m] = *reinterpret_cast<const s8*>(&QHs[m*16 + lr][kh*32 + lg*8]);
        #pragma unroll
        for (int n = 0; n < 4; ++n)
            bf[n] = *reinterpret_cast<const s8*>(&KHs[wave*64 + n*16 + lr][kh*32 + lg*8]);
        #pragma unroll
        for (int m = 0; m < 5; ++m)
            #pragma unroll
            for (int n = 0; n < 4; ++n)
                acc[m][n] = MFMA16(af[m], bf[n], acc[m][n]);
    }
    #pragma unroll
    for (int m = 0; m < 5; ++m)
        #pragma unroll
        for (int r = 0; r < 4; ++r) {
            float mx = -1e30f;
            #pragma unroll
            for (int n = 0; n < 4; ++n) mx = fmaxf(mx, acc[m][n][r]);
            #pragma unroll
            for (int o = 8; o; o >>= 1) mx = fmaxf(mx, __shfl_xor(mx, o));
            if (lr == 0) rmax[m*16 + lg*4 + r][wave] = mx;
        }
    __syncthreads();
    #pragma unroll
    for (int m = 0; m < 5; ++m)
        #pragma unroll
        for (int r = 0; r < 4; ++r) {
            int i = m*16 + lg*4 + r;
            float mi = fmaxf(fmaxf(rmax[i][0], rmax[i][1]), fmaxf(rmax[i][2], rmax[i][3]));
            float s = 0.f;
            #pragma unroll
            for (int n = 0; n < 4; ++n) s += __expf((acc[m][n][r] - mi) * 0.125f);
            #pragma unroll
            for (int o = 8; o; o >>= 1) s += __shfl_xor(s, o);
            if (lr == 0) rsum[i][wave] = s;
        }
    __syncthreads();
    float wn[4] = {0.f, 0.f, 0.f, 0.f};
    #pragma unroll
    for (int m = 0; m < 5; ++m)
        #pragma unroll
        for (int r = 0; r < 4; ++r) {
            int i = m*16 + lg*4 + r;
            if (i < 77) {
                float mi = fmaxf(fmaxf(rmax[i][0], rmax[i][1]), fmaxf(rmax[i][2], rmax[i][3]));
                float li = rsum[i][0] + rsum[i][1] + rsum[i][2] + rsum[i][3];
                float inv = 1.f / li;
                #pragma unroll
                for (int n = 0; n < 4; ++n)
                    wn[n] += __expf((acc[m][n][r] - mi) * 0.125f) * inv;
            }
        }
    #pragma unroll
    for (int n = 0; n < 4; ++n) {
        wn[n] += __shfl_xor(wn[n], 16);
        wn[n] += __shfl_xor(wn[n], 32);
    }
    if (lane < 16) {
        #pragma unroll
        for (int n = 0; n < 4; ++n) Wj[wave*64 + n*16 + lr] = wn[n];
    }
    __syncthreads();
    int d = t & 63;
    #pragma unroll 4
    for (int it = 0; it < 64; ++it) {
        int j = it*4 + (t >> 6);
        long row = (long)rowblk*256 + j;
        float vh = bf2f(KVHb[row*1536 + 768 + h*64 + d]);
        O[row*768 + h*64 + d] = f2bf(Wj[j] * vh);
    }
}

// ============ streaming final combine ============
__global__ __launch_bounds__(256) void final_k(const float* __restrict__ img,
                                               const float* __restrict__ Aax,
                                               const float* __restrict__ Asag,
                                               const float* __restrict__ Acor,
                                               float* __restrict__ out) {
    int blk = blockIdx.x;                 // bc*112 + d
    int bc = blk / 112;
    const float4* ip = reinterpret_cast<const float4*>(img + (size_t)blk * 8960);
    const float4* ap = reinterpret_cast<const float4*>(Aax + (size_t)bc * 8960);
    const float4* sp = reinterpret_cast<const float4*>(Asag + (size_t)blk * 80);
    const float*  cp = Acor + (size_t)blk * 112;
    float4* op = reinterpret_cast<float4*>(out + (size_t)blk * 8960);
    int t = threadIdx.x;
    for (int q = t; q < 2240; q += 256) {
        int h = q / 20, w4 = q % 20;
        float4 iv = ip[q], av = ap[q], sv = sp[w4];
        float cv = cp[h];
        float4 o;
        o.x = iv.x + av.x + sv.x + cv;
        o.y = iv.y + av.y + sv.y + cv;
        o.z = iv.z + av.z + sv.z + cv;
        o.w = iv.w + av.w + sv.w + cv;
        op[q] = o;
    }
}

extern "C" void kernel_launch(void* const* d_in, const int* in_sizes, int n_in,
                              void* d_out, int out_size, void* d_ws, size_t ws_size,
                              hipStream_t stream) {
    (void)in_sizes; (void)n_in; (void)out_size; (void)ws_size;
    const float* img    = (const float*)d_in[0];
    const float* txt    = (const float*)d_in[1];
    const float* pe_w[3] = {(const float*)d_in[2], (const float*)d_in[4], (const float*)d_in[6]};
    const float* pe_b[3] = {(const float*)d_in[3], (const float*)d_in[5], (const float*)d_in[7]};
    const float* pos[3]  = {(const float*)d_in[8], (const float*)d_in[9], (const float*)d_in[10]};
    const float* qw = (const float*)d_in[11];
    const float* kw = (const float*)d_in[12];
    const float* vw_attn = (const float*)d_in[13];
    const float* pw = (const float*)d_in[14];
    const float* pb = (const float*)d_in[15];
    const float* caq_w = (const float*)d_in[16];
    const float* caq_b = (const float*)d_in[17];
    const float* cak_w = (const float*)d_in[18];
    const float* cak_b = (const float*)d_in[19];
    const float* cav_w = (const float*)d_in[20];
    const float* cav_b = (const float*)d_in[21];
    const float* cao_w = (const float*)d_in[22];
    const float* cao_b = (const float*)d_in[23];
    const float* mlp_w1 = (const float*)d_in[24];
    const float* mlp_b1 = (const float*)d_in[25];
    const float* mlp_w2 = (const float*)d_in[26];
    const float* mlp_b2 = (const float*)d_in[27];
    const float* ow[3] = {(const float*)d_in[28], (const float*)d_in[30], (const float*)d_in[32]};
    const float* ob[3] = {(const float*)d_in[29], (const float*)d_in[31], (const float*)d_in[33]};
    const float* view_w = (const float*)d_in[34];
    const float* n_g[3] = {(const float*)d_in[35], (const float*)d_in[36], (const float*)d_in[37]};
    const float* n_b[3] = {(const float*)d_in[38], (const float*)d_in[39], (const float*)d_in[40]};

    // ---- big scratch lives in d_out (fully rewritten by final_k) ----
    unsigned char* sb = (unsigned char*)d_out;
    size_t off = 0;
    auto B = [&](size_t bytes) -> void* {
        void* p = sb + off; off += (bytes + 511) & ~(size_t)511; return p;
    };
    u16* qkvT  = (u16*)B((size_t)2304*768*2);
    u16* pwT   = (u16*)B(768*768*2);
    u16* caqT  = (u16*)B(768*768*2);
    u16* cakvT = (u16*)B((size_t)1536*768*2);
    u16* caoT  = (u16*)B(768*768*2);
    u16* mlp1T = (u16*)B((size_t)3072*768*2);
    u16* mlp2T = (u16*)B((size_t)768*3072*2);
    u16* peT[3]; peT[0] = (u16*)B((size_t)768*1120*2); peT[1] = (u16*)B((size_t)768*1120*2); peT[2] = (u16*)B((size_t)768*1568*2);
    u16* owT[3]; owT[0] = (u16*)B((size_t)1120*768*2); owT[1] = (u16*)B((size_t)1120*768*2); owT[2] = (u16*)B((size_t)1568*768*2);
    float* axp   = (float*)B((size_t)16*573440*4);
    float* m_sag = (float*)B(573440*4);
    float* m_cor = (float*)B(802816*4);
    u16* P0 = (u16*)B((size_t)512*1120*2);
    u16* P1 = (u16*)B((size_t)512*1120*2);
    u16* P2 = (u16*)B((size_t)512*1568*2);
    float* X0  = (float*)B((size_t)1536*768*4);
    float* X1f = (float*)B((size_t)1536*768*4);
    float* X2  = (float*)B((size_t)1536*768*4);
    float* X3f = (float*)B((size_t)1536*768*4);
    float* X4  = (float*)B((size_t)1536*768*4);
    u16* X1b = (u16*)B((size_t)1536*768*2);
    u16* X3b = (u16*)B((size_t)1536*768*2);
    u16* X5b = (u16*)B((size_t)1536*768*2);
    u16* X6b = (u16*)B((size_t)1536*768*2);
    u16* QKVb = (u16*)B((size_t)1536*2304*2);
    u16* Obf = (u16*)B((size_t)1536*768*2);
    u16* Vt  = (u16*)B((size_t)72*64*256*2);
    u16* Hb  = (u16*)B((size_t)1536*3072*2);
    u16* KVHb = (u16*)B((size_t)1536*1536*2);
    u16* QHb  = (u16*)B((size_t)154*768*2);

    // ---- dense view planes live in d_ws ----
    float* ws = (float*)d_ws;
    float* Aax  = ws;
    float* Asag = ws + 573440;
    float* Acor = ws + 1146880;

    // ---- batched weight transposes (1 launch) ----
    TT tab;
    {
        const float* ins[16] = {qw, kw, vw_attn, pw, caq_w, cak_w, cav_w, cao_w,
                                mlp_w1, mlp_w2, pe_w[0], pe_w[1], pe_w[2], ow[0], ow[1], ow[2]};
        u16* outs[16] = {qkvT, qkvT + 768*768, qkvT + 2*768*768, pwT, caqT, cakvT,
                         cakvT + 768*768, caoT, mlp1T, mlp2T, peT[0], peT[1], peT[2],
                         owT[0], owT[1], owT[2]};
        int Ks[16] = {768,768,768,768,768,768,768,768, 768,3072, 1120,1120,1568, 768,768,768};
        int Ns[16] = {768,768,768,768,768,768,768,768, 3072,768, 768,768,768, 1120,1120,1568};
        int st = 0;
        for (int i = 0; i < 16; ++i) {
            tab.in[i] = ins[i]; tab.out[i] = outs[i]; tab.K[i] = Ks[i]; tab.N[i] = Ns[i];
            tab.start[i] = st;
            st += (Ks[i] >> 5) * (Ns[i] >> 5);
        }
        transp_all<<<st, 256, 0, stream>>>(tab);
    }

    mean3_k<<<1024, 256, 0, stream>>>(img, axp, m_sag, m_cor);
    patchify3_k<<<dim3(224,3), 256, 0, stream>>>(axp, m_sag, m_cor, P0, P1, P2);

    auto gemm = [&](const u16* A, const u16* Bt, float* Cf, u16* Cb,
                    int M, int N, int K, const float* bias, const float* resid, int act) {
        dim3 g((N+63)/64, (M+63)/64, 1);
        gemm_bf<<<g, 256, 0, stream>>>(A, Bt, Cf, Cb, M, N, K, bias, resid, act);
    };

    // patch-embed (z=0..2) + QH projection from fp32 txt (z=3), one launch
    {
        PeDesc d;
        d.A[0] = P0; d.A[1] = P1; d.A[2] = P2;
        d.Bt[0] = peT[0]; d.Bt[1] = peT[1]; d.Bt[2] = peT[2]; d.Bt[3] = caqT;
        d.bias[0] = pe_b[0]; d.bias[1] = pe_b[1]; d.bias[2] = pe_b[2]; d.bias[3] = caq_b;
        d.pos[0] = pos[0]; d.pos[1] = pos[1]; d.pos[2] = pos[2];
        d.K[0] = 1120; d.K[1] = 1120; d.K[2] = 1568; d.K[3] = 768;
        d.M[0] = 512; d.M[1] = 512; d.M[2] = 512; d.M[3] = 154;
        gemm_pe<<<dim3(12,8,4), 256, 0, stream>>>(d, txt, X0, QHb);
    }

    ln_k<<<1536, 256, 0, stream>>>(X0, X1f, X1b, n_g[0], n_b[0]);
    // fused QKV projection (big tile) + per-head V transpose
    gemm_big<<<dim3(18,12), 256, 0, stream>>>(X1b, qkvT, QKVb, Vt, 2304, 768, nullptr, nullptr, 0);
    // fully fused self-attention
    attn_k<<<144, 256, 0, stream>>>(QKVb, Vt, Obf);
    gemm(Obf, pwT, X2, nullptr, 1536, 768, 768, pb, X1f, 0);
    ln_k<<<1536, 256, 0, stream>>>(X2, X3f, X3b, n_g[1], n_b[1]);
    // fused cak||cav (big tile, split bias)
    gemm_big<<<dim3(12,12), 256, 0, stream>>>(X3b, cakvT, KVHb, nullptr, 1536, 768, cak_b, cav_b, 0);
    // fully fused cross-attention
    ca_fused<<<72, 256, 0, stream>>>(QHb, KVHb, Obf);
    gemm(Obf, caoT, X4, nullptr, 1536, 768, 768, cao_b, X3f, 0);
    ln_k<<<1536, 256, 0, stream>>>(X4, nullptr, X5b, n_g[2], n_b[2]);
    // MLP
    gemm_big<<<dim3(24,12), 256, 0, stream>>>(X5b, mlp1T, Hb, nullptr, 3072, 768, mlp_b1, nullptr, 1);
    gemm(Hb, mlp2T, nullptr, X6b, 1536, 768, 3072, mlp_b2, X4, 0);
    // output projections + fused unpatchify (batched z=3)
    {
        OwDesc d;
        d.Bt[0] = owT[0]; d.Bt[1] = owT[1]; d.Bt[2] = owT[2];
        d.plane[0] = Aax; d.plane[1] = Asag; d.plane[2] = Acor;
        d.bias[0] = ob[0]; d.bias[1] = ob[1]; d.bias[2] = ob[2];
        d.N[0] = 1120; d.N[1] = 1120; d.N[2] = 1568;
        d.p2[0] = 5; d.p2[1] = 5; d.p2[2] = 7;
        d.Wd[0] = 80; d.Wd[1] = 80; d.Wd[2] = 112;
        gemm_ow<<<dim3(25,8,3), 256, 0, stream>>>(d, X6b, view_w);
    }

    final_k<<<7168, 256, 0, stream>>>(img, Aax, Asag, Acor, (float*)d_out);
}